// Round 5
// baseline (2124.505 us; speedup 1.0000x reference)
//
#include <hip/hip_runtime.h>
#include <hip/hip_bf16.h>
#include <math.h>

#define HEADS 4
#define HID 64
#define OUTD 7

__device__ __forceinline__ float gelu_exact(float x) {
    return 0.5f * x * (1.0f + erff(x * 0.70710678118654752f));
}

// broadcast lane k of v to all lanes (SGPR result); k must be wave-uniform
__device__ __forceinline__ float readlane_f(float v, int k) {
    union { float f; int i; } u;
    u.f = v;
    u.i = __builtin_amdgcn_readlane(u.i, k);
    return u.f;
}

// ---------------- CSR build ----------------

__global__ void hist_kernel(const int* __restrict__ dst, int* __restrict__ cnt, int E) {
    for (int e = blockIdx.x * blockDim.x + threadIdx.x; e < E; e += gridDim.x * blockDim.x)
        atomicAdd(&cnt[dst[e]], 1);
}

__global__ __launch_bounds__(256) void scan1_kernel(const int* __restrict__ cnt,
                                                    int* __restrict__ rowptr,
                                                    int* __restrict__ bsum, int Nn) {
    __shared__ int sums[256];
    int t = threadIdx.x;
    int base = blockIdx.x * 2048 + t * 8;
    int orig[8];
    int run = 0;
#pragma unroll
    for (int i = 0; i < 8; i++) {
        orig[i] = (base + i < Nn) ? cnt[base + i] : 0;
        run += orig[i];
    }
    sums[t] = run;
    __syncthreads();
    for (int off = 1; off < 256; off <<= 1) {
        int y = (t >= off) ? sums[t - off] : 0;
        __syncthreads();
        sums[t] += y;
        __syncthreads();
    }
    int excl = sums[t] - run;
    if (t == 255) bsum[blockIdx.x] = sums[255];
    int e = excl;
#pragma unroll
    for (int i = 0; i < 8; i++) {
        if (base + i < Nn) rowptr[base + i] = e;
        e += orig[i];
    }
}

__global__ void scan2_kernel(int* __restrict__ bsum, int* __restrict__ rowptr, int nb, int Nn) {
    if (blockIdx.x == 0 && threadIdx.x == 0) {
        int run = 0;
        for (int i = 0; i < nb; i++) {
            int t = bsum[i];
            bsum[i] = run;
            run += t;
        }
        rowptr[Nn] = run;
    }
}

__global__ void scan3_kernel(int* __restrict__ rowptr, const int* __restrict__ bsum, int Nn) {
    int i = blockIdx.x * blockDim.x + threadIdx.x;
    if (i < Nn) rowptr[i] += bsum[i >> 11];
}

__global__ void scatter_kernel(const int* __restrict__ dst, const int* __restrict__ rowptr,
                               int* __restrict__ cnt, int* __restrict__ eidx, int E) {
    for (int e = blockIdx.x * blockDim.x + threadIdx.x; e < E; e += gridDim.x * blockDim.x) {
        int d = dst[e];
        int p = rowptr[d] + atomicAdd(&cnt[d], 1);
        eidx[p] = e;
    }
}

// srcp[p] = src[eidx[p]] : CSR-ordered source ids (coalesced reads in aggregate)
__global__ void srcp_kernel(const int* __restrict__ eidx, const int* __restrict__ srcv,
                            int* __restrict__ srcp, int E) {
    int p = blockIdx.x * blockDim.x + threadIdx.x;
    if (p < E) srcp[p] = srcv[eidx[p]];
}

// ---------------- GEMM (x-in-registers + readlane broadcast, W in LDS) ----------------
// MODE 0: X[N,64]  @ Wcat + b -> Z HEAD-MAJOR [4][N][64]  (for head-seq aggregation)
// MODE 1: X[N,256] @ W[256][64] + b[64]                   -> Z[N,64]
// MODE 2: X[N,64]  @ Wo per-head [4][64][7] + bo[4][7]    -> Z[N,32] (8/head, col7=0)

template <int MODE>
__global__ __launch_bounds__(256, 2) void gemm_kernel(const float* __restrict__ X,
                                                      const float* __restrict__ Wt,
                                                      const float* __restrict__ Bt,
                                                      float* __restrict__ Z, int Nn) {
    constexpr int K = (MODE == 1) ? 256 : 64;
    constexpr int M = (MODE == 0) ? 256 : (MODE == 1 ? 64 : 32);
    constexpr int CPL = (MODE == 0) ? 4 : 1;  // cols per lane

    __shared__ float wlds[K * M];

    const int tid = threadIdx.x;
    const int wid = tid >> 6;
    const int lane = tid & 63;
    const int row0 = blockIdx.x * 32 + wid * 8;

    // ---- stage full W panel once ----
    if (MODE == 0) {
#pragma unroll
        for (int it = 0; it < 16; ++it) {
            int flat = it * 1024 + tid * 4;  // k*256 + m
            int k = flat >> 8, m = flat & 255;
            int h = m >> 6, c = m & 63;
            *(float4*)&wlds[flat] = *(const float4*)(Wt + h * 4096 + k * 64 + c);
        }
    } else if (MODE == 1) {
#pragma unroll
        for (int it = 0; it < 16; ++it) {
            int flat = it * 1024 + tid * 4;  // straight copy of [256][64]
            *(float4*)&wlds[flat] = *(const float4*)(Wt + flat);
        }
    } else {
#pragma unroll
        for (int it = 0; it < 8; ++it) {
            int idx = it * 256 + tid;  // k*32 + m
            int k = idx >> 5, m = idx & 31, h = m >> 3, j = m & 7;
            wlds[idx] = (j < 7) ? Wt[h * 448 + k * 7 + j] : 0.f;
        }
    }
    __syncthreads();

    float acc[8][CPL];
#pragma unroll
    for (int r = 0; r < 8; ++r)
#pragma unroll
        for (int c = 0; c < CPL; ++c) acc[r][c] = 0.f;

    if (MODE == 0 || MODE == 2) {
        float xr[8];
#pragma unroll
        for (int r = 0; r < 8; ++r) {
            int rr = row0 + r;
            rr = (rr < Nn) ? rr : (Nn - 1);
            xr[r] = X[(size_t)rr * 64 + lane];
        }
#pragma unroll 4
        for (int k = 0; k < 64; ++k) {
            if (MODE == 0) {
                float4 wv = *(const float4*)&wlds[k * 256 + lane * 4];
#pragma unroll
                for (int r = 0; r < 8; ++r) {
                    float xk = readlane_f(xr[r], k);
                    acc[r][0] = fmaf(xk, wv.x, acc[r][0]);
                    acc[r][1] = fmaf(xk, wv.y, acc[r][1]);
                    acc[r][2] = fmaf(xk, wv.z, acc[r][2]);
                    acc[r][3] = fmaf(xk, wv.w, acc[r][3]);
                }
            } else {
                float wv = wlds[k * 32 + (lane & 31)];
#pragma unroll
                for (int r = 0; r < 8; ++r)
                    acc[r][0] = fmaf(readlane_f(xr[r], k), wv, acc[r][0]);
            }
        }
    } else {
        float xr[8], xn[8];
#pragma unroll
        for (int r = 0; r < 8; ++r) {
            int rr = row0 + r;
            rr = (rr < Nn) ? rr : (Nn - 1);
            xr[r] = X[(size_t)rr * 256 + lane];
        }
        for (int kc = 0; kc < 4; ++kc) {
            if (kc < 3) {
#pragma unroll
                for (int r = 0; r < 8; ++r) {
                    int rr = row0 + r;
                    rr = (rr < Nn) ? rr : (Nn - 1);
                    xn[r] = X[(size_t)rr * 256 + (kc + 1) * 64 + lane];
                }
            }
#pragma unroll 4
            for (int k = 0; k < 64; ++k) {
                float wv = wlds[(kc * 64 + k) * 64 + lane];
#pragma unroll
                for (int r = 0; r < 8; ++r)
                    acc[r][0] = fmaf(readlane_f(xr[r], k), wv, acc[r][0]);
            }
#pragma unroll
            for (int r = 0; r < 8; ++r) xr[r] = xn[r];
        }
    }

    // ---- epilogue ----
    if (MODE == 0) {
        // head-major write: Z[h][row][64]; lane owns head h=lane>>4, cols (lane&15)*4
        float4 bv = *(const float4*)(Bt + lane * 4);
        int h = lane >> 4;
        int c = (lane & 15) * 4;
#pragma unroll
        for (int r = 0; r < 8; ++r) {
            int row = row0 + r;
            if (row < Nn) {
                float4 s = {acc[r][0] + bv.x, acc[r][1] + bv.y, acc[r][2] + bv.z,
                            acc[r][3] + bv.w};
                *(float4*)(Z + ((size_t)h * Nn + row) * 64 + c) = s;
            }
        }
    } else if (MODE == 1) {
        float bv = Bt[lane];
#pragma unroll
        for (int r = 0; r < 8; ++r) {
            int row = row0 + r;
            if (row < Nn) Z[(size_t)row * 64 + lane] = acc[r][0] + bv;
        }
    } else {
        if (lane < 32) {
            int m = lane, h = m >> 3, j = m & 7;
            float bv = (j < 7) ? Bt[h * 7 + j] : 0.f;
#pragma unroll
            for (int r = 0; r < 8; ++r) {
                int row = row0 + r;
                if (row < Nn) Z[(size_t)row * 32 + m] = (j < 7) ? acc[r][0] + bv : 0.f;
            }
        }
    }
}

// ---------------- per-node attention scalars ----------------

// head-major variant: Z is [NH][N][64]; SL/SR written [NH][N] (scalar gathers later)
template <int NH>
__global__ __launch_bounds__(256) void slr_hm_kernel(const float* __restrict__ Z,
                                                     const float* __restrict__ A,
                                                     float* __restrict__ SL,
                                                     float* __restrict__ SR, int Nn) {
    int gw = (blockIdx.x * blockDim.x + threadIdx.x) >> 6;
    int lane = threadIdx.x & 63;
    int total = Nn * NH;
    if (gw >= total) return;
    int h = gw / Nn, n = gw - h * Nn;  // head slow-varying: coalesced slice reads
    float v = Z[((size_t)h * Nn + n) * 64 + lane];
    float al = A[h * 128 + lane];
    float ar = A[h * 128 + 64 + lane];
    float sl = v * al, sr = v * ar;
#pragma unroll
    for (int off = 32; off; off >>= 1) {
        sl += __shfl_xor(sl, off);
        sr += __shfl_xor(sr, off);
    }
    if (lane == 0) {
        SL[(size_t)h * Nn + n] = sl;
        SR[(size_t)h * Nn + n] = sr;
    }
}

// interleaved variant for the out layer: SL/SR[n*NH+h] (float4 gather in aggregateo)
template <int NH, int D, int DP>
__global__ __launch_bounds__(256) void slr_kernel(const float* __restrict__ Z,
                                                  const float* __restrict__ A,
                                                  float* __restrict__ SL, float* __restrict__ SR,
                                                  int Nn) {
    int gw = (blockIdx.x * blockDim.x + threadIdx.x) >> 6;
    int lane = threadIdx.x & 63;
    int total = Nn * NH;
    if (gw >= total) return;
    int n = gw / NH, h = gw % NH;
    float v = 0.f, al = 0.f, ar = 0.f;
    if (lane < D) {
        v = Z[(size_t)n * (NH * DP) + h * DP + lane];
        al = A[h * 2 * D + lane];
        ar = A[h * 2 * D + D + lane];
    }
    float sl = v * al, sr = v * ar;
#pragma unroll
    for (int off = 32; off; off >>= 1) {
        sl += __shfl_xor(sl, off);
        sr += __shfl_xor(sr, off);
    }
    if (lane == 0) {
        SL[(size_t)n * NH + h] = sl;
        SR[(size_t)n * NH + h] = sr;
    }
}

// ---------------- aggregation: head-sequential, one wave per (node, head) ----------------
// Z head-major [NH][N][64]; SL/SR head-major [NH][N]. Grid = NH * bph blocks with
// head = blockIdx.x / bph  ->  heads dispatch sequentially, so the instantaneous
// gather working set is ONE 25.6 MB head slice (L3-resident) instead of 102 MB.
// Output node-major: Hout[n*OSTR + h*64 + lane] (next GEMM reads rows).

template <int NH, int OSTR>
__global__ __launch_bounds__(256) void aggregate_kernel(
    const float* __restrict__ Z, const float* __restrict__ SL, const float* __restrict__ SR,
    const int* __restrict__ rowptr, const int* __restrict__ srcp,
    float* __restrict__ Hout, int Nn) {
    int bph = gridDim.x / NH;
    int h = blockIdx.x / bph;
    int n = (blockIdx.x - h * bph) * 4 + (threadIdx.x >> 6);
    int lane = threadIdx.x & 63;
    if (n >= Nn) return;
    int s0 = rowptr[n], s1 = rowptr[n + 1];
    int deg = s1 - s0;
    float* outp = Hout + (size_t)n * OSTR + h * 64 + lane;
    if (deg == 0) {
        *outp = 0.f;
        return;
    }
    const float* SLh = SL + (size_t)h * Nn;
    const float* Zh = Z + (size_t)h * Nn * 64 + lane;
    const float srn = SR[(size_t)h * Nn + n];
    float hacc = 0.f, den = 0.f;

    if (deg <= 64) {
        float e = -INFINITY;
        int sv = 0;
        if (lane < deg) {
            sv = srcp[s0 + lane];
            e = gelu_exact(SLh[sv] + srn);
        }
        float m = e;
#pragma unroll
        for (int off = 32; off; off >>= 1) m = fmaxf(m, __shfl_xor(m, off));
        float ex = (lane < deg) ? __expf(e - m) : 0.f;
        den = ex;
        for (int jj = 0; jj < deg; ++jj) {
            int s = __shfl(sv, jj);
            float b = __shfl(ex, jj);
            hacc = fmaf(b, Zh[(size_t)s * 64], hacc);
        }
    } else {
        float m = -INFINITY;
        for (int base = s0; base < s1; base += 64) {
            int j = base + lane;
            if (j < s1) m = fmaxf(m, gelu_exact(SLh[srcp[j]] + srn));
        }
#pragma unroll
        for (int off = 32; off; off >>= 1) m = fmaxf(m, __shfl_xor(m, off));
        for (int base = s0; base < s1; base += 64) {
            int j = base + lane;
            int sv = 0;
            float ex = 0.f;
            if (j < s1) {
                sv = srcp[j];
                ex = __expf(gelu_exact(SLh[sv] + srn) - m);
            }
            den += ex;
            int cs = min(64, s1 - base);
            for (int jj = 0; jj < cs; ++jj) {
                int s = __shfl(sv, jj);
                float b = __shfl(ex, jj);
                hacc = fmaf(b, Zh[(size_t)s * 64], hacc);
            }
        }
    }
#pragma unroll
    for (int off = 32; off; off >>= 1) den += __shfl_xor(den, off);
    *outp = hacc / den;
}

// ---------------- out-layer aggregation (4 heads, D=7, Z stride 32) ----------------

#define MAX4_REDUCE(m0, m1, m2, m3)                      \
    _Pragma("unroll") for (int off = 32; off; off >>= 1) { \
        m0 = fmaxf(m0, __shfl_xor(m0, off));             \
        m1 = fmaxf(m1, __shfl_xor(m1, off));             \
        m2 = fmaxf(m2, __shfl_xor(m2, off));             \
        m3 = fmaxf(m3, __shfl_xor(m3, off));             \
    }

#define SUM4_REDUCE(d0, d1, d2, d3)                      \
    _Pragma("unroll") for (int off = 32; off; off >>= 1) { \
        d0 += __shfl_xor(d0, off);                       \
        d1 += __shfl_xor(d1, off);                       \
        d2 += __shfl_xor(d2, off);                       \
        d3 += __shfl_xor(d3, off);                       \
    }

__global__ __launch_bounds__(256) void aggregateo_kernel(
    const float* __restrict__ Z, const float* __restrict__ SL, const float* __restrict__ SR,
    const int* __restrict__ rowptr, const int* __restrict__ srcp,
    float* __restrict__ Hout, int Nn) {
    int n = (blockIdx.x * blockDim.x + threadIdx.x) >> 6;
    int lane = threadIdx.x & 63;
    if (n >= Nn) return;
    int s0 = rowptr[n], s1 = rowptr[n + 1];
    int deg = s1 - s0;
    if (deg == 0) {
        if (lane < 32) Hout[(size_t)n * 32 + lane] = 0.f;
        return;
    }
    const float4 sr4 = *(const float4*)(SR + (size_t)n * 4);
    const int h = (lane & 31) >> 3;
    const int eo = lane >> 5;
    float hacc = 0.f;
    float d0 = 0.f, d1 = 0.f, d2 = 0.f, d3 = 0.f;
    const float* zl = Z + (lane & 31);

    if (deg <= 64) {
        float e0 = -INFINITY, e1 = -INFINITY, e2 = -INFINITY, e3 = -INFINITY;
        int sv = 0;
        if (lane < deg) {
            sv = srcp[s0 + lane];
            float4 sl4 = *(const float4*)(SL + (size_t)sv * 4);
            e0 = gelu_exact(sl4.x + sr4.x);
            e1 = gelu_exact(sl4.y + sr4.y);
            e2 = gelu_exact(sl4.z + sr4.z);
            e3 = gelu_exact(sl4.w + sr4.w);
        }
        float m0 = e0, m1 = e1, m2 = e2, m3 = e3;
        MAX4_REDUCE(m0, m1, m2, m3)
        float ex0 = 0.f, ex1 = 0.f, ex2 = 0.f, ex3 = 0.f;
        if (lane < deg) {
            ex0 = __expf(e0 - m0); ex1 = __expf(e1 - m1);
            ex2 = __expf(e2 - m2); ex3 = __expf(e3 - m3);
        }
        d0 = ex0; d1 = ex1; d2 = ex2; d3 = ex3;
        for (int jj = 0; jj < deg; jj += 2) {
            int lsrc = jj + eo;  // lane>=deg has ex=0 -> safe
            int s = __shfl(sv, lsrc);
            float b0 = __shfl(ex0, lsrc), b1 = __shfl(ex1, lsrc);
            float b2 = __shfl(ex2, lsrc), b3 = __shfl(ex3, lsrc);
            float exs = (h == 0) ? b0 : (h == 1) ? b1 : (h == 2) ? b2 : b3;
            hacc = fmaf(exs, zl[(size_t)s * 32], hacc);
        }
    } else {
        float m0 = -INFINITY, m1 = -INFINITY, m2 = -INFINITY, m3 = -INFINITY;
        for (int base = s0; base < s1; base += 64) {
            int j = base + lane;
            if (j < s1) {
                int s = srcp[j];
                float4 sl4 = *(const float4*)(SL + (size_t)s * 4);
                m0 = fmaxf(m0, gelu_exact(sl4.x + sr4.x));
                m1 = fmaxf(m1, gelu_exact(sl4.y + sr4.y));
                m2 = fmaxf(m2, gelu_exact(sl4.z + sr4.z));
                m3 = fmaxf(m3, gelu_exact(sl4.w + sr4.w));
            }
        }
        MAX4_REDUCE(m0, m1, m2, m3)
        for (int base = s0; base < s1; base += 64) {
            int j = base + lane;
            int sv = 0;
            float ex0 = 0.f, ex1 = 0.f, ex2 = 0.f, ex3 = 0.f;
            if (j < s1) {
                sv = srcp[j];
                float4 sl4 = *(const float4*)(SL + (size_t)sv * 4);
                ex0 = __expf(gelu_exact(sl4.x + sr4.x) - m0);
                ex1 = __expf(gelu_exact(sl4.y + sr4.y) - m1);
                ex2 = __expf(gelu_exact(sl4.z + sr4.z) - m2);
                ex3 = __expf(gelu_exact(sl4.w + sr4.w) - m3);
            }
            d0 += ex0; d1 += ex1; d2 += ex2; d3 += ex3;
            int cs = min(64, s1 - base);
            for (int jj = 0; jj < cs; jj += 2) {
                int lsrc = jj + eo;
                int s = __shfl(sv, lsrc);
                float b0 = __shfl(ex0, lsrc), b1 = __shfl(ex1, lsrc);
                float b2 = __shfl(ex2, lsrc), b3 = __shfl(ex3, lsrc);
                float exs = (h == 0) ? b0 : (h == 1) ? b1 : (h == 2) ? b2 : b3;
                hacc = fmaf(exs, zl[(size_t)s * 32], hacc);
            }
        }
    }
    SUM4_REDUCE(d0, d1, d2, d3)
    hacc += __shfl_xor(hacc, 32);  // merge odd-edge partials into lanes 0-31
    float dsel = (h == 0) ? d0 : (h == 1) ? d1 : (h == 2) ? d2 : d3;
    if (lane < 32) Hout[(size_t)n * 32 + lane] = hacc / dsel;
}

// ---------------- mean-over-heads + linear + softmax ----------------

__global__ void finalize_kernel(const float* __restrict__ Hs, const float* __restrict__ LW,
                                const float* __restrict__ LB, float* __restrict__ out, int Nn) {
    int n = blockIdx.x * blockDim.x + threadIdx.x;
    if (n >= Nn) return;
    float mean[7];
#pragma unroll
    for (int k = 0; k < 7; k++)
        mean[k] = 0.25f * (Hs[(size_t)n * 32 + k] + Hs[(size_t)n * 32 + 8 + k] +
                           Hs[(size_t)n * 32 + 16 + k] + Hs[(size_t)n * 32 + 24 + k]);
    float lg[7];
#pragma unroll
    for (int o = 0; o < 7; o++) {
        float acc = LB[o];
#pragma unroll
        for (int k = 0; k < 7; k++) acc = fmaf(mean[k], LW[k * 7 + o], acc);
        lg[o] = acc;
    }
    float mx = lg[0];
#pragma unroll
    for (int o = 1; o < 7; o++) mx = fmaxf(mx, lg[o]);
    float s = 0.f;
#pragma unroll
    for (int o = 0; o < 7; o++) {
        lg[o] = __expf(lg[o] - mx);
        s += lg[o];
    }
    float inv = 1.f / s;
#pragma unroll
    for (int o = 0; o < 7; o++) out[(size_t)n * 7 + o] = lg[o] * inv;
}

// ---------------- launch ----------------

extern "C" void kernel_launch(void* const* d_in, const int* in_sizes, int n_in,
                              void* d_out, int out_size, void* d_ws, size_t ws_size,
                              hipStream_t stream) {
    const float* feature = (const float*)d_in[0];
    const int* src = (const int*)d_in[1];
    const int* dst = (const int*)d_in[2];
    const float* W0 = (const float*)d_in[3];
    const float* b0 = (const float*)d_in[4];
    const float* a0 = (const float*)d_in[5];
    const float* W0h = (const float*)d_in[6];
    const float* b0h = (const float*)d_in[7];
    const float* a0h = (const float*)d_in[8];
    const float* W1 = (const float*)d_in[9];
    const float* b1 = (const float*)d_in[10];
    const float* a1 = (const float*)d_in[11];
    const float* W1h = (const float*)d_in[12];
    const float* b1h = (const float*)d_in[13];
    const float* a1h = (const float*)d_in[14];
    const float* Wo = (const float*)d_in[15];
    const float* bo = (const float*)d_in[16];
    const float* ao = (const float*)d_in[17];
    const float* linW = (const float*)d_in[18];
    const float* linb = (const float*)d_in[19];
    const int N = in_sizes[0] / 64;
    const int E = in_sizes[1];
    float* out = (float*)d_out;

    char* ws = (char*)d_ws;
    size_t off = 0;
    auto alloc = [&](size_t bytes) {
        void* p = ws + off;
        off += (bytes + 255) & ~(size_t)255;
        return p;
    };
    int* cnt = (int*)alloc((size_t)N * 4);
    int* rowptr = (int*)alloc(((size_t)N + 1) * 4);
    int* bsum = (int*)alloc(256 * 4);
    int* eidx = (int*)alloc((size_t)E * 4);
    int* srcp = (int*)alloc((size_t)E * 4);
    float* zbuf = (float*)alloc((size_t)N * 256 * 4);
    float* hbuf = (float*)alloc((size_t)N * 256 * 4);
    float* fbuf = (float*)alloc((size_t)N * 64 * 4);
    float* slb = (float*)alloc((size_t)N * 4 * 4);
    float* srb = (float*)alloc((size_t)N * 4 * 4);
    float* houts = fbuf;  // safe alias: f2 dead after out-GEMM reads it

    // --- CSR by dst (reused by all 5 aggregation stages) ---
    hipMemsetAsync(cnt, 0, (size_t)N * 4, stream);
    hist_kernel<<<2048, 256, 0, stream>>>(dst, cnt, E);
    int nb = (N + 2047) / 2048;
    scan1_kernel<<<nb, 256, 0, stream>>>(cnt, rowptr, bsum, N);
    scan2_kernel<<<1, 32, 0, stream>>>(bsum, rowptr, nb, N);
    scan3_kernel<<<(N + 255) / 256, 256, 0, stream>>>(rowptr, bsum, N);
    hipMemsetAsync(cnt, 0, (size_t)N * 4, stream);
    scatter_kernel<<<2048, 256, 0, stream>>>(dst, rowptr, cnt, eidx, E);
    srcp_kernel<<<(E + 255) / 256, 256, 0, stream>>>(eidx, src, srcp, E);

    int gemm_blocks = (N + 31) / 32;
    int blk4 = (N * HEADS + 3) / 4;
    int blk1 = (N + 3) / 4;
    int bph = (N + 3) / 4;  // aggregate blocks per head

    // --- layer 0 (4 heads, concat) ---
    gemm_kernel<0><<<gemm_blocks, 256, 0, stream>>>(feature, W0, b0, zbuf, N);
    slr_hm_kernel<4><<<blk4, 256, 0, stream>>>(zbuf, a0, slb, srb, N);
    aggregate_kernel<4, 256><<<4 * bph, 256, 0, stream>>>(zbuf, slb, srb, rowptr, srcp, hbuf, N);
    // --- layer 0 head_linear ---
    gemm_kernel<1><<<gemm_blocks, 256, 0, stream>>>(hbuf, W0h, b0h, zbuf, N);
    slr_hm_kernel<1><<<blk1, 256, 0, stream>>>(zbuf, a0h, slb, srb, N);
    aggregate_kernel<1, 64><<<bph, 256, 0, stream>>>(zbuf, slb, srb, rowptr, srcp, fbuf, N);
    // --- layer 1 (4 heads, concat) ---
    gemm_kernel<0><<<gemm_blocks, 256, 0, stream>>>(fbuf, W1, b1, zbuf, N);
    slr_hm_kernel<4><<<blk4, 256, 0, stream>>>(zbuf, a1, slb, srb, N);
    aggregate_kernel<4, 256><<<4 * bph, 256, 0, stream>>>(zbuf, slb, srb, rowptr, srcp, hbuf, N);
    // --- layer 1 head_linear ---
    gemm_kernel<1><<<gemm_blocks, 256, 0, stream>>>(hbuf, W1h, b1h, zbuf, N);
    slr_hm_kernel<1><<<blk1, 256, 0, stream>>>(zbuf, a1h, slb, srb, N);
    aggregate_kernel<1, 64><<<bph, 256, 0, stream>>>(zbuf, slb, srb, rowptr, srcp, fbuf, N);
    // --- out layer (4 heads, mean) ---
    gemm_kernel<2><<<gemm_blocks, 256, 0, stream>>>(fbuf, Wo, bo, zbuf, N);
    slr_kernel<4, 7, 8><<<blk4, 256, 0, stream>>>(zbuf, ao, slb, srb, N);
    aggregateo_kernel<<<bph, 256, 0, stream>>>(zbuf, slb, srb, rowptr, srcp, houts, N);
    finalize_kernel<<<(N + 255) / 256, 256, 0, stream>>>(houts, linW, linb, out, N);
}

// Round 6
// 1344.304 us; speedup vs baseline: 1.5804x; 1.5804x over previous
//
#include <hip/hip_runtime.h>
#include <hip/hip_bf16.h>
#include <math.h>

#define HEADS 4
#define HID 64
#define OUTD 7

__device__ __forceinline__ float gelu_exact(float x) {
    return 0.5f * x * (1.0f + erff(x * 0.70710678118654752f));
}

// broadcast lane k of v to all lanes (SGPR result); k must be wave-uniform
__device__ __forceinline__ float readlane_f(float v, int k) {
    union { float f; int i; } u;
    u.f = v;
    u.i = __builtin_amdgcn_readlane(u.i, k);
    return u.f;
}

// bf16 helpers (RNE pack, exact unpack)
__device__ __forceinline__ unsigned short f2bf(float f) {
    unsigned int x = __float_as_uint(f);
    unsigned int r = (x + 0x7fffu + ((x >> 16) & 1u)) >> 16;
    return (unsigned short)r;
}
__device__ __forceinline__ float bf2f(unsigned short u) {
    return __uint_as_float(((unsigned int)u) << 16);
}

// ---------------- CSR build ----------------

__global__ void hist_kernel(const int* __restrict__ dst, int* __restrict__ cnt, int E) {
    for (int e = blockIdx.x * blockDim.x + threadIdx.x; e < E; e += gridDim.x * blockDim.x)
        atomicAdd(&cnt[dst[e]], 1);
}

__global__ __launch_bounds__(256) void scan1_kernel(const int* __restrict__ cnt,
                                                    int* __restrict__ rowptr,
                                                    int* __restrict__ bsum, int Nn) {
    __shared__ int sums[256];
    int t = threadIdx.x;
    int base = blockIdx.x * 2048 + t * 8;
    int orig[8];
    int run = 0;
#pragma unroll
    for (int i = 0; i < 8; i++) {
        orig[i] = (base + i < Nn) ? cnt[base + i] : 0;
        run += orig[i];
    }
    sums[t] = run;
    __syncthreads();
    for (int off = 1; off < 256; off <<= 1) {
        int y = (t >= off) ? sums[t - off] : 0;
        __syncthreads();
        sums[t] += y;
        __syncthreads();
    }
    int excl = sums[t] - run;
    if (t == 255) bsum[blockIdx.x] = sums[255];
    int e = excl;
#pragma unroll
    for (int i = 0; i < 8; i++) {
        if (base + i < Nn) rowptr[base + i] = e;
        e += orig[i];
    }
}

__global__ void scan2_kernel(int* __restrict__ bsum, int* __restrict__ rowptr, int nb, int Nn) {
    if (blockIdx.x == 0 && threadIdx.x == 0) {
        int run = 0;
        for (int i = 0; i < nb; i++) {
            int t = bsum[i];
            bsum[i] = run;
            run += t;
        }
        rowptr[Nn] = run;
    }
}

__global__ void scan3_kernel(int* __restrict__ rowptr, const int* __restrict__ bsum, int Nn) {
    int i = blockIdx.x * blockDim.x + threadIdx.x;
    if (i < Nn) rowptr[i] += bsum[i >> 11];
}

__global__ void scatter_kernel(const int* __restrict__ dst, const int* __restrict__ rowptr,
                               int* __restrict__ cnt, int* __restrict__ eidx, int E) {
    for (int e = blockIdx.x * blockDim.x + threadIdx.x; e < E; e += gridDim.x * blockDim.x) {
        int d = dst[e];
        int p = rowptr[d] + atomicAdd(&cnt[d], 1);
        eidx[p] = e;
    }
}

// srcp[p] = src[eidx[p]] : CSR-ordered source ids
__global__ void srcp_kernel(const int* __restrict__ eidx, const int* __restrict__ srcv,
                            int* __restrict__ srcp, int E) {
    int p = blockIdx.x * blockDim.x + threadIdx.x;
    if (p < E) srcp[p] = srcv[eidx[p]];
}

// ---------------- GEMM (x-in-registers + readlane broadcast, W in LDS) ----------------
// MODE 0: X[N,64]  @ Wcat + b -> Zb bf16 [N][256] (4 heads interleaved by 64-col blocks)
//         + FUSED slr: SL/SR[n*4+h] (f32, from f32 acc)
// MODE 1: X[N,256] @ W + b   -> Zb bf16 [N][64] + FUSED slr: SL/SR[n] (f32)
// MODE 2: X[N,64]  @ Wo + bo -> Zf f32 [N][32] (8/head, col7=0); slr separate

template <int MODE>
__global__ __launch_bounds__(256, 2) void gemm_kernel(const float* __restrict__ X,
                                                      const float* __restrict__ Wt,
                                                      const float* __restrict__ Bt,
                                                      const float* __restrict__ Aw,
                                                      unsigned short* __restrict__ Zb,
                                                      float* __restrict__ Zf,
                                                      float* __restrict__ SLo,
                                                      float* __restrict__ SRo, int Nn) {
    constexpr int K = (MODE == 1) ? 256 : 64;
    constexpr int M = (MODE == 0) ? 256 : (MODE == 1 ? 64 : 32);
    constexpr int CPL = (MODE == 0) ? 4 : 1;  // cols per lane

    __shared__ float wlds[K * M];

    const int tid = threadIdx.x;
    const int wid = tid >> 6;
    const int lane = tid & 63;
    const int row0 = blockIdx.x * 32 + wid * 8;

    // ---- stage full W panel once ----
    if (MODE == 0) {
#pragma unroll
        for (int it = 0; it < 16; ++it) {
            int flat = it * 1024 + tid * 4;  // k*256 + m
            int k = flat >> 8, m = flat & 255;
            int h = m >> 6, c = m & 63;
            *(float4*)&wlds[flat] = *(const float4*)(Wt + h * 4096 + k * 64 + c);
        }
    } else if (MODE == 1) {
#pragma unroll
        for (int it = 0; it < 16; ++it) {
            int flat = it * 1024 + tid * 4;
            *(float4*)&wlds[flat] = *(const float4*)(Wt + flat);
        }
    } else {
#pragma unroll
        for (int it = 0; it < 8; ++it) {
            int idx = it * 256 + tid;  // k*32 + m
            int k = idx >> 5, m = idx & 31, h = m >> 3, j = m & 7;
            wlds[idx] = (j < 7) ? Wt[h * 448 + k * 7 + j] : 0.f;
        }
    }
    __syncthreads();

    float acc[8][CPL];
#pragma unroll
    for (int r = 0; r < 8; ++r)
#pragma unroll
        for (int c = 0; c < CPL; ++c) acc[r][c] = 0.f;

    if (MODE == 0 || MODE == 2) {
        float xr[8];
#pragma unroll
        for (int r = 0; r < 8; ++r) {
            int rr = row0 + r;
            rr = (rr < Nn) ? rr : (Nn - 1);
            xr[r] = X[(size_t)rr * 64 + lane];
        }
#pragma unroll 4
        for (int k = 0; k < 64; ++k) {
            if (MODE == 0) {
                float4 wv = *(const float4*)&wlds[k * 256 + lane * 4];
#pragma unroll
                for (int r = 0; r < 8; ++r) {
                    float xk = readlane_f(xr[r], k);
                    acc[r][0] = fmaf(xk, wv.x, acc[r][0]);
                    acc[r][1] = fmaf(xk, wv.y, acc[r][1]);
                    acc[r][2] = fmaf(xk, wv.z, acc[r][2]);
                    acc[r][3] = fmaf(xk, wv.w, acc[r][3]);
                }
            } else {
                float wv = wlds[k * 32 + (lane & 31)];
#pragma unroll
                for (int r = 0; r < 8; ++r)
                    acc[r][0] = fmaf(readlane_f(xr[r], k), wv, acc[r][0]);
            }
        }
    } else {
        float xr[8], xn[8];
#pragma unroll
        for (int r = 0; r < 8; ++r) {
            int rr = row0 + r;
            rr = (rr < Nn) ? rr : (Nn - 1);
            xr[r] = X[(size_t)rr * 256 + lane];
        }
        for (int kc = 0; kc < 4; ++kc) {
            if (kc < 3) {
#pragma unroll
                for (int r = 0; r < 8; ++r) {
                    int rr = row0 + r;
                    rr = (rr < Nn) ? rr : (Nn - 1);
                    xn[r] = X[(size_t)rr * 256 + (kc + 1) * 64 + lane];
                }
            }
#pragma unroll 4
            for (int k = 0; k < 64; ++k) {
                float wv = wlds[(kc * 64 + k) * 64 + lane];
#pragma unroll
                for (int r = 0; r < 8; ++r)
                    acc[r][0] = fmaf(readlane_f(xr[r], k), wv, acc[r][0]);
            }
#pragma unroll
            for (int r = 0; r < 8; ++r) xr[r] = xn[r];
        }
    }

    // ---- epilogue (fused bias + bf16 store + slr) ----
    if (MODE == 0) {
        float4 bv = *(const float4*)(Bt + lane * 4);
        const int h = lane >> 4;
        const int c0 = (lane & 15) * 4;  // col within head
        float4 al4 = *(const float4*)(Aw + h * 128 + c0);
        float4 ar4 = *(const float4*)(Aw + h * 128 + 64 + c0);
#pragma unroll
        for (int r = 0; r < 8; ++r) {
            int row = row0 + r;
            float4 s = {acc[r][0] + bv.x, acc[r][1] + bv.y, acc[r][2] + bv.z, acc[r][3] + bv.w};
            float sp = s.x * al4.x + s.y * al4.y + s.z * al4.z + s.w * al4.w;
            float rp = s.x * ar4.x + s.y * ar4.y + s.z * ar4.z + s.w * ar4.w;
#pragma unroll
            for (int o = 1; o < 16; o <<= 1) {
                sp += __shfl_xor(sp, o);
                rp += __shfl_xor(rp, o);
            }
            if (row < Nn) {
                ushort4 pk = {f2bf(s.x), f2bf(s.y), f2bf(s.z), f2bf(s.w)};
                *(ushort4*)(Zb + (size_t)row * 256 + lane * 4) = pk;
                if ((lane & 15) == 0) {
                    SLo[(size_t)row * 4 + h] = sp;
                    SRo[(size_t)row * 4 + h] = rp;
                }
            }
        }
    } else if (MODE == 1) {
        float bvv = Bt[lane];
        float al = Aw[lane], ar = Aw[64 + lane];
#pragma unroll
        for (int r = 0; r < 8; ++r) {
            int row = row0 + r;
            float zv = acc[r][0] + bvv;
            float sp = zv * al, rp = zv * ar;
#pragma unroll
            for (int o = 1; o < 64; o <<= 1) {
                sp += __shfl_xor(sp, o);
                rp += __shfl_xor(rp, o);
            }
            if (row < Nn) {
                Zb[(size_t)row * 64 + lane] = f2bf(zv);
                if (lane == 0) {
                    SLo[row] = sp;
                    SRo[row] = rp;
                }
            }
        }
    } else {
        if (lane < 32) {
            int m = lane, h = m >> 3, j = m & 7;
            float bvv = (j < 7) ? Bt[h * 7 + j] : 0.f;
#pragma unroll
            for (int r = 0; r < 8; ++r) {
                int row = row0 + r;
                if (row < Nn) Zf[(size_t)row * 32 + m] = (j < 7) ? acc[r][0] + bvv : 0.f;
            }
        }
    }
}

// ---------------- slr for out layer (interleaved SL/SR[n*4+h], f32 z) ----------------

template <int NH, int D, int DP>
__global__ __launch_bounds__(256) void slr_kernel(const float* __restrict__ Z,
                                                  const float* __restrict__ A,
                                                  float* __restrict__ SL, float* __restrict__ SR,
                                                  int Nn) {
    int gw = (blockIdx.x * blockDim.x + threadIdx.x) >> 6;
    int lane = threadIdx.x & 63;
    int total = Nn * NH;
    if (gw >= total) return;
    int n = gw / NH, h = gw % NH;
    float v = 0.f, al = 0.f, ar = 0.f;
    if (lane < D) {
        v = Z[(size_t)n * (NH * DP) + h * DP + lane];
        al = A[h * 2 * D + lane];
        ar = A[h * 2 * D + D + lane];
    }
    float sl = v * al, sr = v * ar;
#pragma unroll
    for (int off = 32; off; off >>= 1) {
        sl += __shfl_xor(sl, off);
        sr += __shfl_xor(sr, off);
    }
    if (lane == 0) {
        SL[(size_t)n * NH + h] = sl;
        SR[(size_t)n * NH + h] = sr;
    }
}

// ---------------- aggregation (fused 4-head, bf16 z gather) ----------------

#define MAX4_REDUCE(m0, m1, m2, m3)                      \
    _Pragma("unroll") for (int off = 32; off; off >>= 1) { \
        m0 = fmaxf(m0, __shfl_xor(m0, off));             \
        m1 = fmaxf(m1, __shfl_xor(m1, off));             \
        m2 = fmaxf(m2, __shfl_xor(m2, off));             \
        m3 = fmaxf(m3, __shfl_xor(m3, off));             \
    }

#define SUM4_REDUCE(d0, d1, d2, d3)                      \
    _Pragma("unroll") for (int off = 32; off; off >>= 1) { \
        d0 += __shfl_xor(d0, off);                       \
        d1 += __shfl_xor(d1, off);                       \
        d2 += __shfl_xor(d2, off);                       \
        d3 += __shfl_xor(d3, off);                       \
    }

// 4 heads: Zb [N][256] bf16 (col = h*64 + lane); Hout [N][256] f32
__global__ __launch_bounds__(256) void aggregate4_kernel(
    const unsigned short* __restrict__ Zb, const float* __restrict__ SL,
    const float* __restrict__ SR, const int* __restrict__ rowptr,
    const int* __restrict__ srcp, float* __restrict__ Hout, int Nn) {
    int n = (blockIdx.x * blockDim.x + threadIdx.x) >> 6;
    int lane = threadIdx.x & 63;
    if (n >= Nn) return;
    int s0 = rowptr[n], s1 = rowptr[n + 1];
    int deg = s1 - s0;
    float* houtp = Hout + (size_t)n * 256 + lane;
    if (deg == 0) {
        houtp[0] = 0.f; houtp[64] = 0.f; houtp[128] = 0.f; houtp[192] = 0.f;
        return;
    }
    const float4 sr4 = *(const float4*)(SR + (size_t)n * 4);
    float hx = 0.f, hy = 0.f, hz = 0.f, hw = 0.f;
    float d0 = 0.f, d1 = 0.f, d2 = 0.f, d3 = 0.f;
    const unsigned short* zl = Zb + lane;

    if (deg <= 64) {
        float e0 = -INFINITY, e1 = -INFINITY, e2 = -INFINITY, e3 = -INFINITY;
        int sv = 0;
        if (lane < deg) {
            sv = srcp[s0 + lane];
            float4 sl4 = *(const float4*)(SL + (size_t)sv * 4);
            e0 = gelu_exact(sl4.x + sr4.x);
            e1 = gelu_exact(sl4.y + sr4.y);
            e2 = gelu_exact(sl4.z + sr4.z);
            e3 = gelu_exact(sl4.w + sr4.w);
        }
        float m0 = e0, m1 = e1, m2 = e2, m3 = e3;
        MAX4_REDUCE(m0, m1, m2, m3)
        float ex0 = 0.f, ex1 = 0.f, ex2 = 0.f, ex3 = 0.f;
        if (lane < deg) {
            ex0 = __expf(e0 - m0); ex1 = __expf(e1 - m1);
            ex2 = __expf(e2 - m2); ex3 = __expf(e3 - m3);
        }
        d0 = ex0; d1 = ex1; d2 = ex2; d3 = ex3;
        int jj = 0;
        for (; jj + 1 < deg; jj += 2) {  // 2-edge unroll for MLP
            int sA = __shfl(sv, jj), sB = __shfl(sv, jj + 1);
            float a0 = __shfl(ex0, jj), a1 = __shfl(ex1, jj);
            float a2 = __shfl(ex2, jj), a3 = __shfl(ex3, jj);
            float b0 = __shfl(ex0, jj + 1), b1 = __shfl(ex1, jj + 1);
            float b2 = __shfl(ex2, jj + 1), b3 = __shfl(ex3, jj + 1);
            const unsigned short* zA = zl + (size_t)sA * 256;
            const unsigned short* zB = zl + (size_t)sB * 256;
            hx = fmaf(a0, bf2f(zA[0]), hx);
            hy = fmaf(a1, bf2f(zA[64]), hy);
            hz = fmaf(a2, bf2f(zA[128]), hz);
            hw = fmaf(a3, bf2f(zA[192]), hw);
            hx = fmaf(b0, bf2f(zB[0]), hx);
            hy = fmaf(b1, bf2f(zB[64]), hy);
            hz = fmaf(b2, bf2f(zB[128]), hz);
            hw = fmaf(b3, bf2f(zB[192]), hw);
        }
        if (jj < deg) {
            int s = __shfl(sv, jj);
            float a0 = __shfl(ex0, jj), a1 = __shfl(ex1, jj);
            float a2 = __shfl(ex2, jj), a3 = __shfl(ex3, jj);
            const unsigned short* zp = zl + (size_t)s * 256;
            hx = fmaf(a0, bf2f(zp[0]), hx);
            hy = fmaf(a1, bf2f(zp[64]), hy);
            hz = fmaf(a2, bf2f(zp[128]), hz);
            hw = fmaf(a3, bf2f(zp[192]), hw);
        }
    } else {
        float m0 = -INFINITY, m1 = -INFINITY, m2 = -INFINITY, m3 = -INFINITY;
        for (int base = s0; base < s1; base += 64) {
            int j = base + lane;
            if (j < s1) {
                int s = srcp[j];
                float4 sl4 = *(const float4*)(SL + (size_t)s * 4);
                m0 = fmaxf(m0, gelu_exact(sl4.x + sr4.x));
                m1 = fmaxf(m1, gelu_exact(sl4.y + sr4.y));
                m2 = fmaxf(m2, gelu_exact(sl4.z + sr4.z));
                m3 = fmaxf(m3, gelu_exact(sl4.w + sr4.w));
            }
        }
        MAX4_REDUCE(m0, m1, m2, m3)
        for (int base = s0; base < s1; base += 64) {
            int j = base + lane;
            int sv = 0;
            float ex0 = 0.f, ex1 = 0.f, ex2 = 0.f, ex3 = 0.f;
            if (j < s1) {
                sv = srcp[j];
                float4 sl4 = *(const float4*)(SL + (size_t)sv * 4);
                ex0 = __expf(gelu_exact(sl4.x + sr4.x) - m0);
                ex1 = __expf(gelu_exact(sl4.y + sr4.y) - m1);
                ex2 = __expf(gelu_exact(sl4.z + sr4.z) - m2);
                ex3 = __expf(gelu_exact(sl4.w + sr4.w) - m3);
            }
            d0 += ex0; d1 += ex1; d2 += ex2; d3 += ex3;
            int cs = min(64, s1 - base);
            for (int jj = 0; jj < cs; ++jj) {
                int s = __shfl(sv, jj);
                float a0 = __shfl(ex0, jj), a1 = __shfl(ex1, jj);
                float a2 = __shfl(ex2, jj), a3 = __shfl(ex3, jj);
                const unsigned short* zp = zl + (size_t)s * 256;
                hx = fmaf(a0, bf2f(zp[0]), hx);
                hy = fmaf(a1, bf2f(zp[64]), hy);
                hz = fmaf(a2, bf2f(zp[128]), hz);
                hw = fmaf(a3, bf2f(zp[192]), hw);
            }
        }
    }
    SUM4_REDUCE(d0, d1, d2, d3)
    houtp[0] = hx / d0;
    houtp[64] = hy / d1;
    houtp[128] = hz / d2;
    houtp[192] = hw / d3;
}

// 1 head: Zb [N][64] bf16
__global__ __launch_bounds__(256) void aggregate1_kernel(
    const unsigned short* __restrict__ Zb, const float* __restrict__ SL,
    const float* __restrict__ SR, const int* __restrict__ rowptr,
    const int* __restrict__ srcp, float* __restrict__ Hout, int Nn) {
    int n = (blockIdx.x * blockDim.x + threadIdx.x) >> 6;
    int lane = threadIdx.x & 63;
    if (n >= Nn) return;
    int s0 = rowptr[n], s1 = rowptr[n + 1];
    int deg = s1 - s0;
    if (deg == 0) {
        Hout[(size_t)n * 64 + lane] = 0.f;
        return;
    }
    const float srn = SR[n];
    float hacc = 0.f, den = 0.f;
    const unsigned short* zl = Zb + lane;

    if (deg <= 64) {
        float e = -INFINITY;
        int sv = 0;
        if (lane < deg) {
            sv = srcp[s0 + lane];
            e = gelu_exact(SL[sv] + srn);
        }
        float m = e;
#pragma unroll
        for (int off = 32; off; off >>= 1) m = fmaxf(m, __shfl_xor(m, off));
        float ex = (lane < deg) ? __expf(e - m) : 0.f;
        den = ex;
        int jj = 0;
        for (; jj + 1 < deg; jj += 2) {
            int sA = __shfl(sv, jj), sB = __shfl(sv, jj + 1);
            float bA = __shfl(ex, jj), bB = __shfl(ex, jj + 1);
            hacc = fmaf(bA, bf2f(zl[(size_t)sA * 64]), hacc);
            hacc = fmaf(bB, bf2f(zl[(size_t)sB * 64]), hacc);
        }
        if (jj < deg) {
            int s = __shfl(sv, jj);
            float b = __shfl(ex, jj);
            hacc = fmaf(b, bf2f(zl[(size_t)s * 64]), hacc);
        }
    } else {
        float m = -INFINITY;
        for (int base = s0; base < s1; base += 64) {
            int j = base + lane;
            if (j < s1) m = fmaxf(m, gelu_exact(SL[srcp[j]] + srn));
        }
#pragma unroll
        for (int off = 32; off; off >>= 1) m = fmaxf(m, __shfl_xor(m, off));
        for (int base = s0; base < s1; base += 64) {
            int j = base + lane;
            int sv = 0;
            float ex = 0.f;
            if (j < s1) {
                sv = srcp[j];
                ex = __expf(gelu_exact(SL[sv] + srn) - m);
            }
            den += ex;
            int cs = min(64, s1 - base);
            for (int jj = 0; jj < cs; ++jj) {
                int s = __shfl(sv, jj);
                float b = __shfl(ex, jj);
                hacc = fmaf(b, bf2f(zl[(size_t)s * 64]), hacc);
            }
        }
    }
#pragma unroll
    for (int off = 32; off; off >>= 1) den += __shfl_xor(den, off);
    Hout[(size_t)n * 64 + lane] = hacc / den;
}

// out layer: 4 heads, D=7 (padded 8), Zf f32 stride 32
__global__ __launch_bounds__(256) void aggregateo_kernel(
    const float* __restrict__ Z, const float* __restrict__ SL, const float* __restrict__ SR,
    const int* __restrict__ rowptr, const int* __restrict__ srcp,
    float* __restrict__ Hout, int Nn) {
    int n = (blockIdx.x * blockDim.x + threadIdx.x) >> 6;
    int lane = threadIdx.x & 63;
    if (n >= Nn) return;
    int s0 = rowptr[n], s1 = rowptr[n + 1];
    int deg = s1 - s0;
    if (deg == 0) {
        if (lane < 32) Hout[(size_t)n * 32 + lane] = 0.f;
        return;
    }
    const float4 sr4 = *(const float4*)(SR + (size_t)n * 4);
    const int h = (lane & 31) >> 3;
    const int eo = lane >> 5;
    float hacc = 0.f;
    float d0 = 0.f, d1 = 0.f, d2 = 0.f, d3 = 0.f;
    const float* zl = Z + (lane & 31);

    if (deg <= 64) {
        float e0 = -INFINITY, e1 = -INFINITY, e2 = -INFINITY, e3 = -INFINITY;
        int sv = 0;
        if (lane < deg) {
            sv = srcp[s0 + lane];
            float4 sl4 = *(const float4*)(SL + (size_t)sv * 4);
            e0 = gelu_exact(sl4.x + sr4.x);
            e1 = gelu_exact(sl4.y + sr4.y);
            e2 = gelu_exact(sl4.z + sr4.z);
            e3 = gelu_exact(sl4.w + sr4.w);
        }
        float m0 = e0, m1 = e1, m2 = e2, m3 = e3;
        MAX4_REDUCE(m0, m1, m2, m3)
        float ex0 = 0.f, ex1 = 0.f, ex2 = 0.f, ex3 = 0.f;
        if (lane < deg) {
            ex0 = __expf(e0 - m0); ex1 = __expf(e1 - m1);
            ex2 = __expf(e2 - m2); ex3 = __expf(e3 - m3);
        }
        d0 = ex0; d1 = ex1; d2 = ex2; d3 = ex3;
        for (int jj = 0; jj < deg; jj += 2) {
            int lsrc = jj + eo;  // lane>=deg has ex=0 -> safe
            int s = __shfl(sv, lsrc);
            float b0 = __shfl(ex0, lsrc), b1 = __shfl(ex1, lsrc);
            float b2 = __shfl(ex2, lsrc), b3 = __shfl(ex3, lsrc);
            float exs = (h == 0) ? b0 : (h == 1) ? b1 : (h == 2) ? b2 : b3;
            hacc = fmaf(exs, zl[(size_t)s * 32], hacc);
        }
    } else {
        float m0 = -INFINITY, m1 = -INFINITY, m2 = -INFINITY, m3 = -INFINITY;
        for (int base = s0; base < s1; base += 64) {
            int j = base + lane;
            if (j < s1) {
                int s = srcp[j];
                float4 sl4 = *(const float4*)(SL + (size_t)s * 4);
                m0 = fmaxf(m0, gelu_exact(sl4.x + sr4.x));
                m1 = fmaxf(m1, gelu_exact(sl4.y + sr4.y));
                m2 = fmaxf(m2, gelu_exact(sl4.z + sr4.z));
                m3 = fmaxf(m3, gelu_exact(sl4.w + sr4.w));
            }
        }
        MAX4_REDUCE(m0, m1, m2, m3)
        for (int base = s0; base < s1; base += 64) {
            int j = base + lane;
            int sv = 0;
            float ex0 = 0.f, ex1 = 0.f, ex2 = 0.f, ex3 = 0.f;
            if (j < s1) {
                sv = srcp[j];
                float4 sl4 = *(const float4*)(SL + (size_t)sv * 4);
                ex0 = __expf(gelu_exact(sl4.x + sr4.x) - m0);
                ex1 = __expf(gelu_exact(sl4.y + sr4.y) - m1);
                ex2 = __expf(gelu_exact(sl4.z + sr4.z) - m2);
                ex3 = __expf(gelu_exact(sl4.w + sr4.w) - m3);
            }
            d0 += ex0; d1 += ex1; d2 += ex2; d3 += ex3;
            int cs = min(64, s1 - base);
            for (int jj = 0; jj < cs; jj += 2) {
                int lsrc = jj + eo;
                int s = __shfl(sv, lsrc);
                float b0 = __shfl(ex0, lsrc), b1 = __shfl(ex1, lsrc);
                float b2 = __shfl(ex2, lsrc), b3 = __shfl(ex3, lsrc);
                float exs = (h == 0) ? b0 : (h == 1) ? b1 : (h == 2) ? b2 : b3;
                hacc = fmaf(exs, zl[(size_t)s * 32], hacc);
            }
        }
    }
    SUM4_REDUCE(d0, d1, d2, d3)
    hacc += __shfl_xor(hacc, 32);
    float dsel = (h == 0) ? d0 : (h == 1) ? d1 : (h == 2) ? d2 : d3;
    if (lane < 32) Hout[(size_t)n * 32 + lane] = hacc / dsel;
}

// ---------------- mean-over-heads + linear + softmax ----------------

__global__ void finalize_kernel(const float* __restrict__ Hs, const float* __restrict__ LW,
                                const float* __restrict__ LB, float* __restrict__ out, int Nn) {
    int n = blockIdx.x * blockDim.x + threadIdx.x;
    if (n >= Nn) return;
    float mean[7];
#pragma unroll
    for (int k = 0; k < 7; k++)
        mean[k] = 0.25f * (Hs[(size_t)n * 32 + k] + Hs[(size_t)n * 32 + 8 + k] +
                           Hs[(size_t)n * 32 + 16 + k] + Hs[(size_t)n * 32 + 24 + k]);
    float lg[7];
#pragma unroll
    for (int o = 0; o < 7; o++) {
        float acc = LB[o];
#pragma unroll
        for (int k = 0; k < 7; k++) acc = fmaf(mean[k], LW[k * 7 + o], acc);
        lg[o] = acc;
    }
    float mx = lg[0];
#pragma unroll
    for (int o = 1; o < 7; o++) mx = fmaxf(mx, lg[o]);
    float s = 0.f;
#pragma unroll
    for (int o = 0; o < 7; o++) {
        lg[o] = __expf(lg[o] - mx);
        s += lg[o];
    }
    float inv = 1.f / s;
#pragma unroll
    for (int o = 0; o < 7; o++) out[(size_t)n * 7 + o] = lg[o] * inv;
}

// ---------------- launch ----------------

extern "C" void kernel_launch(void* const* d_in, const int* in_sizes, int n_in,
                              void* d_out, int out_size, void* d_ws, size_t ws_size,
                              hipStream_t stream) {
    const float* feature = (const float*)d_in[0];
    const int* src = (const int*)d_in[1];
    const int* dst = (const int*)d_in[2];
    const float* W0 = (const float*)d_in[3];
    const float* b0 = (const float*)d_in[4];
    const float* a0 = (const float*)d_in[5];
    const float* W0h = (const float*)d_in[6];
    const float* b0h = (const float*)d_in[7];
    const float* a0h = (const float*)d_in[8];
    const float* W1 = (const float*)d_in[9];
    const float* b1 = (const float*)d_in[10];
    const float* a1 = (const float*)d_in[11];
    const float* W1h = (const float*)d_in[12];
    const float* b1h = (const float*)d_in[13];
    const float* a1h = (const float*)d_in[14];
    const float* Wo = (const float*)d_in[15];
    const float* bo = (const float*)d_in[16];
    const float* ao = (const float*)d_in[17];
    const float* linW = (const float*)d_in[18];
    const float* linb = (const float*)d_in[19];
    const int N = in_sizes[0] / 64;
    const int E = in_sizes[1];
    float* out = (float*)d_out;

    char* ws = (char*)d_ws;
    size_t off = 0;
    auto alloc = [&](size_t bytes) {
        void* p = ws + off;
        off += (bytes + 255) & ~(size_t)255;
        return p;
    };
    int* cnt = (int*)alloc((size_t)N * 4);
    int* rowptr = (int*)alloc(((size_t)N + 1) * 4);
    int* bsum = (int*)alloc(256 * 4);
    int* eidx = (int*)alloc((size_t)E * 4);
    int* srcp = (int*)alloc((size_t)E * 4);
    unsigned short* zbf = (unsigned short*)alloc((size_t)N * 256 * 2);  // bf16 z (modes 0/1)
    float* zo = (float*)alloc((size_t)N * 32 * 4);                      // f32 z (mode 2)
    float* hbuf = (float*)alloc((size_t)N * 256 * 4);
    float* fbuf = (float*)alloc((size_t)N * 64 * 4);
    float* slb = (float*)alloc((size_t)N * 4 * 4);
    float* srb = (float*)alloc((size_t)N * 4 * 4);
    float* houts = fbuf;  // safe alias: f2 dead after out-GEMM reads it

    // --- CSR by dst (reused by all 5 aggregation stages) ---
    hipMemsetAsync(cnt, 0, (size_t)N * 4, stream);
    hist_kernel<<<2048, 256, 0, stream>>>(dst, cnt, E);
    int nb = (N + 2047) / 2048;
    scan1_kernel<<<nb, 256, 0, stream>>>(cnt, rowptr, bsum, N);
    scan2_kernel<<<1, 32, 0, stream>>>(bsum, rowptr, nb, N);
    scan3_kernel<<<(N + 255) / 256, 256, 0, stream>>>(rowptr, bsum, N);
    hipMemsetAsync(cnt, 0, (size_t)N * 4, stream);
    scatter_kernel<<<2048, 256, 0, stream>>>(dst, rowptr, cnt, eidx, E);
    srcp_kernel<<<(E + 255) / 256, 256, 0, stream>>>(eidx, src, srcp, E);

    int gemm_blocks = (N + 31) / 32;
    int blk4 = (N * HEADS + 3) / 4;
    int ablk = (N + 3) / 4;  // one wave per node

    // --- layer 0 (4 heads, concat) ---
    gemm_kernel<0><<<gemm_blocks, 256, 0, stream>>>(feature, W0, b0, a0, zbf, nullptr, slb, srb, N);
    aggregate4_kernel<<<ablk, 256, 0, stream>>>(zbf, slb, srb, rowptr, srcp, hbuf, N);
    // --- layer 0 head_linear ---
    gemm_kernel<1><<<gemm_blocks, 256, 0, stream>>>(hbuf, W0h, b0h, a0h, zbf, nullptr, slb, srb, N);
    aggregate1_kernel<<<ablk, 256, 0, stream>>>(zbf, slb, srb, rowptr, srcp, fbuf, N);
    // --- layer 1 (4 heads, concat) ---
    gemm_kernel<0><<<gemm_blocks, 256, 0, stream>>>(fbuf, W1, b1, a1, zbf, nullptr, slb, srb, N);
    aggregate4_kernel<<<ablk, 256, 0, stream>>>(zbf, slb, srb, rowptr, srcp, hbuf, N);
    // --- layer 1 head_linear ---
    gemm_kernel<1><<<gemm_blocks, 256, 0, stream>>>(hbuf, W1h, b1h, a1h, zbf, nullptr, slb, srb, N);
    aggregate1_kernel<<<ablk, 256, 0, stream>>>(zbf, slb, srb, rowptr, srcp, fbuf, N);
    // --- out layer (4 heads, mean) ---
    gemm_kernel<2><<<gemm_blocks, 256, 0, stream>>>(fbuf, Wo, bo, nullptr, nullptr, zo, nullptr, nullptr, N);
    slr_kernel<4, 7, 8><<<blk4, 256, 0, stream>>>(zo, ao, slb, srb, N);
    aggregateo_kernel<<<ablk, 256, 0, stream>>>(zo, slb, srb, rowptr, srcp, houts, N);
    finalize_kernel<<<(N + 255) / 256, 256, 0, stream>>>(houts, linW, linb, out, N);
}

// Round 8
// 1255.801 us; speedup vs baseline: 1.6918x; 1.0705x over previous
//
#include <hip/hip_runtime.h>
#include <hip/hip_bf16.h>
#include <math.h>

#define HEADS 4
#define HID 64
#define OUTD 7

__device__ __forceinline__ float gelu_exact(float x) {
    return 0.5f * x * (1.0f + erff(x * 0.70710678118654752f));
}

// broadcast lane k of v to all lanes (SGPR result); k must be wave-uniform
__device__ __forceinline__ float readlane_f(float v, int k) {
    union { float f; int i; } u;
    u.f = v;
    u.i = __builtin_amdgcn_readlane(u.i, k);
    return u.f;
}

// bf16 helpers (RNE pack; unpack via bit ops)
__device__ __forceinline__ unsigned int f2bf(float f) {
    unsigned int x = __float_as_uint(f);
    return (x + 0x7fffu + ((x >> 16) & 1u)) >> 16;
}
__device__ __forceinline__ float bf_lo(unsigned int v) {  // low ushort -> float
    return __uint_as_float(v << 16);
}
__device__ __forceinline__ float bf_hi(unsigned int v) {  // high ushort -> float
    return __uint_as_float(v & 0xffff0000u);
}

// ---------------- CSR build ----------------

__global__ void hist_kernel(const int* __restrict__ dst, int* __restrict__ cnt, int E) {
    for (int e = blockIdx.x * blockDim.x + threadIdx.x; e < E; e += gridDim.x * blockDim.x)
        atomicAdd(&cnt[dst[e]], 1);
}

__global__ __launch_bounds__(256) void scan1_kernel(const int* __restrict__ cnt,
                                                    int* __restrict__ rowptr,
                                                    int* __restrict__ bsum, int Nn) {
    __shared__ int sums[256];
    int t = threadIdx.x;
    int base = blockIdx.x * 2048 + t * 8;
    int orig[8];
    int run = 0;
#pragma unroll
    for (int i = 0; i < 8; i++) {
        orig[i] = (base + i < Nn) ? cnt[base + i] : 0;
        run += orig[i];
    }
    sums[t] = run;
    __syncthreads();
    for (int off = 1; off < 256; off <<= 1) {
        int y = (t >= off) ? sums[t - off] : 0;
        __syncthreads();
        sums[t] += y;
        __syncthreads();
    }
    int excl = sums[t] - run;
    if (t == 255) bsum[blockIdx.x] = sums[255];
    int e = excl;
#pragma unroll
    for (int i = 0; i < 8; i++) {
        if (base + i < Nn) rowptr[base + i] = e;
        e += orig[i];
    }
}

__global__ void scan2_kernel(int* __restrict__ bsum, int* __restrict__ rowptr, int nb, int Nn) {
    if (blockIdx.x == 0 && threadIdx.x == 0) {
        int run = 0;
        for (int i = 0; i < nb; i++) {
            int t = bsum[i];
            bsum[i] = run;
            run += t;
        }
        rowptr[Nn] = run;
    }
}

__global__ void scan3_kernel(int* __restrict__ rowptr, const int* __restrict__ bsum, int Nn) {
    int i = blockIdx.x * blockDim.x + threadIdx.x;
    if (i < Nn) rowptr[i] += bsum[i >> 11];
}

// scatter + srcp fused: srcp[p] = src[e] (eidx eliminated)
__global__ void scatter_kernel(const int* __restrict__ dst, const int* __restrict__ rowptr,
                               int* __restrict__ cnt, const int* __restrict__ srcv,
                               int* __restrict__ srcp, int E) {
    for (int e = blockIdx.x * blockDim.x + threadIdx.x; e < E; e += gridDim.x * blockDim.x) {
        int d = dst[e];
        int p = rowptr[d] + atomicAdd(&cnt[d], 1);
        srcp[p] = srcv[e];
    }
}

// ---------------- GEMM (x-in-registers + readlane broadcast, W in LDS) ----------------
// MODE 0: X[N,64]  @ Wcat + b -> Zb bf16 [N][64][4] HEAD-FASTEST (ushort4/col gather)
//         + FUSED slr: SL/SR[n*4+h]
// MODE 1: X[N,256] @ W + b   -> Zb bf16 [N][64] + FUSED slr: SL/SR[n]
// MODE 2: X[N,64]  @ Wo + bo -> Zf f32 [N][32] (8/head, col7=0) + FUSED slr (interleaved)

template <int MODE>
__global__ __launch_bounds__(256, 2) void gemm_kernel(const float* __restrict__ X,
                                                      const float* __restrict__ Wt,
                                                      const float* __restrict__ Bt,
                                                      const float* __restrict__ Aw,
                                                      unsigned short* __restrict__ Zb,
                                                      float* __restrict__ Zf,
                                                      float* __restrict__ SLo,
                                                      float* __restrict__ SRo, int Nn) {
    constexpr int K = (MODE == 1) ? 256 : 64;
    constexpr int M = (MODE == 0) ? 256 : (MODE == 1 ? 64 : 32);
    constexpr int CPL = (MODE == 0) ? 4 : 1;  // cols per lane

    __shared__ float wlds[K * M];

    const int tid = threadIdx.x;
    const int wid = tid >> 6;
    const int lane = tid & 63;
    const int row0 = blockIdx.x * 32 + wid * 8;

    // ---- stage full W panel once ----
    if (MODE == 0) {
#pragma unroll
        for (int it = 0; it < 16; ++it) {
            int flat = it * 1024 + tid * 4;  // k*256 + m
            int k = flat >> 8, m = flat & 255;
            int h = m >> 6, c = m & 63;
            *(float4*)&wlds[flat] = *(const float4*)(Wt + h * 4096 + k * 64 + c);
        }
    } else if (MODE == 1) {
#pragma unroll
        for (int it = 0; it < 16; ++it) {
            int flat = it * 1024 + tid * 4;
            *(float4*)&wlds[flat] = *(const float4*)(Wt + flat);
        }
    } else {
#pragma unroll
        for (int it = 0; it < 8; ++it) {
            int idx = it * 256 + tid;  // k*32 + m
            int k = idx >> 5, m = idx & 31, h = m >> 3, j = m & 7;
            wlds[idx] = (j < 7) ? Wt[h * 448 + k * 7 + j] : 0.f;
        }
    }
    __syncthreads();

    float acc[8][CPL];
#pragma unroll
    for (int r = 0; r < 8; ++r)
#pragma unroll
        for (int c = 0; c < CPL; ++c) acc[r][c] = 0.f;

    if (MODE == 0 || MODE == 2) {
        float xr[8];
#pragma unroll
        for (int r = 0; r < 8; ++r) {
            int rr = row0 + r;
            rr = (rr < Nn) ? rr : (Nn - 1);
            xr[r] = X[(size_t)rr * 64 + lane];
        }
#pragma unroll 4
        for (int k = 0; k < 64; ++k) {
            if (MODE == 0) {
                float4 wv = *(const float4*)&wlds[k * 256 + lane * 4];
#pragma unroll
                for (int r = 0; r < 8; ++r) {
                    float xk = readlane_f(xr[r], k);
                    acc[r][0] = fmaf(xk, wv.x, acc[r][0]);
                    acc[r][1] = fmaf(xk, wv.y, acc[r][1]);
                    acc[r][2] = fmaf(xk, wv.z, acc[r][2]);
                    acc[r][3] = fmaf(xk, wv.w, acc[r][3]);
                }
            } else {
                float wv = wlds[k * 32 + (lane & 31)];
#pragma unroll
                for (int r = 0; r < 8; ++r)
                    acc[r][0] = fmaf(readlane_f(xr[r], k), wv, acc[r][0]);
            }
        }
    } else {
        float xr[8], xn[8];
#pragma unroll
        for (int r = 0; r < 8; ++r) {
            int rr = row0 + r;
            rr = (rr < Nn) ? rr : (Nn - 1);
            xr[r] = X[(size_t)rr * 256 + lane];
        }
        for (int kc = 0; kc < 4; ++kc) {
            if (kc < 3) {
#pragma unroll
                for (int r = 0; r < 8; ++r) {
                    int rr = row0 + r;
                    rr = (rr < Nn) ? rr : (Nn - 1);
                    xn[r] = X[(size_t)rr * 256 + (kc + 1) * 64 + lane];
                }
            }
#pragma unroll 4
            for (int k = 0; k < 64; ++k) {
                float wv = wlds[(kc * 64 + k) * 64 + lane];
#pragma unroll
                for (int r = 0; r < 8; ++r)
                    acc[r][0] = fmaf(readlane_f(xr[r], k), wv, acc[r][0]);
            }
#pragma unroll
            for (int r = 0; r < 8; ++r) xr[r] = xn[r];
        }
    }

    // ---- epilogue ----
    if (MODE == 0) {
        // lane owns head h=lane>>4, cols c0..c0+3; slr 16-lane reduce; then 4x4
        // lane-transpose so lane t stores col t, heads 0..3 as ushort4 (8B coalesced).
        float4 bv = *(const float4*)(Bt + lane * 4);
        const int h = lane >> 4;
        const int c0 = (lane & 15) * 4;
        float4 al4 = *(const float4*)(Aw + h * 128 + c0);
        float4 ar4 = *(const float4*)(Aw + h * 128 + 64 + c0);
        const int t = lane;
        const int lsbase = t >> 2;  // source lane = h2*16 + lsbase
#pragma unroll
        for (int r = 0; r < 8; ++r) {
            int row = row0 + r;
            float4 s = {acc[r][0] + bv.x, acc[r][1] + bv.y, acc[r][2] + bv.z, acc[r][3] + bv.w};
            float sp = s.x * al4.x + s.y * al4.y + s.z * al4.z + s.w * al4.w;
            float rp = s.x * ar4.x + s.y * ar4.y + s.z * ar4.z + s.w * ar4.w;
#pragma unroll
            for (int o = 1; o < 16; o <<= 1) {
                sp += __shfl_xor(sp, o);
                rp += __shfl_xor(rp, o);
            }
            unsigned int lo = f2bf(s.x) | (f2bf(s.y) << 16);
            unsigned int hi = f2bf(s.z) | (f2bf(s.w) << 16);
            unsigned int us[4];
#pragma unroll
            for (int h2 = 0; h2 < 4; ++h2) {
                int ls = (h2 << 4) | lsbase;
                unsigned int vlo = (unsigned int)__shfl((int)lo, ls);
                unsigned int vhi = (unsigned int)__shfl((int)hi, ls);
                unsigned int v = (t & 2) ? vhi : vlo;
                us[h2] = (t & 1) ? (v >> 16) : (v & 0xffffu);
            }
            if (row < Nn) {
                uint2 pk = {us[0] | (us[1] << 16), us[2] | (us[3] << 16)};
                *(uint2*)(Zb + (size_t)row * 256 + t * 4) = pk;
                if ((lane & 15) == 0) {
                    SLo[(size_t)row * 4 + h] = sp;
                    SRo[(size_t)row * 4 + h] = rp;
                }
            }
        }
    } else if (MODE == 1) {
        float bvv = Bt[lane];
        float al = Aw[lane], ar = Aw[64 + lane];
#pragma unroll
        for (int r = 0; r < 8; ++r) {
            int row = row0 + r;
            float zv = acc[r][0] + bvv;
            float sp = zv * al, rp = zv * ar;
#pragma unroll
            for (int o = 1; o < 64; o <<= 1) {
                sp += __shfl_xor(sp, o);
                rp += __shfl_xor(rp, o);
            }
            if (row < Nn) {
                Zb[(size_t)row * 64 + lane] = (unsigned short)f2bf(zv);
                if (lane == 0) {
                    SLo[row] = sp;
                    SRo[row] = rp;
                }
            }
        }
    } else {
        // MODE 2 + fused slr (interleaved SL/SR[n*4+h]); lanes<32 active
        if (lane < 32) {
            int m = lane, h = m >> 3, j = m & 7;
            float bvv = (j < 7) ? Bt[h * 7 + j] : 0.f;
            float al = (j < 7) ? Aw[h * 14 + j] : 0.f;
            float ar = (j < 7) ? Aw[h * 14 + 7 + j] : 0.f;
#pragma unroll
            for (int r = 0; r < 8; ++r) {
                int row = row0 + r;
                float zv = (j < 7) ? acc[r][0] + bvv : 0.f;
                float sp = zv * al, rp = zv * ar;
#pragma unroll
                for (int o = 1; o < 8; o <<= 1) {
                    sp += __shfl_xor(sp, o);
                    rp += __shfl_xor(rp, o);
                }
                if (row < Nn) {
                    Zf[(size_t)row * 32 + m] = zv;
                    if (j == 0) {
                        SLo[(size_t)row * 4 + h] = sp;
                        SRo[(size_t)row * 4 + h] = rp;
                    }
                }
            }
        }
    }
}

// ---------------- aggregation (fused 4-head, head-fastest bf16 z) ----------------

#define MAX4_REDUCE(m0, m1, m2, m3)                      \
    _Pragma("unroll") for (int off = 32; off; off >>= 1) { \
        m0 = fmaxf(m0, __shfl_xor(m0, off));             \
        m1 = fmaxf(m1, __shfl_xor(m1, off));             \
        m2 = fmaxf(m2, __shfl_xor(m2, off));             \
        m3 = fmaxf(m3, __shfl_xor(m3, off));             \
    }

#define SUM4_REDUCE(d0, d1, d2, d3)                      \
    _Pragma("unroll") for (int off = 32; off; off >>= 1) { \
        d0 += __shfl_xor(d0, off);                       \
        d1 += __shfl_xor(d1, off);                       \
        d2 += __shfl_xor(d2, off);                       \
        d3 += __shfl_xor(d3, off);                       \
    }

// 4 heads: Zb [N][64][4] bf16 head-fastest; Hout [N][256] f32 concat layout
__global__ __launch_bounds__(256) void aggregate4_kernel(
    const unsigned short* __restrict__ Zb, const float* __restrict__ SL,
    const float* __restrict__ SR, const int* __restrict__ rowptr,
    const int* __restrict__ srcp, float* __restrict__ Hout, int Nn) {
    int n = (blockIdx.x * blockDim.x + threadIdx.x) >> 6;
    int lane = threadIdx.x & 63;
    if (n >= Nn) return;
    int s0 = rowptr[n], s1 = rowptr[n + 1];
    int deg = s1 - s0;
    float* houtp = Hout + (size_t)n * 256 + lane;
    if (deg == 0) {
        houtp[0] = 0.f; houtp[64] = 0.f; houtp[128] = 0.f; houtp[192] = 0.f;
        return;
    }
    const float4 sr4 = *(const float4*)(SR + (size_t)n * 4);
    float hx = 0.f, hy = 0.f, hz = 0.f, hw = 0.f;
    float d0 = 0.f, d1 = 0.f, d2 = 0.f, d3 = 0.f;
    const uint2* zl = (const uint2*)(Zb + lane * 4);  // + s*64 uint2 per row

#define AGG4_EDGE(JJ)                                                        \
    {                                                                        \
        int s = __shfl(sv, (JJ));                                            \
        float a0 = __shfl(ex0, (JJ)), a1 = __shfl(ex1, (JJ));                \
        float a2 = __shfl(ex2, (JJ)), a3 = __shfl(ex3, (JJ));                \
        uint2 q = zl[(size_t)s * 64];                                        \
        hx = fmaf(a0, bf_lo(q.x), hx);                                       \
        hy = fmaf(a1, bf_hi(q.x), hy);                                       \
        hz = fmaf(a2, bf_lo(q.y), hz);                                       \
        hw = fmaf(a3, bf_hi(q.y), hw);                                       \
    }

    if (deg <= 64) {
        float e0 = -INFINITY, e1 = -INFINITY, e2 = -INFINITY, e3 = -INFINITY;
        int sv = 0;
        if (lane < deg) {
            sv = srcp[s0 + lane];
            float4 sl4 = *(const float4*)(SL + (size_t)sv * 4);
            e0 = gelu_exact(sl4.x + sr4.x);
            e1 = gelu_exact(sl4.y + sr4.y);
            e2 = gelu_exact(sl4.z + sr4.z);
            e3 = gelu_exact(sl4.w + sr4.w);
        }
        float m0 = e0, m1 = e1, m2 = e2, m3 = e3;
        MAX4_REDUCE(m0, m1, m2, m3)
        float ex0 = 0.f, ex1 = 0.f, ex2 = 0.f, ex3 = 0.f;
        if (lane < deg) {
            ex0 = __expf(e0 - m0); ex1 = __expf(e1 - m1);
            ex2 = __expf(e2 - m2); ex3 = __expf(e3 - m3);
        }
        d0 = ex0; d1 = ex1; d2 = ex2; d3 = ex3;
        int jj = 0;
        for (; jj + 3 < deg; jj += 4) {
            AGG4_EDGE(jj)
            AGG4_EDGE(jj + 1)
            AGG4_EDGE(jj + 2)
            AGG4_EDGE(jj + 3)
        }
        for (; jj < deg; ++jj) AGG4_EDGE(jj)
    } else {
        float m0 = -INFINITY, m1 = -INFINITY, m2 = -INFINITY, m3 = -INFINITY;
        for (int base = s0; base < s1; base += 64) {
            int j = base + lane;
            if (j < s1) {
                int s = srcp[j];
                float4 sl4 = *(const float4*)(SL + (size_t)s * 4);
                m0 = fmaxf(m0, gelu_exact(sl4.x + sr4.x));
                m1 = fmaxf(m1, gelu_exact(sl4.y + sr4.y));
                m2 = fmaxf(m2, gelu_exact(sl4.z + sr4.z));
                m3 = fmaxf(m3, gelu_exact(sl4.w + sr4.w));
            }
        }
        MAX4_REDUCE(m0, m1, m2, m3)
        for (int base = s0; base < s1; base += 64) {
            int j = base + lane;
            int sv = 0;
            float ex0 = 0.f, ex1 = 0.f, ex2 = 0.f, ex3 = 0.f;
            if (j < s1) {
                sv = srcp[j];
                float4 sl4 = *(const float4*)(SL + (size_t)sv * 4);
                ex0 = __expf(gelu_exact(sl4.x + sr4.x) - m0);
                ex1 = __expf(gelu_exact(sl4.y + sr4.y) - m1);
                ex2 = __expf(gelu_exact(sl4.z + sr4.z) - m2);
                ex3 = __expf(gelu_exact(sl4.w + sr4.w) - m3);
            }
            d0 += ex0; d1 += ex1; d2 += ex2; d3 += ex3;
            int cs = min(64, s1 - base);
            for (int jj = 0; jj < cs; ++jj) AGG4_EDGE(jj)
        }
    }
#undef AGG4_EDGE
    SUM4_REDUCE(d0, d1, d2, d3)
    houtp[0] = hx / d0;
    houtp[64] = hy / d1;
    houtp[128] = hz / d2;
    houtp[192] = hw / d3;
}

// 1 head: Zb [N][64] bf16
__global__ __launch_bounds__(256) void aggregate1_kernel(
    const unsigned short* __restrict__ Zb, const float* __restrict__ SL,
    const float* __restrict__ SR, const int* __restrict__ rowptr,
    const int* __restrict__ srcp, float* __restrict__ Hout, int Nn) {
    int n = (blockIdx.x * blockDim.x + threadIdx.x) >> 6;
    int lane = threadIdx.x & 63;
    if (n >= Nn) return;
    int s0 = rowptr[n], s1 = rowptr[n + 1];
    int deg = s1 - s0;
    if (deg == 0) {
        Hout[(size_t)n * 64 + lane] = 0.f;
        return;
    }
    const float srn = SR[n];
    float hacc = 0.f, den = 0.f;
    const unsigned short* zl = Zb + lane;

    if (deg <= 64) {
        float e = -INFINITY;
        int sv = 0;
        if (lane < deg) {
            sv = srcp[s0 + lane];
            e = gelu_exact(SL[sv] + srn);
        }
        float m = e;
#pragma unroll
        for (int off = 32; off; off >>= 1) m = fmaxf(m, __shfl_xor(m, off));
        float ex = (lane < deg) ? __expf(e - m) : 0.f;
        den = ex;
        int jj = 0;
        for (; jj + 1 < deg; jj += 2) {
            int sA = __shfl(sv, jj), sB = __shfl(sv, jj + 1);
            float bA = __shfl(ex, jj), bB = __shfl(ex, jj + 1);
            hacc = fmaf(bA, bf_lo((unsigned int)zl[(size_t)sA * 64]) , hacc);
            hacc = fmaf(bB, bf_lo((unsigned int)zl[(size_t)sB * 64]) , hacc);
        }
        if (jj < deg) {
            int s = __shfl(sv, jj);
            float b = __shfl(ex, jj);
            hacc = fmaf(b, bf_lo((unsigned int)zl[(size_t)s * 64]), hacc);
        }
    } else {
        float m = -INFINITY;
        for (int base = s0; base < s1; base += 64) {
            int j = base + lane;
            if (j < s1) m = fmaxf(m, gelu_exact(SL[srcp[j]] + srn));
        }
#pragma unroll
        for (int off = 32; off; off >>= 1) m = fmaxf(m, __shfl_xor(m, off));
        for (int base = s0; base < s1; base += 64) {
            int j = base + lane;
            int sv = 0;
            float ex = 0.f;
            if (j < s1) {
                sv = srcp[j];
                ex = __expf(gelu_exact(SL[sv] + srn) - m);
            }
            den += ex;
            int cs = min(64, s1 - base);
            for (int jj = 0; jj < cs; ++jj) {
                int s = __shfl(sv, jj);
                float b = __shfl(ex, jj);
                hacc = fmaf(b, bf_lo((unsigned int)zl[(size_t)s * 64]), hacc);
            }
        }
    }
#pragma unroll
    for (int off = 32; off; off >>= 1) den += __shfl_xor(den, off);
    Hout[(size_t)n * 64 + lane] = hacc / den;
}

// out layer: 4 heads, D=7 (padded 8), Zf f32 stride 32
__global__ __launch_bounds__(256) void aggregateo_kernel(
    const float* __restrict__ Z, const float* __restrict__ SL, const float* __restrict__ SR,
    const int* __restrict__ rowptr, const int* __restrict__ srcp,
    float* __restrict__ Hout, int Nn) {
    int n = (blockIdx.x * blockDim.x + threadIdx.x) >> 6;
    int lane = threadIdx.x & 63;
    if (n >= Nn) return;
    int s0 = rowptr[n], s1 = rowptr[n + 1];
    int deg = s1 - s0;
    if (deg == 0) {
        if (lane < 32) Hout[(size_t)n * 32 + lane] = 0.f;
        return;
    }
    const float4 sr4 = *(const float4*)(SR + (size_t)n * 4);
    const int h = (lane & 31) >> 3;
    const int eo = lane >> 5;
    float hacc = 0.f;
    float d0 = 0.f, d1 = 0.f, d2 = 0.f, d3 = 0.f;
    const float* zl = Z + (lane & 31);

    if (deg <= 64) {
        float e0 = -INFINITY, e1 = -INFINITY, e2 = -INFINITY, e3 = -INFINITY;
        int sv = 0;
        if (lane < deg) {
            sv = srcp[s0 + lane];
            float4 sl4 = *(const float4*)(SL + (size_t)sv * 4);
            e0 = gelu_exact(sl4.x + sr4.x);
            e1 = gelu_exact(sl4.y + sr4.y);
            e2 = gelu_exact(sl4.z + sr4.z);
            e3 = gelu_exact(sl4.w + sr4.w);
        }
        float m0 = e0, m1 = e1, m2 = e2, m3 = e3;
        MAX4_REDUCE(m0, m1, m2, m3)
        float ex0 = 0.f, ex1 = 0.f, ex2 = 0.f, ex3 = 0.f;
        if (lane < deg) {
            ex0 = __expf(e0 - m0); ex1 = __expf(e1 - m1);
            ex2 = __expf(e2 - m2); ex3 = __expf(e3 - m3);
        }
        d0 = ex0; d1 = ex1; d2 = ex2; d3 = ex3;
        for (int jj = 0; jj < deg; jj += 2) {
            int lsrc = jj + eo;  // lane>=deg has ex=0 -> safe
            int s = __shfl(sv, lsrc);
            float b0 = __shfl(ex0, lsrc), b1 = __shfl(ex1, lsrc);
            float b2 = __shfl(ex2, lsrc), b3 = __shfl(ex3, lsrc);
            float exs = (h == 0) ? b0 : (h == 1) ? b1 : (h == 2) ? b2 : b3;
            hacc = fmaf(exs, zl[(size_t)s * 32], hacc);
        }
    } else {
        float m0 = -INFINITY, m1 = -INFINITY, m2 = -INFINITY, m3 = -INFINITY;
        for (int base = s0; base < s1; base += 64) {
            int j = base + lane;
            if (j < s1) {
                int s = srcp[j];
                float4 sl4 = *(const float4*)(SL + (size_t)s * 4);
                m0 = fmaxf(m0, gelu_exact(sl4.x + sr4.x));
                m1 = fmaxf(m1, gelu_exact(sl4.y + sr4.y));
                m2 = fmaxf(m2, gelu_exact(sl4.z + sr4.z));
                m3 = fmaxf(m3, gelu_exact(sl4.w + sr4.w));
            }
        }
        MAX4_REDUCE(m0, m1, m2, m3)
        for (int base = s0; base < s1; base += 64) {
            int j = base + lane;
            int sv = 0;
            float ex0 = 0.f, ex1 = 0.f, ex2 = 0.f, ex3 = 0.f;
            if (j < s1) {
                sv = srcp[j];
                float4 sl4 = *(const float4*)(SL + (size_t)sv * 4);
                ex0 = __expf(gelu_exact(sl4.x + sr4.x) - m0);
                ex1 = __expf(gelu_exact(sl4.y + sr4.y) - m1);
                ex2 = __expf(gelu_exact(sl4.z + sr4.z) - m2);
                ex3 = __expf(gelu_exact(sl4.w + sr4.w) - m3);
            }
            d0 += ex0; d1 += ex1; d2 += ex2; d3 += ex3;
            int cs = min(64, s1 - base);
            for (int jj = 0; jj < cs; jj += 2) {
                int lsrc = jj + eo;
                int s = __shfl(sv, lsrc);
                float b0 = __shfl(ex0, lsrc), b1 = __shfl(ex1, lsrc);
                float b2 = __shfl(ex2, lsrc), b3 = __shfl(ex3, lsrc);
                float exs = (h == 0) ? b0 : (h == 1) ? b1 : (h == 2) ? b2 : b3;
                hacc = fmaf(exs, zl[(size_t)s * 32], hacc);
            }
        }
    }
    SUM4_REDUCE(d0, d1, d2, d3)
    hacc += __shfl_xor(hacc, 32);
    float dsel = (h == 0) ? d0 : (h == 1) ? d1 : (h == 2) ? d2 : d3;
    if (lane < 32) Hout[(size_t)n * 32 + lane] = hacc / dsel;
}

// ---------------- mean-over-heads + linear + softmax ----------------

__global__ void finalize_kernel(const float* __restrict__ Hs, const float* __restrict__ LW,
                                const float* __restrict__ LB, float* __restrict__ out, int Nn) {
    int n = blockIdx.x * blockDim.x + threadIdx.x;
    if (n >= Nn) return;
    float mean[7];
#pragma unroll
    for (int k = 0; k < 7; k++)
        mean[k] = 0.25f * (Hs[(size_t)n * 32 + k] + Hs[(size_t)n * 32 + 8 + k] +
                           Hs[(size_t)n * 32 + 16 + k] + Hs[(size_t)n * 32 + 24 + k]);
    float lg[7];
#pragma unroll
    for (int o = 0; o < 7; o++) {
        float acc = LB[o];
#pragma unroll
        for (int k = 0; k < 7; k++) acc = fmaf(mean[k], LW[k * 7 + o], acc);
        lg[o] = acc;
    }
    float mx = lg[0];
#pragma unroll
    for (int o = 1; o < 7; o++) mx = fmaxf(mx, lg[o]);
    float s = 0.f;
#pragma unroll
    for (int o = 0; o < 7; o++) {
        lg[o] = __expf(lg[o] - mx);
        s += lg[o];
    }
    float inv = 1.f / s;
#pragma unroll
    for (int o = 0; o < 7; o++) out[(size_t)n * 7 + o] = lg[o] * inv;
}

// ---------------- launch ----------------

extern "C" void kernel_launch(void* const* d_in, const int* in_sizes, int n_in,
                              void* d_out, int out_size, void* d_ws, size_t ws_size,
                              hipStream_t stream) {
    const float* feature = (const float*)d_in[0];
    const int* src = (const int*)d_in[1];
    const int* dst = (const int*)d_in[2];
    const float* W0 = (const float*)d_in[3];
    const float* b0 = (const float*)d_in[4];
    const float* a0 = (const float*)d_in[5];
    const float* W0h = (const float*)d_in[6];
    const float* b0h = (const float*)d_in[7];
    const float* a0h = (const float*)d_in[8];
    const float* W1 = (const float*)d_in[9];
    const float* b1 = (const float*)d_in[10];
    const float* a1 = (const float*)d_in[11];
    const float* W1h = (const float*)d_in[12];
    const float* b1h = (const float*)d_in[13];
    const float* a1h = (const float*)d_in[14];
    const float* Wo = (const float*)d_in[15];
    const float* bo = (const float*)d_in[16];
    const float* ao = (const float*)d_in[17];
    const float* linW = (const float*)d_in[18];
    const float* linb = (const float*)d_in[19];
    const int N = in_sizes[0] / 64;
    const int E = in_sizes[1];
    float* out = (float*)d_out;

    char* ws = (char*)d_ws;
    size_t off = 0;
    auto alloc = [&](size_t bytes) {
        void* p = ws + off;
        off += (bytes + 255) & ~(size_t)255;
        return p;
    };
    int* cnt = (int*)alloc((size_t)N * 4);
    int* rowptr = (int*)alloc(((size_t)N + 1) * 4);
    int* bsum = (int*)alloc(256 * 4);
    int* srcp = (int*)alloc((size_t)E * 4);
    unsigned short* zbf = (unsigned short*)alloc((size_t)N * 256 * 2);  // bf16 z
    float* zo = (float*)alloc((size_t)N * 32 * 4);                      // f32 z (mode 2)
    float* hbuf = (float*)alloc((size_t)N * 256 * 4);
    float* fbuf = (float*)alloc((size_t)N * 64 * 4);
    float* slb = (float*)alloc((size_t)N * 4 * 4);
    float* srb = (float*)alloc((size_t)N * 4 * 4);
    float* houts = fbuf;  // safe alias: f2 dead after out-GEMM reads it

    // --- CSR by dst (reused by all 5 aggregation stages) ---
    hipMemsetAsync(cnt, 0, (size_t)N * 4, stream);
    hist_kernel<<<2048, 256, 0, stream>>>(dst, cnt, E);
    int nb = (N + 2047) / 2048;
    scan1_kernel<<<nb, 256, 0, stream>>>(cnt, rowptr, bsum, N);
    scan2_kernel<<<1, 32, 0, stream>>>(bsum, rowptr, nb, N);
    scan3_kernel<<<(N + 255) / 256, 256, 0, stream>>>(rowptr, bsum, N);
    hipMemsetAsync(cnt, 0, (size_t)N * 4, stream);
    scatter_kernel<<<2048, 256, 0, stream>>>(dst, rowptr, cnt, src, srcp, E);

    int gemm_blocks = (N + 31) / 32;
    int ablk = (N + 3) / 4;  // one wave per node

    // --- layer 0 (4 heads, concat) ---
    gemm_kernel<0><<<gemm_blocks, 256, 0, stream>>>(feature, W0, b0, a0, zbf, nullptr, slb, srb, N);
    aggregate4_kernel<<<ablk, 256, 0, stream>>>(zbf, slb, srb, rowptr, srcp, hbuf, N);
    // --- layer 0 head_linear ---
    gemm_kernel<1><<<gemm_blocks, 256, 0, stream>>>(hbuf, W0h, b0h, a0h, zbf, nullptr, slb, srb, N);
    aggregate1_kernel<<<ablk, 256, 0, stream>>>(zbf, slb, srb, rowptr, srcp, fbuf, N);
    // --- layer 1 (4 heads, concat) ---
    gemm_kernel<0><<<gemm_blocks, 256, 0, stream>>>(fbuf, W1, b1, a1, zbf, nullptr, slb, srb, N);
    aggregate4_kernel<<<ablk, 256, 0, stream>>>(zbf, slb, srb, rowptr, srcp, hbuf, N);
    // --- layer 1 head_linear ---
    gemm_kernel<1><<<gemm_blocks, 256, 0, stream>>>(hbuf, W1h, b1h, a1h, zbf, nullptr, slb, srb, N);
    aggregate1_kernel<<<ablk, 256, 0, stream>>>(zbf, slb, srb, rowptr, srcp, fbuf, N);
    // --- out layer (4 heads, mean) ---
    gemm_kernel<2><<<gemm_blocks, 256, 0, stream>>>(fbuf, Wo, bo, ao, nullptr, zo, slb, srb, N);
    aggregateo_kernel<<<ablk, 256, 0, stream>>>(zo, slb, srb, rowptr, srcp, houts, N);
    finalize_kernel<<<(N + 255) / 256, 256, 0, stream>>>(houts, linW, linb, out, N);
}

// Round 9
// 1055.339 us; speedup vs baseline: 2.0131x; 1.1900x over previous
//
#include <hip/hip_runtime.h>
#include <hip/hip_bf16.h>
#include <math.h>

#define HEADS 4
#define HID 64
#define OUTD 7

typedef __attribute__((ext_vector_type(8))) short bf16x8;
typedef __attribute__((ext_vector_type(4))) float f32x4;

__device__ __forceinline__ float gelu_exact(float x) {
    return 0.5f * x * (1.0f + erff(x * 0.70710678118654752f));
}

// broadcast lane k (wave-uniform) -> SGPR
__device__ __forceinline__ float readlane_f(float v, int k) {
    union { float f; int i; } u;
    u.f = v;
    u.i = __builtin_amdgcn_readlane(u.i, k);
    return u.f;
}
__device__ __forceinline__ int readlane_i(int v, int k) {
    return __builtin_amdgcn_readlane(v, k);
}

// bf16 helpers (RNE pack; unpack via bit ops)
__device__ __forceinline__ unsigned int f2bf(float f) {
    unsigned int x = __float_as_uint(f);
    return (x + 0x7fffu + ((x >> 16) & 1u)) >> 16;
}
__device__ __forceinline__ float bf_lo(unsigned int v) {
    return __uint_as_float(v << 16);
}
__device__ __forceinline__ float bf_hi(unsigned int v) {
    return __uint_as_float(v & 0xffff0000u);
}

// ---------------- CSR build ----------------

__global__ void hist_kernel(const int* __restrict__ dst, int* __restrict__ cnt, int E) {
    for (int e = blockIdx.x * blockDim.x + threadIdx.x; e < E; e += gridDim.x * blockDim.x)
        atomicAdd(&cnt[dst[e]], 1);
}

__global__ __launch_bounds__(256) void scan1_kernel(const int* __restrict__ cnt,
                                                    int* __restrict__ rowptr,
                                                    int* __restrict__ bsum, int Nn) {
    __shared__ int sums[256];
    int t = threadIdx.x;
    int base = blockIdx.x * 2048 + t * 8;
    int orig[8];
    int run = 0;
#pragma unroll
    for (int i = 0; i < 8; i++) {
        orig[i] = (base + i < Nn) ? cnt[base + i] : 0;
        run += orig[i];
    }
    sums[t] = run;
    __syncthreads();
    for (int off = 1; off < 256; off <<= 1) {
        int y = (t >= off) ? sums[t - off] : 0;
        __syncthreads();
        sums[t] += y;
        __syncthreads();
    }
    int excl = sums[t] - run;
    if (t == 255) bsum[blockIdx.x] = sums[255];
    int e = excl;
#pragma unroll
    for (int i = 0; i < 8; i++) {
        if (base + i < Nn) rowptr[base + i] = e;
        e += orig[i];
    }
}

__global__ void scan2_kernel(int* __restrict__ bsum, int* __restrict__ rowptr, int nb, int Nn) {
    if (blockIdx.x == 0 && threadIdx.x == 0) {
        int run = 0;
        for (int i = 0; i < nb; i++) {
            int t = bsum[i];
            bsum[i] = run;
            run += t;
        }
        rowptr[Nn] = run;
    }
}

__global__ void scan3_kernel(int* __restrict__ rowptr, const int* __restrict__ bsum, int Nn) {
    int i = blockIdx.x * blockDim.x + threadIdx.x;
    if (i < Nn) rowptr[i] += bsum[i >> 11];
}

__global__ void scatter_kernel(const int* __restrict__ dst, const int* __restrict__ rowptr,
                               int* __restrict__ cnt, const int* __restrict__ srcv,
                               int* __restrict__ srcp, int E) {
    for (int e = blockIdx.x * blockDim.x + threadIdx.x; e < E; e += gridDim.x * blockDim.x) {
        int d = dst[e];
        int p = rowptr[d] + atomicAdd(&cnt[d], 1);
        srcp[p] = srcv[e];
    }
}

// W f32 [256][64] -> Wt bf16 [64][256] (transposed, for MFMA B-fragments)
__global__ void wconv_kernel(const float* __restrict__ W, unsigned short* __restrict__ Wt) {
    int m = blockIdx.x, k = threadIdx.x;  // 64 blocks x 256 threads
    Wt[m * 256 + k] = (unsigned short)f2bf(W[k * 64 + m]);
}

// ---------------- GEMM (VALU; MODES 0 and 2 only) ----------------
// MODE 0: X[N,64] f32 @ Wcat + b -> Zb bf16 [N][64][4] head-fastest + slr SL/SR[n*4+h]
// MODE 2: X[N,64] f32 @ Wo + bo -> Zf f32 [N][32] + slr (interleaved)

template <int MODE>
__global__ __launch_bounds__(256, 2) void gemm_kernel(const float* __restrict__ X,
                                                      const float* __restrict__ Wt,
                                                      const float* __restrict__ Bt,
                                                      const float* __restrict__ Aw,
                                                      unsigned short* __restrict__ Zb,
                                                      float* __restrict__ Zf,
                                                      float* __restrict__ SLo,
                                                      float* __restrict__ SRo, int Nn) {
    constexpr int K = 64;
    constexpr int M = (MODE == 0) ? 256 : 32;
    constexpr int CPL = (MODE == 0) ? 4 : 1;

    __shared__ float wlds[K * M];

    const int tid = threadIdx.x;
    const int wid = tid >> 6;
    const int lane = tid & 63;
    const int row0 = blockIdx.x * 32 + wid * 8;

    if (MODE == 0) {
#pragma unroll
        for (int it = 0; it < 16; ++it) {
            int flat = it * 1024 + tid * 4;  // k*256 + m
            int k = flat >> 8, m = flat & 255;
            int h = m >> 6, c = m & 63;
            *(float4*)&wlds[flat] = *(const float4*)(Wt + h * 4096 + k * 64 + c);
        }
    } else {
#pragma unroll
        for (int it = 0; it < 8; ++it) {
            int idx = it * 256 + tid;  // k*32 + m
            int k = idx >> 5, m = idx & 31, h = m >> 3, j = m & 7;
            wlds[idx] = (j < 7) ? Wt[h * 448 + k * 7 + j] : 0.f;
        }
    }
    __syncthreads();

    float acc[8][CPL];
#pragma unroll
    for (int r = 0; r < 8; ++r)
#pragma unroll
        for (int c = 0; c < CPL; ++c) acc[r][c] = 0.f;

    float xr[8];
#pragma unroll
    for (int r = 0; r < 8; ++r) {
        int rr = row0 + r;
        rr = (rr < Nn) ? rr : (Nn - 1);
        xr[r] = X[(size_t)rr * 64 + lane];
    }
#pragma unroll 4
    for (int k = 0; k < 64; ++k) {
        if (MODE == 0) {
            float4 wv = *(const float4*)&wlds[k * 256 + lane * 4];
#pragma unroll
            for (int r = 0; r < 8; ++r) {
                float xk = readlane_f(xr[r], k);
                acc[r][0] = fmaf(xk, wv.x, acc[r][0]);
                acc[r][1] = fmaf(xk, wv.y, acc[r][1]);
                acc[r][2] = fmaf(xk, wv.z, acc[r][2]);
                acc[r][3] = fmaf(xk, wv.w, acc[r][3]);
            }
        } else {
            float wv = wlds[k * 32 + (lane & 31)];
#pragma unroll
            for (int r = 0; r < 8; ++r)
                acc[r][0] = fmaf(readlane_f(xr[r], k), wv, acc[r][0]);
        }
    }

    // ---- epilogue ----
    if (MODE == 0) {
        float4 bv = *(const float4*)(Bt + lane * 4);
        const int h = lane >> 4;
        const int c0 = (lane & 15) * 4;
        float4 al4 = *(const float4*)(Aw + h * 128 + c0);
        float4 ar4 = *(const float4*)(Aw + h * 128 + 64 + c0);
        const int t = lane;
        const int lsbase = t >> 2;
#pragma unroll
        for (int r = 0; r < 8; ++r) {
            int row = row0 + r;
            float4 s = {acc[r][0] + bv.x, acc[r][1] + bv.y, acc[r][2] + bv.z, acc[r][3] + bv.w};
            float sp = s.x * al4.x + s.y * al4.y + s.z * al4.z + s.w * al4.w;
            float rp = s.x * ar4.x + s.y * ar4.y + s.z * ar4.z + s.w * ar4.w;
#pragma unroll
            for (int o = 1; o < 16; o <<= 1) {
                sp += __shfl_xor(sp, o);
                rp += __shfl_xor(rp, o);
            }
            unsigned int lo = f2bf(s.x) | (f2bf(s.y) << 16);
            unsigned int hi = f2bf(s.z) | (f2bf(s.w) << 16);
            unsigned int us[4];
#pragma unroll
            for (int h2 = 0; h2 < 4; ++h2) {
                int ls = (h2 << 4) | lsbase;
                unsigned int vlo = (unsigned int)__shfl((int)lo, ls);
                unsigned int vhi = (unsigned int)__shfl((int)hi, ls);
                unsigned int v = (t & 2) ? vhi : vlo;
                us[h2] = (t & 1) ? (v >> 16) : (v & 0xffffu);
            }
            if (row < Nn) {
                uint2 pk = {us[0] | (us[1] << 16), us[2] | (us[3] << 16)};
                *(uint2*)(Zb + (size_t)row * 256 + t * 4) = pk;
                if ((lane & 15) == 0) {
                    SLo[(size_t)row * 4 + h] = sp;
                    SRo[(size_t)row * 4 + h] = rp;
                }
            }
        }
    } else {
        if (lane < 32) {
            int m = lane, h = m >> 3, j = m & 7;
            float bvv = (j < 7) ? Bt[h * 7 + j] : 0.f;
            float al = (j < 7) ? Aw[h * 14 + j] : 0.f;
            float ar = (j < 7) ? Aw[h * 14 + 7 + j] : 0.f;
#pragma unroll
            for (int r = 0; r < 8; ++r) {
                int row = row0 + r;
                float zv = (j < 7) ? acc[r][0] + bvv : 0.f;
                float sp = zv * al, rp = zv * ar;
#pragma unroll
                for (int o = 1; o < 8; o <<= 1) {
                    sp += __shfl_xor(sp, o);
                    rp += __shfl_xor(rp, o);
                }
                if (row < Nn) {
                    Zf[(size_t)row * 32 + m] = zv;
                    if (j == 0) {
                        SLo[(size_t)row * 4 + h] = sp;
                        SRo[(size_t)row * 4 + h] = rp;
                    }
                }
            }
        }
    }
}

// ---------------- MODE 1 GEMM via MFMA (bf16 x bf16 -> f32) ----------------
// X bf16 [N][256], Wt bf16 [64][256] (transposed). Wave = 16 rows x 64 cols,
// K=256 = 8 ksteps x (1 A-load + 4 B-loads + 4 MFMA). No LDS, no barriers;
// Wt (32KB) is L1-resident. Output: Zb bf16 [N][64] + fused slr SL/SR[n].
// Layouts (m89/m92-verified): A/B frag = 8 bf16 along k, lane&15 = row(A)/col(B),
// lane>>4 = k-octet; C/D col=lane&15, row=(lane>>4)*4+reg.

__global__ __launch_bounds__(256) void gemm1_mfma_kernel(
    const unsigned short* __restrict__ X, const unsigned short* __restrict__ Wt,
    const float* __restrict__ Bt, const float* __restrict__ Aw,
    unsigned short* __restrict__ Zb, float* __restrict__ SLo, float* __restrict__ SRo,
    int Nn) {
    const int tid = threadIdx.x;
    const int wid = tid >> 6;
    const int lane = tid & 63;
    const int g = lane >> 4, i = lane & 15;
    const int rowbase = blockIdx.x * 64 + wid * 16;

    int arow = rowbase + i;
    if (arow >= Nn) arow = Nn - 1;
    const bf16x8* xa = (const bf16x8*)(X + (size_t)arow * 256 + g * 8);
    const bf16x8* w0 = (const bf16x8*)(Wt + (size_t)(i) * 256 + g * 8);
    const bf16x8* w1 = (const bf16x8*)(Wt + (size_t)(16 + i) * 256 + g * 8);
    const bf16x8* w2 = (const bf16x8*)(Wt + (size_t)(32 + i) * 256 + g * 8);
    const bf16x8* w3 = (const bf16x8*)(Wt + (size_t)(48 + i) * 256 + g * 8);

    f32x4 acc0 = {0.f, 0.f, 0.f, 0.f};
    f32x4 acc1 = acc0, acc2 = acc0, acc3 = acc0;
#pragma unroll
    for (int ks = 0; ks < 8; ++ks) {
        bf16x8 av = xa[ks * 4];
        bf16x8 b0 = w0[ks * 4];
        bf16x8 b1 = w1[ks * 4];
        bf16x8 b2 = w2[ks * 4];
        bf16x8 b3 = w3[ks * 4];
        acc0 = __builtin_amdgcn_mfma_f32_16x16x32_bf16(av, b0, acc0, 0, 0, 0);
        acc1 = __builtin_amdgcn_mfma_f32_16x16x32_bf16(av, b1, acc1, 0, 0, 0);
        acc2 = __builtin_amdgcn_mfma_f32_16x16x32_bf16(av, b2, acc2, 0, 0, 0);
        acc3 = __builtin_amdgcn_mfma_f32_16x16x32_bf16(av, b3, acc3, 0, 0, 0);
    }

    // epilogue: bias + slr + bf16 store
    float bv0 = Bt[i], bv1 = Bt[16 + i], bv2 = Bt[32 + i], bv3 = Bt[48 + i];
    float al0 = Aw[i], al1 = Aw[16 + i], al2 = Aw[32 + i], al3 = Aw[48 + i];
    float ar0 = Aw[64 + i], ar1 = Aw[80 + i], ar2 = Aw[96 + i], ar3 = Aw[112 + i];
    float z0[4], z1[4], z2[4], z3[4], sp[4], rp[4];
#pragma unroll
    for (int r = 0; r < 4; ++r) {
        z0[r] = acc0[r] + bv0;
        z1[r] = acc1[r] + bv1;
        z2[r] = acc2[r] + bv2;
        z3[r] = acc3[r] + bv3;
        sp[r] = z0[r] * al0 + z1[r] * al1 + z2[r] * al2 + z3[r] * al3;
        rp[r] = z0[r] * ar0 + z1[r] * ar1 + z2[r] * ar2 + z3[r] * ar3;
    }
#pragma unroll
    for (int o = 1; o <= 8; o <<= 1) {
#pragma unroll
        for (int r = 0; r < 4; ++r) {
            sp[r] += __shfl_xor(sp[r], o);
            rp[r] += __shfl_xor(rp[r], o);
        }
    }
#pragma unroll
    for (int r = 0; r < 4; ++r) {
        int row = rowbase + g * 4 + r;
        if (row < Nn) {
            unsigned short* zp = Zb + (size_t)row * 64 + i;
            zp[0] = (unsigned short)f2bf(z0[r]);
            zp[16] = (unsigned short)f2bf(z1[r]);
            zp[32] = (unsigned short)f2bf(z2[r]);
            zp[48] = (unsigned short)f2bf(z3[r]);
            if (i == 0) {
                SLo[row] = sp[r];
                SRo[row] = rp[r];
            }
        }
    }
}

// ---------------- aggregation ----------------

#define MAX4_REDUCE(m0, m1, m2, m3)                      \
    _Pragma("unroll") for (int off = 32; off; off >>= 1) { \
        m0 = fmaxf(m0, __shfl_xor(m0, off));             \
        m1 = fmaxf(m1, __shfl_xor(m1, off));             \
        m2 = fmaxf(m2, __shfl_xor(m2, off));             \
        m3 = fmaxf(m3, __shfl_xor(m3, off));             \
    }

#define SUM4_REDUCE(d0, d1, d2, d3)                      \
    _Pragma("unroll") for (int off = 32; off; off >>= 1) { \
        d0 += __shfl_xor(d0, off);                       \
        d1 += __shfl_xor(d1, off);                       \
        d2 += __shfl_xor(d2, off);                       \
        d3 += __shfl_xor(d3, off);                       \
    }

// 4 heads: Zb [N][64][4] bf16 head-fastest; OUT: Hb bf16 [N][256] (h*64+c) for MFMA.
// Broadcasts use readlane (jj wave-uniform) -> SGPR weights + SGPR-base gather.
__global__ __launch_bounds__(256) void aggregate4_kernel(
    const unsigned short* __restrict__ Zb, const float* __restrict__ SL,
    const float* __restrict__ SR, const int* __restrict__ rowptr,
    const int* __restrict__ srcp, unsigned short* __restrict__ Hb, int Nn) {
    int n = (blockIdx.x * blockDim.x + threadIdx.x) >> 6;
    int lane = threadIdx.x & 63;
    if (n >= Nn) return;
    int s0 = rowptr[n], s1 = rowptr[n + 1];
    int deg = s1 - s0;
    unsigned short* hp = Hb + (size_t)n * 256 + lane;
    if (deg == 0) {
        hp[0] = 0; hp[64] = 0; hp[128] = 0; hp[192] = 0;
        return;
    }
    const float4 sr4 = *(const float4*)(SR + (size_t)n * 4);
    float hx = 0.f, hy = 0.f, hz = 0.f, hw = 0.f;
    float d0 = 0.f, d1 = 0.f, d2 = 0.f, d3 = 0.f;

#define AGG4_EDGE(JJ)                                                        \
    {                                                                        \
        int s = readlane_i(sv, (JJ));                                        \
        float a0 = readlane_f(ex0, (JJ)), a1 = readlane_f(ex1, (JJ));        \
        float a2 = readlane_f(ex2, (JJ)), a3 = readlane_f(ex3, (JJ));        \
        uint2 q = *(const uint2*)(Zb + (size_t)s * 256 + lane * 4);          \
        hx = fmaf(a0, bf_lo(q.x), hx);                                       \
        hy = fmaf(a1, bf_hi(q.x), hy);                                       \
        hz = fmaf(a2, bf_lo(q.y), hz);                                       \
        hw = fmaf(a3, bf_hi(q.y), hw);                                       \
    }

    if (deg <= 64) {
        float e0 = -INFINITY, e1 = -INFINITY, e2 = -INFINITY, e3 = -INFINITY;
        int sv = 0;
        if (lane < deg) {
            sv = srcp[s0 + lane];
            float4 sl4 = *(const float4*)(SL + (size_t)sv * 4);
            e0 = gelu_exact(sl4.x + sr4.x);
            e1 = gelu_exact(sl4.y + sr4.y);
            e2 = gelu_exact(sl4.z + sr4.z);
            e3 = gelu_exact(sl4.w + sr4.w);
        }
        float m0 = e0, m1 = e1, m2 = e2, m3 = e3;
        MAX4_REDUCE(m0, m1, m2, m3)
        float ex0 = 0.f, ex1 = 0.f, ex2 = 0.f, ex3 = 0.f;
        if (lane < deg) {
            ex0 = __expf(e0 - m0); ex1 = __expf(e1 - m1);
            ex2 = __expf(e2 - m2); ex3 = __expf(e3 - m3);
        }
        d0 = ex0; d1 = ex1; d2 = ex2; d3 = ex3;
        int jj = 0;
        for (; jj + 3 < deg; jj += 4) {
            AGG4_EDGE(jj)
            AGG4_EDGE(jj + 1)
            AGG4_EDGE(jj + 2)
            AGG4_EDGE(jj + 3)
        }
        for (; jj < deg; ++jj) AGG4_EDGE(jj)
    } else {
        float m0 = -INFINITY, m1 = -INFINITY, m2 = -INFINITY, m3 = -INFINITY;
        for (int base = s0; base < s1; base += 64) {
            int j = base + lane;
            if (j < s1) {
                int s = srcp[j];
                float4 sl4 = *(const float4*)(SL + (size_t)s * 4);
                m0 = fmaxf(m0, gelu_exact(sl4.x + sr4.x));
                m1 = fmaxf(m1, gelu_exact(sl4.y + sr4.y));
                m2 = fmaxf(m2, gelu_exact(sl4.z + sr4.z));
                m3 = fmaxf(m3, gelu_exact(sl4.w + sr4.w));
            }
        }
        MAX4_REDUCE(m0, m1, m2, m3)
        for (int base = s0; base < s1; base += 64) {
            int j = base + lane;
            int sv = 0;
            float ex0 = 0.f, ex1 = 0.f, ex2 = 0.f, ex3 = 0.f;
            if (j < s1) {
                sv = srcp[j];
                float4 sl4 = *(const float4*)(SL + (size_t)sv * 4);
                ex0 = __expf(gelu_exact(sl4.x + sr4.x) - m0);
                ex1 = __expf(gelu_exact(sl4.y + sr4.y) - m1);
                ex2 = __expf(gelu_exact(sl4.z + sr4.z) - m2);
                ex3 = __expf(gelu_exact(sl4.w + sr4.w) - m3);
            }
            d0 += ex0; d1 += ex1; d2 += ex2; d3 += ex3;
            int cs = min(64, s1 - base);
            for (int jj = 0; jj < cs; ++jj) AGG4_EDGE(jj)
        }
    }
#undef AGG4_EDGE
    SUM4_REDUCE(d0, d1, d2, d3)
    hp[0] = (unsigned short)f2bf(hx / d0);
    hp[64] = (unsigned short)f2bf(hy / d1);
    hp[128] = (unsigned short)f2bf(hz / d2);
    hp[192] = (unsigned short)f2bf(hw / d3);
}

// 1 head: Zb [N][64] bf16 -> fbuf f32
__global__ __launch_bounds__(256) void aggregate1_kernel(
    const unsigned short* __restrict__ Zb, const float* __restrict__ SL,
    const float* __restrict__ SR, const int* __restrict__ rowptr,
    const int* __restrict__ srcp, float* __restrict__ Hout, int Nn) {
    int n = (blockIdx.x * blockDim.x + threadIdx.x) >> 6;
    int lane = threadIdx.x & 63;
    if (n >= Nn) return;
    int s0 = rowptr[n], s1 = rowptr[n + 1];
    int deg = s1 - s0;
    if (deg == 0) {
        Hout[(size_t)n * 64 + lane] = 0.f;
        return;
    }
    const float srn = SR[n];
    float hacc = 0.f, den = 0.f;

    if (deg <= 64) {
        float e = -INFINITY;
        int sv = 0;
        if (lane < deg) {
            sv = srcp[s0 + lane];
            e = gelu_exact(SL[sv] + srn);
        }
        float m = e;
#pragma unroll
        for (int off = 32; off; off >>= 1) m = fmaxf(m, __shfl_xor(m, off));
        float ex = (lane < deg) ? __expf(e - m) : 0.f;
        den = ex;
        int jj = 0;
        for (; jj + 1 < deg; jj += 2) {
            int sA = readlane_i(sv, jj), sB = readlane_i(sv, jj + 1);
            float bA = readlane_f(ex, jj), bB = readlane_f(ex, jj + 1);
            hacc = fmaf(bA, bf_lo((unsigned int)Zb[(size_t)sA * 64 + lane]), hacc);
            hacc = fmaf(bB, bf_lo((unsigned int)Zb[(size_t)sB * 64 + lane]), hacc);
        }
        if (jj < deg) {
            int s = readlane_i(sv, jj);
            float b = readlane_f(ex, jj);
            hacc = fmaf(b, bf_lo((unsigned int)Zb[(size_t)s * 64 + lane]), hacc);
        }
    } else {
        float m = -INFINITY;
        for (int base = s0; base < s1; base += 64) {
            int j = base + lane;
            if (j < s1) m = fmaxf(m, gelu_exact(SL[srcp[j]] + srn));
        }
#pragma unroll
        for (int off = 32; off; off >>= 1) m = fmaxf(m, __shfl_xor(m, off));
        for (int base = s0; base < s1; base += 64) {
            int j = base + lane;
            int sv = 0;
            float ex = 0.f;
            if (j < s1) {
                sv = srcp[j];
                ex = __expf(gelu_exact(SL[sv] + srn) - m);
            }
            den += ex;
            int cs = min(64, s1 - base);
            for (int jj = 0; jj < cs; ++jj) {
                int s = readlane_i(sv, jj);
                float b = readlane_f(ex, jj);
                hacc = fmaf(b, bf_lo((unsigned int)Zb[(size_t)s * 64 + lane]), hacc);
            }
        }
    }
#pragma unroll
    for (int off = 32; off; off >>= 1) den += __shfl_xor(den, off);
    Hout[(size_t)n * 64 + lane] = hacc / den;
}

// out layer: 4 heads, D=7 (padded 8), Zf f32 stride 32
__global__ __launch_bounds__(256) void aggregateo_kernel(
    const float* __restrict__ Z, const float* __restrict__ SL, const float* __restrict__ SR,
    const int* __restrict__ rowptr, const int* __restrict__ srcp,
    float* __restrict__ Hout, int Nn) {
    int n = (blockIdx.x * blockDim.x + threadIdx.x) >> 6;
    int lane = threadIdx.x & 63;
    if (n >= Nn) return;
    int s0 = rowptr[n], s1 = rowptr[n + 1];
    int deg = s1 - s0;
    if (deg == 0) {
        if (lane < 32) Hout[(size_t)n * 32 + lane] = 0.f;
        return;
    }
    const float4 sr4 = *(const float4*)(SR + (size_t)n * 4);
    const int h = (lane & 31) >> 3;
    const int eo = lane >> 5;
    float hacc = 0.f;
    float d0 = 0.f, d1 = 0.f, d2 = 0.f, d3 = 0.f;
    const float* zl = Z + (lane & 31);

    if (deg <= 64) {
        float e0 = -INFINITY, e1 = -INFINITY, e2 = -INFINITY, e3 = -INFINITY;
        int sv = 0;
        if (lane < deg) {
            sv = srcp[s0 + lane];
            float4 sl4 = *(const float4*)(SL + (size_t)sv * 4);
            e0 = gelu_exact(sl4.x + sr4.x);
            e1 = gelu_exact(sl4.y + sr4.y);
            e2 = gelu_exact(sl4.z + sr4.z);
            e3 = gelu_exact(sl4.w + sr4.w);
        }
        float m0 = e0, m1 = e1, m2 = e2, m3 = e3;
        MAX4_REDUCE(m0, m1, m2, m3)
        float ex0 = 0.f, ex1 = 0.f, ex2 = 0.f, ex3 = 0.f;
        if (lane < deg) {
            ex0 = __expf(e0 - m0); ex1 = __expf(e1 - m1);
            ex2 = __expf(e2 - m2); ex3 = __expf(e3 - m3);
        }
        d0 = ex0; d1 = ex1; d2 = ex2; d3 = ex3;
        for (int jj = 0; jj < deg; jj += 2) {
            int lsrc = jj + eo;
            int s = __shfl(sv, lsrc);
            float b0 = __shfl(ex0, lsrc), b1 = __shfl(ex1, lsrc);
            float b2 = __shfl(ex2, lsrc), b3 = __shfl(ex3, lsrc);
            float exs = (h == 0) ? b0 : (h == 1) ? b1 : (h == 2) ? b2 : b3;
            hacc = fmaf(exs, zl[(size_t)s * 32], hacc);
        }
    } else {
        float m0 = -INFINITY, m1 = -INFINITY, m2 = -INFINITY, m3 = -INFINITY;
        for (int base = s0; base < s1; base += 64) {
            int j = base + lane;
            if (j < s1) {
                int s = srcp[j];
                float4 sl4 = *(const float4*)(SL + (size_t)s * 4);
                m0 = fmaxf(m0, gelu_exact(sl4.x + sr4.x));
                m1 = fmaxf(m1, gelu_exact(sl4.y + sr4.y));
                m2 = fmaxf(m2, gelu_exact(sl4.z + sr4.z));
                m3 = fmaxf(m3, gelu_exact(sl4.w + sr4.w));
            }
        }
        MAX4_REDUCE(m0, m1, m2, m3)
        for (int base = s0; base < s1; base += 64) {
            int j = base + lane;
            int sv = 0;
            float ex0 = 0.f, ex1 = 0.f, ex2 = 0.f, ex3 = 0.f;
            if (j < s1) {
                sv = srcp[j];
                float4 sl4 = *(const float4*)(SL + (size_t)sv * 4);
                ex0 = __expf(gelu_exact(sl4.x + sr4.x) - m0);
                ex1 = __expf(gelu_exact(sl4.y + sr4.y) - m1);
                ex2 = __expf(gelu_exact(sl4.z + sr4.z) - m2);
                ex3 = __expf(gelu_exact(sl4.w + sr4.w) - m3);
            }
            d0 += ex0; d1 += ex1; d2 += ex2; d3 += ex3;
            int cs = min(64, s1 - base);
            for (int jj = 0; jj < cs; jj += 2) {
                int lsrc = jj + eo;
                int s = __shfl(sv, lsrc);
                float b0 = __shfl(ex0, lsrc), b1 = __shfl(ex1, lsrc);
                float b2 = __shfl(ex2, lsrc), b3 = __shfl(ex3, lsrc);
                float exs = (h == 0) ? b0 : (h == 1) ? b1 : (h == 2) ? b2 : b3;
                hacc = fmaf(exs, zl[(size_t)s * 32], hacc);
            }
        }
    }
    SUM4_REDUCE(d0, d1, d2, d3)
    hacc += __shfl_xor(hacc, 32);
    float dsel = (h == 0) ? d0 : (h == 1) ? d1 : (h == 2) ? d2 : d3;
    if (lane < 32) Hout[(size_t)n * 32 + lane] = hacc / dsel;
}

// ---------------- mean-over-heads + linear + softmax ----------------

__global__ void finalize_kernel(const float* __restrict__ Hs, const float* __restrict__ LW,
                                const float* __restrict__ LB, float* __restrict__ out, int Nn) {
    int n = blockIdx.x * blockDim.x + threadIdx.x;
    if (n >= Nn) return;
    float mean[7];
#pragma unroll
    for (int k = 0; k < 7; k++)
        mean[k] = 0.25f * (Hs[(size_t)n * 32 + k] + Hs[(size_t)n * 32 + 8 + k] +
                           Hs[(size_t)n * 32 + 16 + k] + Hs[(size_t)n * 32 + 24 + k]);
    float lg[7];
#pragma unroll
    for (int o = 0; o < 7; o++) {
        float acc = LB[o];
#pragma unroll
        for (int k = 0; k < 7; k++) acc = fmaf(mean[k], LW[k * 7 + o], acc);
        lg[o] = acc;
    }
    float mx = lg[0];
#pragma unroll
    for (int o = 1; o < 7; o++) mx = fmaxf(mx, lg[o]);
    float s = 0.f;
#pragma unroll
    for (int o = 0; o < 7; o++) {
        lg[o] = __expf(lg[o] - mx);
        s += lg[o];
    }
    float inv = 1.f / s;
#pragma unroll
    for (int o = 0; o < 7; o++) out[(size_t)n * 7 + o] = lg[o] * inv;
}

// ---------------- launch ----------------

extern "C" void kernel_launch(void* const* d_in, const int* in_sizes, int n_in,
                              void* d_out, int out_size, void* d_ws, size_t ws_size,
                              hipStream_t stream) {
    const float* feature = (const float*)d_in[0];
    const int* src = (const int*)d_in[1];
    const int* dst = (const int*)d_in[2];
    const float* W0 = (const float*)d_in[3];
    const float* b0 = (const float*)d_in[4];
    const float* a0 = (const float*)d_in[5];
    const float* W0h = (const float*)d_in[6];
    const float* b0h = (const float*)d_in[7];
    const float* a0h = (const float*)d_in[8];
    const float* W1 = (const float*)d_in[9];
    const float* b1 = (const float*)d_in[10];
    const float* a1 = (const float*)d_in[11];
    const float* W1h = (const float*)d_in[12];
    const float* b1h = (const float*)d_in[13];
    const float* a1h = (const float*)d_in[14];
    const float* Wo = (const float*)d_in[15];
    const float* bo = (const float*)d_in[16];
    const float* ao = (const float*)d_in[17];
    const float* linW = (const float*)d_in[18];
    const float* linb = (const float*)d_in[19];
    const int N = in_sizes[0] / 64;
    const int E = in_sizes[1];
    float* out = (float*)d_out;

    char* ws = (char*)d_ws;
    size_t off = 0;
    auto alloc = [&](size_t bytes) {
        void* p = ws + off;
        off += (bytes + 255) & ~(size_t)255;
        return p;
    };
    int* cnt = (int*)alloc((size_t)N * 4);
    int* rowptr = (int*)alloc(((size_t)N + 1) * 4);
    int* bsum = (int*)alloc(256 * 4);
    int* srcp = (int*)alloc((size_t)E * 4);
    unsigned short* zbf = (unsigned short*)alloc((size_t)N * 256 * 2);   // gather tables
    unsigned short* hbufb = (unsigned short*)alloc((size_t)N * 256 * 2); // agg4 out (MFMA X)
    unsigned short* wtb = (unsigned short*)alloc(64 * 256 * 2);          // bf16 W^T
    float* zo = (float*)alloc((size_t)N * 32 * 4);
    float* fbuf = (float*)alloc((size_t)N * 64 * 4);
    float* slb = (float*)alloc((size_t)N * 4 * 4);
    float* srb = (float*)alloc((size_t)N * 4 * 4);
    float* houts = fbuf;  // safe alias: f2 dead after out-GEMM reads it

    // --- CSR by dst (reused by all 5 aggregation stages) ---
    hipMemsetAsync(cnt, 0, (size_t)N * 4, stream);
    hist_kernel<<<2048, 256, 0, stream>>>(dst, cnt, E);
    int nb = (N + 2047) / 2048;
    scan1_kernel<<<nb, 256, 0, stream>>>(cnt, rowptr, bsum, N);
    scan2_kernel<<<1, 32, 0, stream>>>(bsum, rowptr, nb, N);
    scan3_kernel<<<(N + 255) / 256, 256, 0, stream>>>(rowptr, bsum, N);
    hipMemsetAsync(cnt, 0, (size_t)N * 4, stream);
    scatter_kernel<<<2048, 256, 0, stream>>>(dst, rowptr, cnt, src, srcp, E);

    int gemm_blocks = (N + 31) / 32;
    int mfma_blocks = (N + 63) / 64;
    int ablk = (N + 3) / 4;  // one wave per node

    // --- layer 0 (4 heads, concat) ---
    gemm_kernel<0><<<gemm_blocks, 256, 0, stream>>>(feature, W0, b0, a0, zbf, nullptr, slb, srb, N);
    aggregate4_kernel<<<ablk, 256, 0, stream>>>(zbf, slb, srb, rowptr, srcp, hbufb, N);
    // --- layer 0 head_linear (MFMA) ---
    wconv_kernel<<<64, 256, 0, stream>>>(W0h, wtb);
    gemm1_mfma_kernel<<<mfma_blocks, 256, 0, stream>>>(hbufb, wtb, b0h, a0h, zbf, slb, srb, N);
    aggregate1_kernel<<<ablk, 256, 0, stream>>>(zbf, slb, srb, rowptr, srcp, fbuf, N);
    // --- layer 1 (4 heads, concat) ---
    gemm_kernel<0><<<gemm_blocks, 256, 0, stream>>>(fbuf, W1, b1, a1, zbf, nullptr, slb, srb, N);
    aggregate4_kernel<<<ablk, 256, 0, stream>>>(zbf, slb, srb, rowptr, srcp, hbufb, N);
    // --- layer 1 head_linear (MFMA) ---
    wconv_kernel<<<64, 256, 0, stream>>>(W1h, wtb);
    gemm1_mfma_kernel<<<mfma_blocks, 256, 0, stream>>>(hbufb, wtb, b1h, a1h, zbf, slb, srb, N);
    aggregate1_kernel<<<ablk, 256, 0, stream>>>(zbf, slb, srb, rowptr, srcp, fbuf, N);
    // --- out layer (4 heads, mean) ---
    gemm_kernel<2><<<gemm_blocks, 256, 0, stream>>>(fbuf, Wo, bo, ao, nullptr, zo, slb, srb, N);
    aggregateo_kernel<<<ablk, 256, 0, stream>>>(zo, slb, srb, rowptr, srcp, houts, N);
    finalize_kernel<<<(N + 255) / 256, 256, 0, stream>>>(houts, linW, linb, out, N);
}

// Round 10
// 1024.752 us; speedup vs baseline: 2.0732x; 1.0298x over previous
//
#include <hip/hip_runtime.h>
#include <hip/hip_bf16.h>
#include <math.h>

#define HEADS 4
#define HID 64
#define OUTD 7

typedef __attribute__((ext_vector_type(8))) short bf16x8;
typedef __attribute__((ext_vector_type(4))) float f32x4;

__device__ __forceinline__ float gelu_exact(float x) {
    return 0.5f * x * (1.0f + erff(x * 0.70710678118654752f));
}

// broadcast lane k (wave-uniform) -> SGPR
__device__ __forceinline__ float readlane_f(float v, int k) {
    union { float f; int i; } u;
    u.f = v;
    u.i = __builtin_amdgcn_readlane(u.i, k);
    return u.f;
}
__device__ __forceinline__ int readlane_i(int v, int k) {
    return __builtin_amdgcn_readlane(v, k);
}

// bf16 helpers (RNE pack; unpack via bit ops)
__device__ __forceinline__ unsigned int f2bf(float f) {
    unsigned int x = __float_as_uint(f);
    return (x + 0x7fffu + ((x >> 16) & 1u)) >> 16;
}
__device__ __forceinline__ float bf_lo(unsigned int v) {
    return __uint_as_float(v << 16);
}
__device__ __forceinline__ float bf_hi(unsigned int v) {
    return __uint_as_float(v & 0xffff0000u);
}

// ---------------- CSR build ----------------

__global__ void hist_kernel(const int* __restrict__ dst, int* __restrict__ cnt, int E) {
    for (int e = blockIdx.x * blockDim.x + threadIdx.x; e < E; e += gridDim.x * blockDim.x)
        atomicAdd(&cnt[dst[e]], 1);
}

__global__ __launch_bounds__(256) void scan1_kernel(const int* __restrict__ cnt,
                                                    int* __restrict__ rowptr,
                                                    int* __restrict__ bsum, int Nn) {
    __shared__ int sums[256];
    int t = threadIdx.x;
    int base = blockIdx.x * 2048 + t * 8;
    int orig[8];
    int run = 0;
#pragma unroll
    for (int i = 0; i < 8; i++) {
        orig[i] = (base + i < Nn) ? cnt[base + i] : 0;
        run += orig[i];
    }
    sums[t] = run;
    __syncthreads();
    for (int off = 1; off < 256; off <<= 1) {
        int y = (t >= off) ? sums[t - off] : 0;
        __syncthreads();
        sums[t] += y;
        __syncthreads();
    }
    int excl = sums[t] - run;
    if (t == 255) bsum[blockIdx.x] = sums[255];
    int e = excl;
#pragma unroll
    for (int i = 0; i < 8; i++) {
        if (base + i < Nn) rowptr[base + i] = e;
        e += orig[i];
    }
}

__global__ void scan2_kernel(int* __restrict__ bsum, int* __restrict__ rowptr, int nb, int Nn) {
    if (blockIdx.x == 0 && threadIdx.x == 0) {
        int run = 0;
        for (int i = 0; i < nb; i++) {
            int t = bsum[i];
            bsum[i] = run;
            run += t;
        }
        rowptr[Nn] = run;
    }
}

__global__ void scan3_kernel(int* __restrict__ rowptr, const int* __restrict__ bsum, int Nn) {
    int i = blockIdx.x * blockDim.x + threadIdx.x;
    if (i < Nn) rowptr[i] += bsum[i >> 11];
}

__global__ void scatter_kernel(const int* __restrict__ dst, const int* __restrict__ rowptr,
                               int* __restrict__ cnt, const int* __restrict__ srcv,
                               int* __restrict__ srcp, int E) {
    for (int e = blockIdx.x * blockDim.x + threadIdx.x; e < E; e += gridDim.x * blockDim.x) {
        int d = dst[e];
        int p = rowptr[d] + atomicAdd(&cnt[d], 1);
        srcp[p] = srcv[e];
    }
}

// W f32 [256][64] -> Wt bf16 [64][256] (transposed, for MFMA B-fragments)
__global__ void wconv_kernel(const float* __restrict__ W, unsigned short* __restrict__ Wt) {
    int m = blockIdx.x, k = threadIdx.x;  // 64 blocks x 256 threads
    Wt[m * 256 + k] = (unsigned short)f2bf(W[k * 64 + m]);
}

// ---------------- GEMM (VALU; MODES 0 and 2 only) ----------------
// MODE 0: X[N,64] f32 @ Wcat + b -> Zb bf16 [N][64][4] head-fastest + slr SL/SR[n*4+h]
// MODE 2: X[N,64] f32 @ Wo + bo -> Zf f32 [N][32] + slr (interleaved)

template <int MODE>
__global__ __launch_bounds__(256, 2) void gemm_kernel(const float* __restrict__ X,
                                                      const float* __restrict__ Wt,
                                                      const float* __restrict__ Bt,
                                                      const float* __restrict__ Aw,
                                                      unsigned short* __restrict__ Zb,
                                                      float* __restrict__ Zf,
                                                      float* __restrict__ SLo,
                                                      float* __restrict__ SRo, int Nn) {
    constexpr int K = 64;
    constexpr int M = (MODE == 0) ? 256 : 32;
    constexpr int CPL = (MODE == 0) ? 4 : 1;

    __shared__ float wlds[K * M];

    const int tid = threadIdx.x;
    const int wid = tid >> 6;
    const int lane = tid & 63;
    const int row0 = blockIdx.x * 32 + wid * 8;

    if (MODE == 0) {
#pragma unroll
        for (int it = 0; it < 16; ++it) {
            int flat = it * 1024 + tid * 4;  // k*256 + m
            int k = flat >> 8, m = flat & 255;
            int h = m >> 6, c = m & 63;
            *(float4*)&wlds[flat] = *(const float4*)(Wt + h * 4096 + k * 64 + c);
        }
    } else {
#pragma unroll
        for (int it = 0; it < 8; ++it) {
            int idx = it * 256 + tid;  // k*32 + m
            int k = idx >> 5, m = idx & 31, h = m >> 3, j = m & 7;
            wlds[idx] = (j < 7) ? Wt[h * 448 + k * 7 + j] : 0.f;
        }
    }
    __syncthreads();

    float acc[8][CPL];
#pragma unroll
    for (int r = 0; r < 8; ++r)
#pragma unroll
        for (int c = 0; c < CPL; ++c) acc[r][c] = 0.f;

    float xr[8];
#pragma unroll
    for (int r = 0; r < 8; ++r) {
        int rr = row0 + r;
        rr = (rr < Nn) ? rr : (Nn - 1);
        xr[r] = X[(size_t)rr * 64 + lane];
    }
#pragma unroll 4
    for (int k = 0; k < 64; ++k) {
        if (MODE == 0) {
            float4 wv = *(const float4*)&wlds[k * 256 + lane * 4];
#pragma unroll
            for (int r = 0; r < 8; ++r) {
                float xk = readlane_f(xr[r], k);
                acc[r][0] = fmaf(xk, wv.x, acc[r][0]);
                acc[r][1] = fmaf(xk, wv.y, acc[r][1]);
                acc[r][2] = fmaf(xk, wv.z, acc[r][2]);
                acc[r][3] = fmaf(xk, wv.w, acc[r][3]);
            }
        } else {
            float wv = wlds[k * 32 + (lane & 31)];
#pragma unroll
            for (int r = 0; r < 8; ++r)
                acc[r][0] = fmaf(readlane_f(xr[r], k), wv, acc[r][0]);
        }
    }

    // ---- epilogue ----
    if (MODE == 0) {
        float4 bv = *(const float4*)(Bt + lane * 4);
        const int h = lane >> 4;
        const int c0 = (lane & 15) * 4;
        float4 al4 = *(const float4*)(Aw + h * 128 + c0);
        float4 ar4 = *(const float4*)(Aw + h * 128 + 64 + c0);
        const int t = lane;
        const int lsbase = t >> 2;
#pragma unroll
        for (int r = 0; r < 8; ++r) {
            int row = row0 + r;
            float4 s = {acc[r][0] + bv.x, acc[r][1] + bv.y, acc[r][2] + bv.z, acc[r][3] + bv.w};
            float sp = s.x * al4.x + s.y * al4.y + s.z * al4.z + s.w * al4.w;
            float rp = s.x * ar4.x + s.y * ar4.y + s.z * ar4.z + s.w * ar4.w;
#pragma unroll
            for (int o = 1; o < 16; o <<= 1) {
                sp += __shfl_xor(sp, o);
                rp += __shfl_xor(rp, o);
            }
            unsigned int lo = f2bf(s.x) | (f2bf(s.y) << 16);
            unsigned int hi = f2bf(s.z) | (f2bf(s.w) << 16);
            unsigned int us[4];
#pragma unroll
            for (int h2 = 0; h2 < 4; ++h2) {
                int ls = (h2 << 4) | lsbase;
                unsigned int vlo = (unsigned int)__shfl((int)lo, ls);
                unsigned int vhi = (unsigned int)__shfl((int)hi, ls);
                unsigned int v = (t & 2) ? vhi : vlo;
                us[h2] = (t & 1) ? (v >> 16) : (v & 0xffffu);
            }
            if (row < Nn) {
                uint2 pk = {us[0] | (us[1] << 16), us[2] | (us[3] << 16)};
                *(uint2*)(Zb + (size_t)row * 256 + t * 4) = pk;
                if ((lane & 15) == 0) {
                    SLo[(size_t)row * 4 + h] = sp;
                    SRo[(size_t)row * 4 + h] = rp;
                }
            }
        }
    } else {
        if (lane < 32) {
            int m = lane, h = m >> 3, j = m & 7;
            float bvv = (j < 7) ? Bt[h * 7 + j] : 0.f;
            float al = (j < 7) ? Aw[h * 14 + j] : 0.f;
            float ar = (j < 7) ? Aw[h * 14 + 7 + j] : 0.f;
#pragma unroll
            for (int r = 0; r < 8; ++r) {
                int row = row0 + r;
                float zv = (j < 7) ? acc[r][0] + bvv : 0.f;
                float sp = zv * al, rp = zv * ar;
#pragma unroll
                for (int o = 1; o < 8; o <<= 1) {
                    sp += __shfl_xor(sp, o);
                    rp += __shfl_xor(rp, o);
                }
                if (row < Nn) {
                    Zf[(size_t)row * 32 + m] = zv;
                    if (j == 0) {
                        SLo[(size_t)row * 4 + h] = sp;
                        SRo[(size_t)row * 4 + h] = rp;
                    }
                }
            }
        }
    }
}

// ---------------- MODE 1 GEMM via MFMA (bf16 x bf16 -> f32) ----------------

__global__ __launch_bounds__(256) void gemm1_mfma_kernel(
    const unsigned short* __restrict__ X, const unsigned short* __restrict__ Wt,
    const float* __restrict__ Bt, const float* __restrict__ Aw,
    unsigned short* __restrict__ Zb, float* __restrict__ SLo, float* __restrict__ SRo,
    int Nn) {
    const int tid = threadIdx.x;
    const int wid = tid >> 6;
    const int lane = tid & 63;
    const int g = lane >> 4, i = lane & 15;
    const int rowbase = blockIdx.x * 64 + wid * 16;

    int arow = rowbase + i;
    if (arow >= Nn) arow = Nn - 1;
    const bf16x8* xa = (const bf16x8*)(X + (size_t)arow * 256 + g * 8);
    const bf16x8* w0 = (const bf16x8*)(Wt + (size_t)(i) * 256 + g * 8);
    const bf16x8* w1 = (const bf16x8*)(Wt + (size_t)(16 + i) * 256 + g * 8);
    const bf16x8* w2 = (const bf16x8*)(Wt + (size_t)(32 + i) * 256 + g * 8);
    const bf16x8* w3 = (const bf16x8*)(Wt + (size_t)(48 + i) * 256 + g * 8);

    f32x4 acc0 = {0.f, 0.f, 0.f, 0.f};
    f32x4 acc1 = acc0, acc2 = acc0, acc3 = acc0;
#pragma unroll
    for (int ks = 0; ks < 8; ++ks) {
        bf16x8 av = xa[ks * 4];
        bf16x8 b0 = w0[ks * 4];
        bf16x8 b1 = w1[ks * 4];
        bf16x8 b2 = w2[ks * 4];
        bf16x8 b3 = w3[ks * 4];
        acc0 = __builtin_amdgcn_mfma_f32_16x16x32_bf16(av, b0, acc0, 0, 0, 0);
        acc1 = __builtin_amdgcn_mfma_f32_16x16x32_bf16(av, b1, acc1, 0, 0, 0);
        acc2 = __builtin_amdgcn_mfma_f32_16x16x32_bf16(av, b2, acc2, 0, 0, 0);
        acc3 = __builtin_amdgcn_mfma_f32_16x16x32_bf16(av, b3, acc3, 0, 0, 0);
    }

    float bv0 = Bt[i], bv1 = Bt[16 + i], bv2 = Bt[32 + i], bv3 = Bt[48 + i];
    float al0 = Aw[i], al1 = Aw[16 + i], al2 = Aw[32 + i], al3 = Aw[48 + i];
    float ar0 = Aw[64 + i], ar1 = Aw[80 + i], ar2 = Aw[96 + i], ar3 = Aw[112 + i];
    float z0[4], z1[4], z2[4], z3[4], sp[4], rp[4];
#pragma unroll
    for (int r = 0; r < 4; ++r) {
        z0[r] = acc0[r] + bv0;
        z1[r] = acc1[r] + bv1;
        z2[r] = acc2[r] + bv2;
        z3[r] = acc3[r] + bv3;
        sp[r] = z0[r] * al0 + z1[r] * al1 + z2[r] * al2 + z3[r] * al3;
        rp[r] = z0[r] * ar0 + z1[r] * ar1 + z2[r] * ar2 + z3[r] * ar3;
    }
#pragma unroll
    for (int o = 1; o <= 8; o <<= 1) {
#pragma unroll
        for (int r = 0; r < 4; ++r) {
            sp[r] += __shfl_xor(sp[r], o);
            rp[r] += __shfl_xor(rp[r], o);
        }
    }
#pragma unroll
    for (int r = 0; r < 4; ++r) {
        int row = rowbase + g * 4 + r;
        if (row < Nn) {
            unsigned short* zp = Zb + (size_t)row * 64 + i;
            zp[0] = (unsigned short)f2bf(z0[r]);
            zp[16] = (unsigned short)f2bf(z1[r]);
            zp[32] = (unsigned short)f2bf(z2[r]);
            zp[48] = (unsigned short)f2bf(z3[r]);
            if (i == 0) {
                SLo[row] = sp[r];
                SRo[row] = rp[r];
            }
        }
    }
}

// ---------------- aggregation ----------------

#define MAX4_REDUCE(m0, m1, m2, m3)                      \
    _Pragma("unroll") for (int off = 32; off; off >>= 1) { \
        m0 = fmaxf(m0, __shfl_xor(m0, off));             \
        m1 = fmaxf(m1, __shfl_xor(m1, off));             \
        m2 = fmaxf(m2, __shfl_xor(m2, off));             \
        m3 = fmaxf(m3, __shfl_xor(m3, off));             \
    }

#define SUM4_REDUCE(d0, d1, d2, d3)                      \
    _Pragma("unroll") for (int off = 32; off; off >>= 1) { \
        d0 += __shfl_xor(d0, off);                       \
        d1 += __shfl_xor(d1, off);                       \
        d2 += __shfl_xor(d2, off);                       \
        d3 += __shfl_xor(d3, off);                       \
    }

// 4 heads: Zb [N][64][4] bf16 head-fastest; OUT: Hb bf16 [N][256].
// Per-edge {src, w0..w3} staged in WAVE-PRIVATE LDS after the score phase;
// loop reads them via uniform-address ds_read (broadcast, conflict-free, LDS
// pipe co-issues with VALU) -> replaces 5 v_readlane/edge with 0 VALU.
__global__ __launch_bounds__(256) void aggregate4_kernel(
    const unsigned short* __restrict__ Zb, const float* __restrict__ SL,
    const float* __restrict__ SR, const int* __restrict__ rowptr,
    const int* __restrict__ srcp, unsigned short* __restrict__ Hb, int Nn) {
    __shared__ int sstage[4][64];
    __shared__ float4 wstage[4][64];
    int wid = threadIdx.x >> 6;
    int n = (blockIdx.x * blockDim.x + threadIdx.x) >> 6;
    int lane = threadIdx.x & 63;
    if (n >= Nn) return;
    int s0 = rowptr[n], s1 = rowptr[n + 1];
    int deg = s1 - s0;
    unsigned short* hp = Hb + (size_t)n * 256 + lane;
    if (deg == 0) {
        hp[0] = 0; hp[64] = 0; hp[128] = 0; hp[192] = 0;
        return;
    }
    const float4 sr4 = *(const float4*)(SR + (size_t)n * 4);
    float hx = 0.f, hy = 0.f, hz = 0.f, hw = 0.f;
    float d0 = 0.f, d1 = 0.f, d2 = 0.f, d3 = 0.f;
    const unsigned laneoff = (unsigned)(lane * 8);

#define AGG4_EDGE_LDS(JJ)                                                    \
    {                                                                        \
        int s = sstage[wid][(JJ)];                                           \
        float4 w = wstage[wid][(JJ)];                                        \
        uint2 q = *(const uint2*)((const char*)Zb + ((unsigned)s * 512u + laneoff)); \
        hx = fmaf(w.x, bf_lo(q.x), hx);                                      \
        hy = fmaf(w.y, bf_hi(q.x), hy);                                      \
        hz = fmaf(w.z, bf_lo(q.y), hz);                                      \
        hw = fmaf(w.w, bf_hi(q.y), hw);                                      \
    }

    if (deg <= 64) {
        float e0 = -INFINITY, e1 = -INFINITY, e2 = -INFINITY, e3 = -INFINITY;
        int sv = 0;
        if (lane < deg) {
            sv = srcp[s0 + lane];
            float4 sl4 = *(const float4*)(SL + (size_t)sv * 4);
            e0 = gelu_exact(sl4.x + sr4.x);
            e1 = gelu_exact(sl4.y + sr4.y);
            e2 = gelu_exact(sl4.z + sr4.z);
            e3 = gelu_exact(sl4.w + sr4.w);
        }
        float m0 = e0, m1 = e1, m2 = e2, m3 = e3;
        MAX4_REDUCE(m0, m1, m2, m3)
        float ex0 = 0.f, ex1 = 0.f, ex2 = 0.f, ex3 = 0.f;
        if (lane < deg) {
            ex0 = __expf(e0 - m0); ex1 = __expf(e1 - m1);
            ex2 = __expf(e2 - m2); ex3 = __expf(e3 - m3);
        }
        d0 = ex0; d1 = ex1; d2 = ex2; d3 = ex3;
        if (lane < deg) {
            sstage[wid][lane] = sv;
            wstage[wid][lane] = make_float4(ex0, ex1, ex2, ex3);
        }
        int jj = 0;
        for (; jj + 3 < deg; jj += 4) {
            AGG4_EDGE_LDS(jj)
            AGG4_EDGE_LDS(jj + 1)
            AGG4_EDGE_LDS(jj + 2)
            AGG4_EDGE_LDS(jj + 3)
        }
        for (; jj < deg; ++jj) AGG4_EDGE_LDS(jj)
    } else {
        // rare fallback (deg>64): readlane broadcast, chunked
        float m0 = -INFINITY, m1 = -INFINITY, m2 = -INFINITY, m3 = -INFINITY;
        for (int base = s0; base < s1; base += 64) {
            int j = base + lane;
            if (j < s1) {
                int s = srcp[j];
                float4 sl4 = *(const float4*)(SL + (size_t)s * 4);
                m0 = fmaxf(m0, gelu_exact(sl4.x + sr4.x));
                m1 = fmaxf(m1, gelu_exact(sl4.y + sr4.y));
                m2 = fmaxf(m2, gelu_exact(sl4.z + sr4.z));
                m3 = fmaxf(m3, gelu_exact(sl4.w + sr4.w));
            }
        }
        MAX4_REDUCE(m0, m1, m2, m3)
        for (int base = s0; base < s1; base += 64) {
            int j = base + lane;
            int sv = 0;
            float ex0 = 0.f, ex1 = 0.f, ex2 = 0.f, ex3 = 0.f;
            if (j < s1) {
                sv = srcp[j];
                float4 sl4 = *(const float4*)(SL + (size_t)sv * 4);
                ex0 = __expf(gelu_exact(sl4.x + sr4.x) - m0);
                ex1 = __expf(gelu_exact(sl4.y + sr4.y) - m1);
                ex2 = __expf(gelu_exact(sl4.z + sr4.z) - m2);
                ex3 = __expf(gelu_exact(sl4.w + sr4.w) - m3);
            }
            d0 += ex0; d1 += ex1; d2 += ex2; d3 += ex3;
            int cs = min(64, s1 - base);
            for (int jj = 0; jj < cs; ++jj) {
                int s = readlane_i(sv, jj);
                float a0 = readlane_f(ex0, jj), a1 = readlane_f(ex1, jj);
                float a2 = readlane_f(ex2, jj), a3 = readlane_f(ex3, jj);
                uint2 q = *(const uint2*)((const char*)Zb + ((unsigned)s * 512u + laneoff));
                hx = fmaf(a0, bf_lo(q.x), hx);
                hy = fmaf(a1, bf_hi(q.x), hy);
                hz = fmaf(a2, bf_lo(q.y), hz);
                hw = fmaf(a3, bf_hi(q.y), hw);
            }
        }
    }
#undef AGG4_EDGE_LDS
    SUM4_REDUCE(d0, d1, d2, d3)
    hp[0] = (unsigned short)f2bf(hx / d0);
    hp[64] = (unsigned short)f2bf(hy / d1);
    hp[128] = (unsigned short)f2bf(hz / d2);
    hp[192] = (unsigned short)f2bf(hw / d3);
}

// 1 head: Zb [N][64] bf16 -> fbuf f32; same LDS-staging scheme
__global__ __launch_bounds__(256) void aggregate1_kernel(
    const unsigned short* __restrict__ Zb, const float* __restrict__ SL,
    const float* __restrict__ SR, const int* __restrict__ rowptr,
    const int* __restrict__ srcp, float* __restrict__ Hout, int Nn) {
    __shared__ int s1s[4][64];
    __shared__ float w1s[4][64];
    int wid = threadIdx.x >> 6;
    int n = (blockIdx.x * blockDim.x + threadIdx.x) >> 6;
    int lane = threadIdx.x & 63;
    if (n >= Nn) return;
    int s0 = rowptr[n], s1 = rowptr[n + 1];
    int deg = s1 - s0;
    if (deg == 0) {
        Hout[(size_t)n * 64 + lane] = 0.f;
        return;
    }
    const float srn = SR[n];
    float hacc = 0.f, den = 0.f;
    const unsigned laneoff = (unsigned)(lane * 2);

    if (deg <= 64) {
        float e = -INFINITY;
        int sv = 0;
        if (lane < deg) {
            sv = srcp[s0 + lane];
            e = gelu_exact(SL[sv] + srn);
        }
        float m = e;
#pragma unroll
        for (int off = 32; off; off >>= 1) m = fmaxf(m, __shfl_xor(m, off));
        float ex = (lane < deg) ? __expf(e - m) : 0.f;
        den = ex;
        if (lane < deg) {
            s1s[wid][lane] = sv;
            w1s[wid][lane] = ex;
        }
        int jj = 0;
        for (; jj + 3 < deg; jj += 4) {
#pragma unroll
            for (int u = 0; u < 4; ++u) {
                int s = s1s[wid][jj + u];
                float b = w1s[wid][jj + u];
                unsigned short zq = *(const unsigned short*)((const char*)Zb +
                                                             ((unsigned)s * 128u + laneoff));
                hacc = fmaf(b, bf_lo((unsigned int)zq), hacc);
            }
        }
        for (; jj < deg; ++jj) {
            int s = s1s[wid][jj];
            float b = w1s[wid][jj];
            unsigned short zq = *(const unsigned short*)((const char*)Zb +
                                                         ((unsigned)s * 128u + laneoff));
            hacc = fmaf(b, bf_lo((unsigned int)zq), hacc);
        }
    } else {
        float m = -INFINITY;
        for (int base = s0; base < s1; base += 64) {
            int j = base + lane;
            if (j < s1) m = fmaxf(m, gelu_exact(SL[srcp[j]] + srn));
        }
#pragma unroll
        for (int off = 32; off; off >>= 1) m = fmaxf(m, __shfl_xor(m, off));
        for (int base = s0; base < s1; base += 64) {
            int j = base + lane;
            int sv = 0;
            float ex = 0.f;
            if (j < s1) {
                sv = srcp[j];
                ex = __expf(gelu_exact(SL[sv] + srn) - m);
            }
            den += ex;
            int cs = min(64, s1 - base);
            for (int jj = 0; jj < cs; ++jj) {
                int s = readlane_i(sv, jj);
                float b = readlane_f(ex, jj);
                hacc = fmaf(b, bf_lo((unsigned int)Zb[(size_t)s * 64 + lane]), hacc);
            }
        }
    }
#pragma unroll
    for (int off = 32; off; off >>= 1) den += __shfl_xor(den, off);
    Hout[(size_t)n * 64 + lane] = hacc / den;
}

// out layer: 4 heads, D=7 (padded 8), Zf f32 stride 32
__global__ __launch_bounds__(256) void aggregateo_kernel(
    const float* __restrict__ Z, const float* __restrict__ SL, const float* __restrict__ SR,
    const int* __restrict__ rowptr, const int* __restrict__ srcp,
    float* __restrict__ Hout, int Nn) {
    int n = (blockIdx.x * blockDim.x + threadIdx.x) >> 6;
    int lane = threadIdx.x & 63;
    if (n >= Nn) return;
    int s0 = rowptr[n], s1 = rowptr[n + 1];
    int deg = s1 - s0;
    if (deg == 0) {
        if (lane < 32) Hout[(size_t)n * 32 + lane] = 0.f;
        return;
    }
    const float4 sr4 = *(const float4*)(SR + (size_t)n * 4);
    const int h = (lane & 31) >> 3;
    const int eo = lane >> 5;
    float hacc = 0.f;
    float d0 = 0.f, d1 = 0.f, d2 = 0.f, d3 = 0.f;
    const float* zl = Z + (lane & 31);

    if (deg <= 64) {
        float e0 = -INFINITY, e1 = -INFINITY, e2 = -INFINITY, e3 = -INFINITY;
        int sv = 0;
        if (lane < deg) {
            sv = srcp[s0 + lane];
            float4 sl4 = *(const float4*)(SL + (size_t)sv * 4);
            e0 = gelu_exact(sl4.x + sr4.x);
            e1 = gelu_exact(sl4.y + sr4.y);
            e2 = gelu_exact(sl4.z + sr4.z);
            e3 = gelu_exact(sl4.w + sr4.w);
        }
        float m0 = e0, m1 = e1, m2 = e2, m3 = e3;
        MAX4_REDUCE(m0, m1, m2, m3)
        float ex0 = 0.f, ex1 = 0.f, ex2 = 0.f, ex3 = 0.f;
        if (lane < deg) {
            ex0 = __expf(e0 - m0); ex1 = __expf(e1 - m1);
            ex2 = __expf(e2 - m2); ex3 = __expf(e3 - m3);
        }
        d0 = ex0; d1 = ex1; d2 = ex2; d3 = ex3;
        for (int jj = 0; jj < deg; jj += 2) {
            int lsrc = jj + eo;
            int s = __shfl(sv, lsrc);
            float b0 = __shfl(ex0, lsrc), b1 = __shfl(ex1, lsrc);
            float b2 = __shfl(ex2, lsrc), b3 = __shfl(ex3, lsrc);
            float exs = (h == 0) ? b0 : (h == 1) ? b1 : (h == 2) ? b2 : b3;
            hacc = fmaf(exs, zl[(size_t)s * 32], hacc);
        }
    } else {
        float m0 = -INFINITY, m1 = -INFINITY, m2 = -INFINITY, m3 = -INFINITY;
        for (int base = s0; base < s1; base += 64) {
            int j = base + lane;
            if (j < s1) {
                int s = srcp[j];
                float4 sl4 = *(const float4*)(SL + (size_t)s * 4);
                m0 = fmaxf(m0, gelu_exact(sl4.x + sr4.x));
                m1 = fmaxf(m1, gelu_exact(sl4.y + sr4.y));
                m2 = fmaxf(m2, gelu_exact(sl4.z + sr4.z));
                m3 = fmaxf(m3, gelu_exact(sl4.w + sr4.w));
            }
        }
        MAX4_REDUCE(m0, m1, m2, m3)
        for (int base = s0; base < s1; base += 64) {
            int j = base + lane;
            int sv = 0;
            float ex0 = 0.f, ex1 = 0.f, ex2 = 0.f, ex3 = 0.f;
            if (j < s1) {
                sv = srcp[j];
                float4 sl4 = *(const float4*)(SL + (size_t)sv * 4);
                ex0 = __expf(gelu_exact(sl4.x + sr4.x) - m0);
                ex1 = __expf(gelu_exact(sl4.y + sr4.y) - m1);
                ex2 = __expf(gelu_exact(sl4.z + sr4.z) - m2);
                ex3 = __expf(gelu_exact(sl4.w + sr4.w) - m3);
            }
            d0 += ex0; d1 += ex1; d2 += ex2; d3 += ex3;
            int cs = min(64, s1 - base);
            for (int jj = 0; jj < cs; jj += 2) {
                int lsrc = jj + eo;
                int s = __shfl(sv, lsrc);
                float b0 = __shfl(ex0, lsrc), b1 = __shfl(ex1, lsrc);
                float b2 = __shfl(ex2, lsrc), b3 = __shfl(ex3, lsrc);
                float exs = (h == 0) ? b0 : (h == 1) ? b1 : (h == 2) ? b2 : b3;
                hacc = fmaf(exs, zl[(size_t)s * 32], hacc);
            }
        }
    }
    SUM4_REDUCE(d0, d1, d2, d3)
    hacc += __shfl_xor(hacc, 32);
    float dsel = (h == 0) ? d0 : (h == 1) ? d1 : (h == 2) ? d2 : d3;
    if (lane < 32) Hout[(size_t)n * 32 + lane] = hacc / dsel;
}

// ---------------- mean-over-heads + linear + softmax ----------------

__global__ void finalize_kernel(const float* __restrict__ Hs, const float* __restrict__ LW,
                                const float* __restrict__ LB, float* __restrict__ out, int Nn) {
    int n = blockIdx.x * blockDim.x + threadIdx.x;
    if (n >= Nn) return;
    float mean[7];
#pragma unroll
    for (int k = 0; k < 7; k++)
        mean[k] = 0.25f * (Hs[(size_t)n * 32 + k] + Hs[(size_t)n * 32 + 8 + k] +
                           Hs[(size_t)n * 32 + 16 + k] + Hs[(size_t)n * 32 + 24 + k]);
    float lg[7];
#pragma unroll
    for (int o = 0; o < 7; o++) {
        float acc = LB[o];
#pragma unroll
        for (int k = 0; k < 7; k++) acc = fmaf(mean[k], LW[k * 7 + o], acc);
        lg[o] = acc;
    }
    float mx = lg[0];
#pragma unroll
    for (int o = 1; o < 7; o++) mx = fmaxf(mx, lg[o]);
    float s = 0.f;
#pragma unroll
    for (int o = 0; o < 7; o++) {
        lg[o] = __expf(lg[o] - mx);
        s += lg[o];
    }
    float inv = 1.f / s;
#pragma unroll
    for (int o = 0; o < 7; o++) out[(size_t)n * 7 + o] = lg[o] * inv;
}

// ---------------- launch ----------------

extern "C" void kernel_launch(void* const* d_in, const int* in_sizes, int n_in,
                              void* d_out, int out_size, void* d_ws, size_t ws_size,
                              hipStream_t stream) {
    const float* feature = (const float*)d_in[0];
    const int* src = (const int*)d_in[1];
    const int* dst = (const int*)d_in[2];
    const float* W0 = (const float*)d_in[3];
    const float* b0 = (const float*)d_in[4];
    const float* a0 = (const float*)d_in[5];
    const float* W0h = (const float*)d_in[6];
    const float* b0h = (const float*)d_in[7];
    const float* a0h = (const float*)d_in[8];
    const float* W1 = (const float*)d_in[9];
    const float* b1 = (const float*)d_in[10];
    const float* a1 = (const float*)d_in[11];
    const float* W1h = (const float*)d_in[12];
    const float* b1h = (const float*)d_in[13];
    const float* a1h = (const float*)d_in[14];
    const float* Wo = (const float*)d_in[15];
    const float* bo = (const float*)d_in[16];
    const float* ao = (const float*)d_in[17];
    const float* linW = (const float*)d_in[18];
    const float* linb = (const float*)d_in[19];
    const int N = in_sizes[0] / 64;
    const int E = in_sizes[1];
    float* out = (float*)d_out;

    char* ws = (char*)d_ws;
    size_t off = 0;
    auto alloc = [&](size_t bytes) {
        void* p = ws + off;
        off += (bytes + 255) & ~(size_t)255;
        return p;
    };
    int* cnt = (int*)alloc((size_t)N * 4);
    int* rowptr = (int*)alloc(((size_t)N + 1) * 4);
    int* bsum = (int*)alloc(256 * 4);
    int* srcp = (int*)alloc((size_t)E * 4);
    unsigned short* zbf = (unsigned short*)alloc((size_t)N * 256 * 2);   // gather tables
    unsigned short* hbufb = (unsigned short*)alloc((size_t)N * 256 * 2); // agg4 out (MFMA X)
    unsigned short* wtb = (unsigned short*)alloc(64 * 256 * 2);          // bf16 W^T
    float* zo = (float*)alloc((size_t)N * 32 * 4);
    float* fbuf = (float*)alloc((size_t)N * 64 * 4);
    float* slb = (float*)alloc((size_t)N * 4 * 4);
    float* srb = (float*)alloc((size_t)N * 4 * 4);
    float* houts = fbuf;  // safe alias: f2 dead after out-GEMM reads it

    // --- CSR by dst (reused by all 5 aggregation stages) ---
    hipMemsetAsync(cnt, 0, (size_t)N * 4, stream);
    hist_kernel<<<2048, 256, 0, stream>>>(dst, cnt, E);
    int nb = (N + 2047) / 2048;
    scan1_kernel<<<nb, 256, 0, stream>>>(cnt, rowptr, bsum, N);
    scan2_kernel<<<1, 32, 0, stream>>>(bsum, rowptr, nb, N);
    scan3_kernel<<<(N + 255) / 256, 256, 0, stream>>>(rowptr, bsum, N);
    hipMemsetAsync(cnt, 0, (size_t)N * 4, stream);
    scatter_kernel<<<2048, 256, 0, stream>>>(dst, rowptr, cnt, src, srcp, E);

    int gemm_blocks = (N + 31) / 32;
    int mfma_blocks = (N + 63) / 64;
    int ablk = (N + 3) / 4;  // one wave per node

    // --- layer 0 (4 heads, concat) ---
    gemm_kernel<0><<<gemm_blocks, 256, 0, stream>>>(feature, W0, b0, a0, zbf, nullptr, slb, srb, N);
    aggregate4_kernel<<<ablk, 256, 0, stream>>>(zbf, slb, srb, rowptr, srcp, hbufb, N);
    // --- layer 0 head_linear (MFMA) ---
    wconv_kernel<<<64, 256, 0, stream>>>(W0h, wtb);
    gemm1_mfma_kernel<<<mfma_blocks, 256, 0, stream>>>(hbufb, wtb, b0h, a0h, zbf, slb, srb, N);
    aggregate1_kernel<<<ablk, 256, 0, stream>>>(zbf, slb, srb, rowptr, srcp, fbuf, N);
    // --- layer 1 (4 heads, concat) ---
    gemm_kernel<0><<<gemm_blocks, 256, 0, stream>>>(fbuf, W1, b1, a1, zbf, nullptr, slb, srb, N);
    aggregate4_kernel<<<ablk, 256, 0, stream>>>(zbf, slb, srb, rowptr, srcp, hbufb, N);
    // --- layer 1 head_linear (MFMA) ---
    wconv_kernel<<<64, 256, 0, stream>>>(W1h, wtb);
    gemm1_mfma_kernel<<<mfma_blocks, 256, 0, stream>>>(hbufb, wtb, b1h, a1h, zbf, slb, srb, N);
    aggregate1_kernel<<<ablk, 256, 0, stream>>>(zbf, slb, srb, rowptr, srcp, fbuf, N);
    // --- out layer (4 heads, mean) ---
    gemm_kernel<2><<<gemm_blocks, 256, 0, stream>>>(fbuf, Wo, bo, ao, nullptr, zo, slb, srb, N);
    aggregateo_kernel<<<ablk, 256, 0, stream>>>(zo, slb, srb, rowptr, srcp, houts, N);
    finalize_kernel<<<(N + 255) / 256, 256, 0, stream>>>(houts, linW, linb, out, N);
}

// Round 12
// 900.900 us; speedup vs baseline: 2.3582x; 1.1375x over previous
//
#include <hip/hip_runtime.h>
#include <hip/hip_bf16.h>
#include <math.h>

#define HEADS 4
#define HID 64
#define OUTD 7

typedef __attribute__((ext_vector_type(8))) short bf16x8;
typedef __attribute__((ext_vector_type(4))) float f32x4;

__device__ __forceinline__ float gelu_exact(float x) {
    return 0.5f * x * (1.0f + erff(x * 0.70710678118654752f));
}

// broadcast lane k (wave-uniform) -> SGPR
__device__ __forceinline__ float readlane_f(float v, int k) {
    union { float f; int i; } u;
    u.f = v;
    u.i = __builtin_amdgcn_readlane(u.i, k);
    return u.f;
}
__device__ __forceinline__ int readlane_i(int v, int k) {
    return __builtin_amdgcn_readlane(v, k);
}

// bf16 helpers (RNE pack; unpack via bit ops)
__device__ __forceinline__ unsigned int f2bf(float f) {
    unsigned int x = __float_as_uint(f);
    return (x + 0x7fffu + ((x >> 16) & 1u)) >> 16;
}
__device__ __forceinline__ float bf_lo(unsigned int v) {
    return __uint_as_float(v << 16);
}
__device__ __forceinline__ float bf_hi(unsigned int v) {
    return __uint_as_float(v & 0xffff0000u);
}

// ---------------- CSR build ----------------
// histrank: atomic lives here (was in scatter); rank store is COALESCED.
__global__ void histrank_kernel(const int* __restrict__ dst, int* __restrict__ cnt,
                                int* __restrict__ rank, int E) {
    for (int e = blockIdx.x * blockDim.x + threadIdx.x; e < E; e += gridDim.x * blockDim.x)
        rank[e] = atomicAdd(&cnt[dst[e]], 1);
}

__global__ __launch_bounds__(256) void scan1_kernel(const int* __restrict__ cnt,
                                                    int* __restrict__ rowptr,
                                                    int* __restrict__ bsum, int Nn) {
    __shared__ int sums[256];
    int t = threadIdx.x;
    int base = blockIdx.x * 2048 + t * 8;
    int orig[8];
    int run = 0;
#pragma unroll
    for (int i = 0; i < 8; i++) {
        orig[i] = (base + i < Nn) ? cnt[base + i] : 0;
        run += orig[i];
    }
    sums[t] = run;
    __syncthreads();
    for (int off = 1; off < 256; off <<= 1) {
        int y = (t >= off) ? sums[t - off] : 0;
        __syncthreads();
        sums[t] += y;
        __syncthreads();
    }
    int excl = sums[t] - run;
    if (t == 255) bsum[blockIdx.x] = sums[255];
    int e = excl;
#pragma unroll
    for (int i = 0; i < 8; i++) {
        if (base + i < Nn) rowptr[base + i] = e;
        e += orig[i];
    }
}

__global__ void scan2_kernel(int* __restrict__ bsum, int* __restrict__ rowptr, int nb, int Nn) {
    if (blockIdx.x == 0 && threadIdx.x == 0) {
        int run = 0;
        for (int i = 0; i < nb; i++) {
            int t = bsum[i];
            bsum[i] = run;
            run += t;
        }
        rowptr[Nn] = run;
    }
}

__global__ void scan3_kernel(int* __restrict__ rowptr, const int* __restrict__ bsum, int Nn) {
    int i = blockIdx.x * blockDim.x + threadIdx.x;
    if (i < Nn) rowptr[i] += bsum[i >> 11];
}

// atomic-free scatter: p = rowptr[dst] + rank
__global__ void scatter2_kernel(const int* __restrict__ dst, const int* __restrict__ rank,
                                const int* __restrict__ rowptr, const int* __restrict__ srcv,
                                int* __restrict__ srcp, int E) {
    for (int e = blockIdx.x * blockDim.x + threadIdx.x; e < E; e += gridDim.x * blockDim.x)
        srcp[rowptr[dst[e]] + rank[e]] = srcv[e];
}

// feature f32 -> bf16 (vectorized)
__global__ void xconv_kernel(const float* __restrict__ X, unsigned short* __restrict__ Xb,
                             int total4) {
    int idx = blockIdx.x * blockDim.x + threadIdx.x;
    if (idx < total4) {
        float4 v = ((const float4*)X)[idx];
        ushort4 o = {(unsigned short)f2bf(v.x), (unsigned short)f2bf(v.y),
                     (unsigned short)f2bf(v.z), (unsigned short)f2bf(v.w)};
        ((ushort4*)Xb)[idx] = o;
    }
}

// W f32 [256][64] -> Wt bf16 [64][256] (transposed; MODE1 MFMA B)
__global__ void wconv1_kernel(const float* __restrict__ W, unsigned short* __restrict__ Wt) {
    int m = blockIdx.x, k = threadIdx.x;  // 64 blocks x 256 threads
    Wt[m * 256 + k] = (unsigned short)f2bf(W[k * 64 + m]);
}

// Wcat f32 [4][64][64] -> Wt0 bf16 [256][64]: Wt0[(h*64+c)][k] = W[h][k][c]
__global__ void wconv0_kernel(const float* __restrict__ W, unsigned short* __restrict__ Wt) {
    int m = blockIdx.x, k = threadIdx.x;  // 256 blocks x 64 threads
    int h = m >> 6, c = m & 63;
    Wt[m * 64 + k] = (unsigned short)f2bf(W[h * 4096 + k * 64 + c]);
}

// ---------------- MODE 0 GEMM via MFMA ----------------
// Xb bf16 [N][64] @ Wt0 bf16 [256][64] -> Zb bf16 [N][64][4] head-fastest
// + fused slr SL/SR[n*4+h]. Wave = 16 rows x 256 cols; K=64 = 2 ksteps x 16 tiles.
// Lane (g=lane>>4, i=lane&15) holds cols {16j+i}; head h col c=16jj+i is tile
// j=4h+jj -> each lane packs all 4 heads for its 4 c values (uint2 store).

__global__ __launch_bounds__(256) void gemm0_mfma_kernel(
    const unsigned short* __restrict__ Xb, const unsigned short* __restrict__ Wt,
    const float* __restrict__ Bt, const float* __restrict__ Aw,
    unsigned short* __restrict__ Zb, float* __restrict__ SLo, float* __restrict__ SRo,
    int Nn) {
    const int wid = threadIdx.x >> 6;
    const int lane = threadIdx.x & 63;
    const int g = lane >> 4, i = lane & 15;
    const int rowbase = blockIdx.x * 64 + wid * 16;
    int arow = rowbase + i;
    if (arow >= Nn) arow = Nn - 1;
    const bf16x8* xa = (const bf16x8*)(Xb + (size_t)arow * 64 + g * 8);

    f32x4 acc[16];
#pragma unroll
    for (int j = 0; j < 16; ++j) acc[j] = (f32x4){0.f, 0.f, 0.f, 0.f};
#pragma unroll
    for (int ks = 0; ks < 2; ++ks) {
        bf16x8 av = xa[ks * 4];
#pragma unroll
        for (int j = 0; j < 16; ++j) {
            bf16x8 bv = *(const bf16x8*)(Wt + (size_t)(16 * j + i) * 64 + ks * 32 + g * 8);
            acc[j] = __builtin_amdgcn_mfma_f32_16x16x32_bf16(av, bv, acc[j], 0, 0, 0);
        }
    }
    float bvv[4][4], alv[4][4], arv[4][4];
#pragma unroll
    for (int h = 0; h < 4; ++h)
#pragma unroll
        for (int jj = 0; jj < 4; ++jj) {
            int c = 16 * jj + i;
            bvv[h][jj] = Bt[64 * h + c];
            alv[h][jj] = Aw[h * 128 + c];
            arv[h][jj] = Aw[h * 128 + 64 + c];
        }
#pragma unroll
    for (int r = 0; r < 4; ++r) {
        int row = rowbase + g * 4 + r;
        float z[4][4], sp[4], rp[4];
#pragma unroll
        for (int h = 0; h < 4; ++h) {
            sp[h] = 0.f;
            rp[h] = 0.f;
        }
#pragma unroll
        for (int h = 0; h < 4; ++h)
#pragma unroll
            for (int jj = 0; jj < 4; ++jj) {
                float zv = acc[4 * h + jj][r] + bvv[h][jj];
                z[h][jj] = zv;
                sp[h] = fmaf(zv, alv[h][jj], sp[h]);
                rp[h] = fmaf(zv, arv[h][jj], rp[h]);
            }
#pragma unroll
        for (int o = 1; o < 16; o <<= 1) {
#pragma unroll
            for (int h = 0; h < 4; ++h) {
                sp[h] += __shfl_xor(sp[h], o);
                rp[h] += __shfl_xor(rp[h], o);
            }
        }
        if (row < Nn) {
#pragma unroll
            for (int jj = 0; jj < 4; ++jj) {
                unsigned int lo = f2bf(z[0][jj]) | (f2bf(z[1][jj]) << 16);
                unsigned int hi = f2bf(z[2][jj]) | (f2bf(z[3][jj]) << 16);
                uint2 pk = {lo, hi};
                *(uint2*)(Zb + (size_t)row * 256 + (16 * jj + i) * 4) = pk;
            }
            if (i == 0) {
                *(float4*)(SLo + (size_t)row * 4) = make_float4(sp[0], sp[1], sp[2], sp[3]);
                *(float4*)(SRo + (size_t)row * 4) = make_float4(rp[0], rp[1], rp[2], rp[3]);
            }
        }
    }
}

// ---------------- MODE 1 GEMM via MFMA (validated r9) ----------------

__global__ __launch_bounds__(256) void gemm1_mfma_kernel(
    const unsigned short* __restrict__ X, const unsigned short* __restrict__ Wt,
    const float* __restrict__ Bt, const float* __restrict__ Aw,
    unsigned short* __restrict__ Zb, float* __restrict__ SLo, float* __restrict__ SRo,
    int Nn) {
    const int tid = threadIdx.x;
    const int wid = tid >> 6;
    const int lane = tid & 63;
    const int g = lane >> 4, i = lane & 15;
    const int rowbase = blockIdx.x * 64 + wid * 16;

    int arow = rowbase + i;
    if (arow >= Nn) arow = Nn - 1;
    const bf16x8* xa = (const bf16x8*)(X + (size_t)arow * 256 + g * 8);
    const bf16x8* w0 = (const bf16x8*)(Wt + (size_t)(i)*256 + g * 8);
    const bf16x8* w1 = (const bf16x8*)(Wt + (size_t)(16 + i) * 256 + g * 8);
    const bf16x8* w2 = (const bf16x8*)(Wt + (size_t)(32 + i) * 256 + g * 8);
    const bf16x8* w3 = (const bf16x8*)(Wt + (size_t)(48 + i) * 256 + g * 8);

    f32x4 acc0 = {0.f, 0.f, 0.f, 0.f};
    f32x4 acc1 = acc0, acc2 = acc0, acc3 = acc0;
#pragma unroll
    for (int ks = 0; ks < 8; ++ks) {
        bf16x8 av = xa[ks * 4];
        bf16x8 b0 = w0[ks * 4];
        bf16x8 b1 = w1[ks * 4];
        bf16x8 b2 = w2[ks * 4];
        bf16x8 b3 = w3[ks * 4];
        acc0 = __builtin_amdgcn_mfma_f32_16x16x32_bf16(av, b0, acc0, 0, 0, 0);
        acc1 = __builtin_amdgcn_mfma_f32_16x16x32_bf16(av, b1, acc1, 0, 0, 0);
        acc2 = __builtin_amdgcn_mfma_f32_16x16x32_bf16(av, b2, acc2, 0, 0, 0);
        acc3 = __builtin_amdgcn_mfma_f32_16x16x32_bf16(av, b3, acc3, 0, 0, 0);
    }

    float bv0 = Bt[i], bv1 = Bt[16 + i], bv2 = Bt[32 + i], bv3 = Bt[48 + i];
    float al0 = Aw[i], al1 = Aw[16 + i], al2 = Aw[32 + i], al3 = Aw[48 + i];
    float ar0 = Aw[64 + i], ar1 = Aw[80 + i], ar2 = Aw[96 + i], ar3 = Aw[112 + i];
    float z0[4], z1[4], z2[4], z3[4], sp[4], rp[4];
#pragma unroll
    for (int r = 0; r < 4; ++r) {
        z0[r] = acc0[r] + bv0;
        z1[r] = acc1[r] + bv1;
        z2[r] = acc2[r] + bv2;
        z3[r] = acc3[r] + bv3;
        sp[r] = z0[r] * al0 + z1[r] * al1 + z2[r] * al2 + z3[r] * al3;
        rp[r] = z0[r] * ar0 + z1[r] * ar1 + z2[r] * ar2 + z3[r] * ar3;
    }
#pragma unroll
    for (int o = 1; o <= 8; o <<= 1) {
#pragma unroll
        for (int r = 0; r < 4; ++r) {
            sp[r] += __shfl_xor(sp[r], o);
            rp[r] += __shfl_xor(rp[r], o);
        }
    }
#pragma unroll
    for (int r = 0; r < 4; ++r) {
        int row = rowbase + g * 4 + r;
        if (row < Nn) {
            unsigned short* zp = Zb + (size_t)row * 64 + i;
            zp[0] = (unsigned short)f2bf(z0[r]);
            zp[16] = (unsigned short)f2bf(z1[r]);
            zp[32] = (unsigned short)f2bf(z2[r]);
            zp[48] = (unsigned short)f2bf(z3[r]);
            if (i == 0) {
                SLo[row] = sp[r];
                SRo[row] = rp[r];
            }
        }
    }
}

// ---------------- out-layer GEMM (VALU, bf16 X) ----------------
// Xb bf16 [N][64] @ Wo [4][64][7] + bo -> Zf f32 [N][32] + slr interleaved

__global__ __launch_bounds__(256, 2) void gemm2_kernel(const unsigned short* __restrict__ Xb,
                                                       const float* __restrict__ Wt,
                                                       const float* __restrict__ Bt,
                                                       const float* __restrict__ Aw,
                                                       float* __restrict__ Zf,
                                                       float* __restrict__ SLo,
                                                       float* __restrict__ SRo, int Nn) {
    __shared__ float wlds[64 * 32];
    const int tid = threadIdx.x;
    const int wid = tid >> 6;
    const int lane = tid & 63;
    const int row0 = blockIdx.x * 32 + wid * 8;

#pragma unroll
    for (int it = 0; it < 8; ++it) {
        int idx = it * 256 + tid;  // k*32 + m
        int k = idx >> 5, m = idx & 31, h = m >> 3, j = m & 7;
        wlds[idx] = (j < 7) ? Wt[h * 448 + k * 7 + j] : 0.f;
    }
    __syncthreads();

    float acc[8] = {};
    float xr[8];
#pragma unroll
    for (int r = 0; r < 8; ++r) {
        int rr = row0 + r;
        rr = (rr < Nn) ? rr : (Nn - 1);
        xr[r] = bf_lo((unsigned int)Xb[(size_t)rr * 64 + lane]);
    }
#pragma unroll 4
    for (int k = 0; k < 64; ++k) {
        float wv = wlds[k * 32 + (lane & 31)];
#pragma unroll
        for (int r = 0; r < 8; ++r) acc[r] = fmaf(readlane_f(xr[r], k), wv, acc[r]);
    }

    if (lane < 32) {
        int m = lane, h = m >> 3, j = m & 7;
        float bvv = (j < 7) ? Bt[h * 7 + j] : 0.f;
        float al = (j < 7) ? Aw[h * 14 + j] : 0.f;
        float ar = (j < 7) ? Aw[h * 14 + 7 + j] : 0.f;
#pragma unroll
        for (int r = 0; r < 8; ++r) {
            int row = row0 + r;
            float zv = (j < 7) ? acc[r] + bvv : 0.f;
            float sp = zv * al, rp = zv * ar;
#pragma unroll
            for (int o = 1; o < 8; o <<= 1) {
                sp += __shfl_xor(sp, o);
                rp += __shfl_xor(rp, o);
            }
            if (row < Nn) {
                Zf[(size_t)row * 32 + m] = zv;
                if (j == 0) {
                    SLo[(size_t)row * 4 + h] = sp;
                    SRo[(size_t)row * 4 + h] = rp;
                }
            }
        }
    }
}

// ---------------- aggregation ----------------

#define MAX4_REDUCE(m0, m1, m2, m3)                      \
    _Pragma("unroll") for (int off = 32; off; off >>= 1) { \
        m0 = fmaxf(m0, __shfl_xor(m0, off));             \
        m1 = fmaxf(m1, __shfl_xor(m1, off));             \
        m2 = fmaxf(m2, __shfl_xor(m2, off));             \
        m3 = fmaxf(m3, __shfl_xor(m3, off));             \
    }

#define SUM4_REDUCE(d0, d1, d2, d3)                      \
    _Pragma("unroll") for (int off = 32; off; off >>= 1) { \
        d0 += __shfl_xor(d0, off);                       \
        d1 += __shfl_xor(d1, off);                       \
        d2 += __shfl_xor(d2, off);                       \
        d3 += __shfl_xor(d3, off);                       \
    }

// 4 heads: Zb [N][64][4] bf16 head-fastest -> Hb bf16 [N][256] concat
__global__ __launch_bounds__(256) void aggregate4_kernel(
    const unsigned short* __restrict__ Zb, const float* __restrict__ SL,
    const float* __restrict__ SR, const int* __restrict__ rowptr,
    const int* __restrict__ srcp, unsigned short* __restrict__ Hb, int Nn) {
    __shared__ int sstage[4][64];
    __shared__ float4 wstage[4][64];
    int wid = threadIdx.x >> 6;
    int n = (blockIdx.x * blockDim.x + threadIdx.x) >> 6;
    int lane = threadIdx.x & 63;
    if (n >= Nn) return;
    int s0 = rowptr[n], s1 = rowptr[n + 1];
    int deg = s1 - s0;
    unsigned short* hp = Hb + (size_t)n * 256 + lane;
    if (deg == 0) {
        hp[0] = 0; hp[64] = 0; hp[128] = 0; hp[192] = 0;
        return;
    }
    const float4 sr4 = *(const float4*)(SR + (size_t)n * 4);
    float hx = 0.f, hy = 0.f, hz = 0.f, hw = 0.f;
    float d0 = 0.f, d1 = 0.f, d2 = 0.f, d3 = 0.f;
    const unsigned laneoff = (unsigned)(lane * 8);

#define AGG4_EDGE_LDS(JJ)                                                    \
    {                                                                        \
        int s = sstage[wid][(JJ)];                                           \
        float4 w = wstage[wid][(JJ)];                                        \
        uint2 q = *(const uint2*)((const char*)Zb + ((unsigned)s * 512u + laneoff)); \
        hx = fmaf(w.x, bf_lo(q.x), hx);                                      \
        hy = fmaf(w.y, bf_hi(q.x), hy);                                      \
        hz = fmaf(w.z, bf_lo(q.y), hz);                                      \
        hw = fmaf(w.w, bf_hi(q.y), hw);                                      \
    }

    if (deg <= 64) {
        float e0 = -INFINITY, e1 = -INFINITY, e2 = -INFINITY, e3 = -INFINITY;
        int sv = 0;
        if (lane < deg) {
            sv = srcp[s0 + lane];
            float4 sl4 = *(const float4*)(SL + (size_t)sv * 4);
            e0 = gelu_exact(sl4.x + sr4.x);
            e1 = gelu_exact(sl4.y + sr4.y);
            e2 = gelu_exact(sl4.z + sr4.z);
            e3 = gelu_exact(sl4.w + sr4.w);
        }
        float m0 = e0, m1 = e1, m2 = e2, m3 = e3;
        MAX4_REDUCE(m0, m1, m2, m3)
        float ex0 = 0.f, ex1 = 0.f, ex2 = 0.f, ex3 = 0.f;
        if (lane < deg) {
            ex0 = __expf(e0 - m0); ex1 = __expf(e1 - m1);
            ex2 = __expf(e2 - m2); ex3 = __expf(e3 - m3);
        }
        d0 = ex0; d1 = ex1; d2 = ex2; d3 = ex3;
        if (lane < deg) {
            sstage[wid][lane] = sv;
            wstage[wid][lane] = make_float4(ex0, ex1, ex2, ex3);
        }
        int jj = 0;
        for (; jj + 3 < deg; jj += 4) {
            AGG4_EDGE_LDS(jj)
            AGG4_EDGE_LDS(jj + 1)
            AGG4_EDGE_LDS(jj + 2)
            AGG4_EDGE_LDS(jj + 3)
        }
        for (; jj < deg; ++jj) AGG4_EDGE_LDS(jj)
    } else {
        float m0 = -INFINITY, m1 = -INFINITY, m2 = -INFINITY, m3 = -INFINITY;
        for (int base = s0; base < s1; base += 64) {
            int j = base + lane;
            if (j < s1) {
                int s = srcp[j];
                float4 sl4 = *(const float4*)(SL + (size_t)s * 4);
                m0 = fmaxf(m0, gelu_exact(sl4.x + sr4.x));
                m1 = fmaxf(m1, gelu_exact(sl4.y + sr4.y));
                m2 = fmaxf(m2, gelu_exact(sl4.z + sr4.z));
                m3 = fmaxf(m3, gelu_exact(sl4.w + sr4.w));
            }
        }
        MAX4_REDUCE(m0, m1, m2, m3)
        for (int base = s0; base < s1; base += 64) {
            int j = base + lane;
            int sv = 0;
            float ex0 = 0.f, ex1 = 0.f, ex2 = 0.f, ex3 = 0.f;
            if (j < s1) {
                sv = srcp[j];
                float4 sl4 = *(const float4*)(SL + (size_t)sv * 4);
                ex0 = __expf(gelu_exact(sl4.x + sr4.x) - m0);
                ex1 = __expf(gelu_exact(sl4.y + sr4.y) - m1);
                ex2 = __expf(gelu_exact(sl4.z + sr4.z) - m2);
                ex3 = __expf(gelu_exact(sl4.w + sr4.w) - m3);
            }
            d0 += ex0; d1 += ex1; d2 += ex2; d3 += ex3;
            int cs = min(64, s1 - base);
            for (int jj = 0; jj < cs; ++jj) {
                int s = readlane_i(sv, jj);
                float a0 = readlane_f(ex0, jj), a1 = readlane_f(ex1, jj);
                float a2 = readlane_f(ex2, jj), a3 = readlane_f(ex3, jj);
                uint2 q = *(const uint2*)((const char*)Zb + ((unsigned)s * 512u + laneoff));
                hx = fmaf(a0, bf_lo(q.x), hx);
                hy = fmaf(a1, bf_hi(q.x), hy);
                hz = fmaf(a2, bf_lo(q.y), hz);
                hw = fmaf(a3, bf_hi(q.y), hw);
            }
        }
    }
#undef AGG4_EDGE_LDS
    SUM4_REDUCE(d0, d1, d2, d3)
    hp[0] = (unsigned short)f2bf(hx / d0);
    hp[64] = (unsigned short)f2bf(hy / d1);
    hp[128] = (unsigned short)f2bf(hz / d2);
    hp[192] = (unsigned short)f2bf(hw / d3);
}

// 1 head: Zb [N][64] bf16 -> Hout bf16 [N][64]
__global__ __launch_bounds__(256) void aggregate1_kernel(
    const unsigned short* __restrict__ Zb, const float* __restrict__ SL,
    const float* __restrict__ SR, const int* __restrict__ rowptr,
    const int* __restrict__ srcp, unsigned short* __restrict__ Hout, int Nn) {
    __shared__ int s1s[4][64];
    __shared__ float w1s[4][64];
    int wid = threadIdx.x >> 6;
    int n = (blockIdx.x * blockDim.x + threadIdx.x) >> 6;
    int lane = threadIdx.x & 63;
    if (n >= Nn) return;
    int s0 = rowptr[n], s1 = rowptr[n + 1];
    int deg = s1 - s0;
    if (deg == 0) {
        Hout[(size_t)n * 64 + lane] = 0;
        return;
    }
    const float srn = SR[n];
    float hacc = 0.f, den = 0.f;
    const unsigned laneoff = (unsigned)(lane * 2);

    if (deg <= 64) {
        float e = -INFINITY;
        int sv = 0;
        if (lane < deg) {
            sv = srcp[s0 + lane];
            e = gelu_exact(SL[sv] + srn);
        }
        float m = e;
#pragma unroll
        for (int off = 32; off; off >>= 1) m = fmaxf(m, __shfl_xor(m, off));
        float ex = (lane < deg) ? __expf(e - m) : 0.f;
        den = ex;
        if (lane < deg) {
            s1s[wid][lane] = sv;
            w1s[wid][lane] = ex;
        }
        int jj = 0;
        for (; jj + 3 < deg; jj += 4) {
#pragma unroll
            for (int u = 0; u < 4; ++u) {
                int s = s1s[wid][jj + u];
                float b = w1s[wid][jj + u];
                unsigned short zq = *(const unsigned short*)((const char*)Zb +
                                                             ((unsigned)s * 128u + laneoff));
                hacc = fmaf(b, bf_lo((unsigned int)zq), hacc);
            }
        }
        for (; jj < deg; ++jj) {
            int s = s1s[wid][jj];
            float b = w1s[wid][jj];
            unsigned short zq = *(const unsigned short*)((const char*)Zb +
                                                         ((unsigned)s * 128u + laneoff));
            hacc = fmaf(b, bf_lo((unsigned int)zq), hacc);
        }
    } else {
        float m = -INFINITY;
        for (int base = s0; base < s1; base += 64) {
            int j = base + lane;
            if (j < s1) m = fmaxf(m, gelu_exact(SL[srcp[j]] + srn));
        }
#pragma unroll
        for (int off = 32; off; off >>= 1) m = fmaxf(m, __shfl_xor(m, off));
        for (int base = s0; base < s1; base += 64) {
            int j = base + lane;
            int sv = 0;
            float ex = 0.f;
            if (j < s1) {
                sv = srcp[j];
                ex = __expf(gelu_exact(SL[sv] + srn) - m);
            }
            den += ex;
            int cs = min(64, s1 - base);
            for (int jj = 0; jj < cs; ++jj) {
                int s = readlane_i(sv, jj);
                float b = readlane_f(ex, jj);
                hacc = fmaf(b, bf_lo((unsigned int)Zb[(size_t)s * 64 + lane]), hacc);
            }
        }
    }
#pragma unroll
    for (int off = 32; off; off >>= 1) den += __shfl_xor(den, off);
    Hout[(size_t)n * 64 + lane] = (unsigned short)f2bf(hacc / den);
}

// out layer: 4 heads, D=7 (padded 8), Zf f32 stride 32 -> Hout f32 [N][32]
__global__ __launch_bounds__(256) void aggregateo_kernel(
    const float* __restrict__ Z, const float* __restrict__ SL, const float* __restrict__ SR,
    const int* __restrict__ rowptr, const int* __restrict__ srcp,
    float* __restrict__ Hout, int Nn) {
    int n = (blockIdx.x * blockDim.x + threadIdx.x) >> 6;
    int lane = threadIdx.x & 63;
    if (n >= Nn) return;
    int s0 = rowptr[n], s1 = rowptr[n + 1];
    int deg = s1 - s0;
    if (deg == 0) {
        if (lane < 32) Hout[(size_t)n * 32 + lane] = 0.f;
        return;
    }
    const float4 sr4 = *(const float4*)(SR + (size_t)n * 4);
    const int h = (lane & 31) >> 3;
    const int eo = lane >> 5;
    float hacc = 0.f;
    float d0 = 0.f, d1 = 0.f, d2 = 0.f, d3 = 0.f;
    const float* zl = Z + (lane & 31);

    if (deg <= 64) {
        float e0 = -INFINITY, e1 = -INFINITY, e2 = -INFINITY, e3 = -INFINITY;
        int sv = 0;
        if (lane < deg) {
            sv = srcp[s0 + lane];
            float4 sl4 = *(const float4*)(SL + (size_t)sv * 4);
            e0 = gelu_exact(sl4.x + sr4.x);
            e1 = gelu_exact(sl4.y + sr4.y);
            e2 = gelu_exact(sl4.z + sr4.z);
            e3 = gelu_exact(sl4.w + sr4.w);
        }
        float m0 = e0, m1 = e1, m2 = e2, m3 = e3;
        MAX4_REDUCE(m0, m1, m2, m3)
        float ex0 = 0.f, ex1 = 0.f, ex2 = 0.f, ex3 = 0.f;
        if (lane < deg) {
            ex0 = __expf(e0 - m0); ex1 = __expf(e1 - m1);
            ex2 = __expf(e2 - m2); ex3 = __expf(e3 - m3);
        }
        d0 = ex0; d1 = ex1; d2 = ex2; d3 = ex3;
        for (int jj = 0; jj < deg; jj += 2) {
            int lsrc = jj + eo;
            int s = __shfl(sv, lsrc);
            float b0 = __shfl(ex0, lsrc), b1 = __shfl(ex1, lsrc);
            float b2 = __shfl(ex2, lsrc), b3 = __shfl(ex3, lsrc);
            float exs = (h == 0) ? b0 : (h == 1) ? b1 : (h == 2) ? b2 : b3;
            hacc = fmaf(exs, zl[(size_t)s * 32], hacc);
        }
    } else {
        float m0 = -INFINITY, m1 = -INFINITY, m2 = -INFINITY, m3 = -INFINITY;
        for (int base = s0; base < s1; base += 64) {
            int j = base + lane;
            if (j < s1) {
                int s = srcp[j];
                float4 sl4 = *(const float4*)(SL + (size_t)s * 4);
                m0 = fmaxf(m0, gelu_exact(sl4.x + sr4.x));
                m1 = fmaxf(m1, gelu_exact(sl4.y + sr4.y));
                m2 = fmaxf(m2, gelu_exact(sl4.z + sr4.z));
                m3 = fmaxf(m3, gelu_exact(sl4.w + sr4.w));
            }
        }
        MAX4_REDUCE(m0, m1, m2, m3)
        for (int base = s0; base < s1; base += 64) {
            int j = base + lane;
            int sv = 0;
            float ex0 = 0.f, ex1 = 0.f, ex2 = 0.f, ex3 = 0.f;
            if (j < s1) {
                sv = srcp[j];
                float4 sl4 = *(const float4*)(SL + (size_t)sv * 4);
                ex0 = __expf(gelu_exact(sl4.x + sr4.x) - m0);
                ex1 = __expf(gelu_exact(sl4.y + sr4.y) - m1);
                ex2 = __expf(gelu_exact(sl4.z + sr4.z) - m2);
                ex3 = __expf(gelu_exact(sl4.w + sr4.w) - m3);
            }
            d0 += ex0; d1 += ex1; d2 += ex2; d3 += ex3;
            int cs = min(64, s1 - base);
            for (int jj = 0; jj < cs; jj += 2) {
                int lsrc = jj + eo;
                int s = __shfl(sv, lsrc);
                float b0 = __shfl(ex0, lsrc), b1 = __shfl(ex1, lsrc);
                float b2 = __shfl(ex2, lsrc), b3 = __shfl(ex3, lsrc);
                float exs = (h == 0) ? b0 : (h == 1) ? b1 : (h == 2) ? b2 : b3;
                hacc = fmaf(exs, zl[(size_t)s * 32], hacc);
            }
        }
    }
    SUM4_REDUCE(d0, d1, d2, d3)
    hacc += __shfl_xor(hacc, 32);
    float dsel = (h == 0) ? d0 : (h == 1) ? d1 : (h == 2) ? d2 : d3;
    if (lane < 32) Hout[(size_t)n * 32 + lane] = hacc / dsel;
}

// ---------------- mean-over-heads + linear + softmax ----------------

__global__ void finalize_kernel(const float* __restrict__ Hs, const float* __restrict__ LW,
                                const float* __restrict__ LB, float* __restrict__ out, int Nn) {
    int n = blockIdx.x * blockDim.x + threadIdx.x;
    if (n >= Nn) return;
    float mean[7];
#pragma unroll
    for (int k = 0; k < 7; k++)
        mean[k] = 0.25f * (Hs[(size_t)n * 32 + k] + Hs[(size_t)n * 32 + 8 + k] +
                           Hs[(size_t)n * 32 + 16 + k] + Hs[(size_t)n * 32 + 24 + k]);
    float lg[7];
#pragma unroll
    for (int o = 0; o < 7; o++) {
        float acc = LB[o];
#pragma unroll
        for (int k = 0; k < 7; k++) acc = fmaf(mean[k], LW[k * 7 + o], acc);
        lg[o] = acc;
    }
    float mx = lg[0];
#pragma unroll
    for (int o = 1; o < 7; o++) mx = fmaxf(mx, lg[o]);
    float s = 0.f;
#pragma unroll
    for (int o = 0; o < 7; o++) {
        lg[o] = __expf(lg[o] - mx);
        s += lg[o];
    }
    float inv = 1.f / s;
#pragma unroll
    for (int o = 0; o < 7; o++) out[(size_t)n * 7 + o] = lg[o] * inv;
}

// ---------------- launch ----------------

extern "C" void kernel_launch(void* const* d_in, const int* in_sizes, int n_in,
                              void* d_out, int out_size, void* d_ws, size_t ws_size,
                              hipStream_t stream) {
    const float* feature = (const float*)d_in[0];
    const int* src = (const int*)d_in[1];
    const int* dst = (const int*)d_in[2];
    const float* W0 = (const float*)d_in[3];
    const float* b0 = (const float*)d_in[4];
    const float* a0 = (const float*)d_in[5];
    const float* W0h = (const float*)d_in[6];
    const float* b0h = (const float*)d_in[7];
    const float* a0h = (const float*)d_in[8];
    const float* W1 = (const float*)d_in[9];
    const float* b1 = (const float*)d_in[10];
    const float* a1 = (const float*)d_in[11];
    const float* W1h = (const float*)d_in[12];
    const float* b1h = (const float*)d_in[13];
    const float* a1h = (const float*)d_in[14];
    const float* Wo = (const float*)d_in[15];
    const float* bo = (const float*)d_in[16];
    const float* ao = (const float*)d_in[17];
    const float* linW = (const float*)d_in[18];
    const float* linb = (const float*)d_in[19];
    const int N = in_sizes[0] / 64;
    const int E = in_sizes[1];
    float* out = (float*)d_out;

    char* ws = (char*)d_ws;
    size_t off = 0;
    auto alloc = [&](size_t bytes) {
        void* p = ws + off;
        off += (bytes + 255) & ~(size_t)255;
        return p;
    };
    int* cnt = (int*)alloc((size_t)N * 4);
    int* rowptr = (int*)alloc(((size_t)N + 1) * 4);
    int* bsum = (int*)alloc(256 * 4);
    int* rank = (int*)alloc((size_t)E * 4);
    int* srcp = (int*)alloc((size_t)E * 4);
    unsigned short* zbf = (unsigned short*)alloc((size_t)N * 256 * 2);   // gather tables
    unsigned short* hbufb = (unsigned short*)alloc((size_t)N * 256 * 2); // agg4 out
    unsigned short* wtb = (unsigned short*)alloc(256 * 64 * 2);          // bf16 W (reused)
    unsigned short* xfeat = (unsigned short*)alloc((size_t)N * 64 * 2);  // bf16 feature
    unsigned short* fb16 = (unsigned short*)alloc((size_t)N * 64 * 2);   // agg1 out (bf16)
    float* zo = (float*)alloc((size_t)N * 32 * 4);
    float* slb = (float*)alloc((size_t)N * 4 * 4);
    float* srb = (float*)alloc((size_t)N * 4 * 4);
    float* houts = (float*)fb16;  // alias: fb16 dead after gemm2 reads it

    // --- CSR by dst (atomic folded into histrank; scatter atomic-free) ---
    hipMemsetAsync(cnt, 0, (size_t)N * 4, stream);
    histrank_kernel<<<2048, 256, 0, stream>>>(dst, cnt, rank, E);
    int nb = (N + 2047) / 2048;
    scan1_kernel<<<nb, 256, 0, stream>>>(cnt, rowptr, bsum, N);
    scan2_kernel<<<1, 32, 0, stream>>>(bsum, rowptr, nb, N);
    scan3_kernel<<<(N + 255) / 256, 256, 0, stream>>>(rowptr, bsum, N);
    scatter2_kernel<<<2048, 256, 0, stream>>>(dst, rank, rowptr, src, srcp, E);
    xconv_kernel<<<(N * 64 / 4 + 255) / 256, 256, 0, stream>>>(feature, xfeat, N * 64 / 4);

    int mfma_blocks = (N + 63) / 64;
    int g2_blocks = (N + 31) / 32;
    int ablk = (N + 3) / 4;  // one wave per node

    // --- layer 0 (4 heads, concat) ---
    wconv0_kernel<<<256, 64, 0, stream>>>(W0, wtb);
    gemm0_mfma_kernel<<<mfma_blocks, 256, 0, stream>>>(xfeat, wtb, b0, a0, zbf, slb, srb, N);
    aggregate4_kernel<<<ablk, 256, 0, stream>>>(zbf, slb, srb, rowptr, srcp, hbufb, N);
    // --- layer 0 head_linear (MFMA) ---
    wconv1_kernel<<<64, 256, 0, stream>>>(W0h, wtb);
    gemm1_mfma_kernel<<<mfma_blocks, 256, 0, stream>>>(hbufb, wtb, b0h, a0h, zbf, slb, srb, N);
    aggregate1_kernel<<<ablk, 256, 0, stream>>>(zbf, slb, srb, rowptr, srcp, fb16, N);
    // --- layer 1 (4 heads, concat) ---
    wconv0_kernel<<<256, 64, 0, stream>>>(W1, wtb);
    gemm0_mfma_kernel<<<mfma_blocks, 256, 0, stream>>>(fb16, wtb, b1, a1, zbf, slb, srb, N);
    aggregate4_kernel<<<ablk, 256, 0, stream>>>(zbf, slb, srb, rowptr, srcp, hbufb, N);
    // --- layer 1 head_linear (MFMA) ---
    wconv1_kernel<<<64, 256, 0, stream>>>(W1h, wtb);
    gemm1_mfma_kernel<<<mfma_blocks, 256, 0, stream>>>(hbufb, wtb, b1h, a1h, zbf, slb, srb, N);
    aggregate1_kernel<<<ablk, 256, 0, stream>>>(zbf, slb, srb, rowptr, srcp, fb16, N);
    // --- out layer (4 heads, mean) ---
    gemm2_kernel<<<g2_blocks, 256, 0, stream>>>(fb16, Wo, bo, ao, zo, slb, srb, N);
    aggregateo_kernel<<<ablk, 256, 0, stream>>>(zo, slb, srb, rowptr, srcp, houts, N);
    finalize_kernel<<<(N + 255) / 256, 256, 0, stream>>>(houts, linW, linb, out, N);
}